// Round 8
// baseline (498.541 us; speedup 1.0000x reference)
//
#include <hip/hip_runtime.h>
#include <hip/hip_bf16.h>
#include <math.h>

#define B_  2
#define T_  2048
#define D_  1024
#define H_  16
#define DK_ 64
#define FF_ 4096
#define BT_ (B_*T_)

typedef __attribute__((ext_vector_type(8))) short bf16x8;
typedef __attribute__((ext_vector_type(4))) float f32x4;

__device__ __forceinline__ ushort f2bf(float f) {
    __hip_bfloat16 h = __float2bfloat16(f);
    return *reinterpret_cast<ushort*>(&h);
}
__device__ __forceinline__ float bf2f(ushort u) {
    __hip_bfloat16 h;
    *reinterpret_cast<ushort*>(&h) = u;
    return __bfloat162float(h);
}

// async global->LDS, 16B per lane. LDS dest must be wave-uniform base + lane*16.
__device__ __forceinline__ void g2l16(const ushort* g, ushort* l) {
    __builtin_amdgcn_global_load_lds(
        (const __attribute__((address_space(1))) void*)g,
        (__attribute__((address_space(3))) void*)l, 16, 0, 0);
}

// ---------------------------------------------------------------------------
// f32 -> bf16 elementwise (vectorized, n multiple of 1024)
// ---------------------------------------------------------------------------
__global__ __launch_bounds__(256) void cvt_bf16_kernel(
    const float* __restrict__ in, ushort* __restrict__ out, int n)
{
    int i = (blockIdx.x * 256 + threadIdx.x) * 4;
    if (i >= n) return;
    float4 v = *(const float4*)(in + i);
    ushort4 o;
    o.x = f2bf(v.x); o.y = f2bf(v.y); o.z = f2bf(v.z); o.w = f2bf(v.w);
    *(ushort4*)(out + i) = o;
}

// ---------------------------------------------------------------------------
// transpose + convert: in f32 [K][N] -> out bf16 [N][K]; batched over z.
// ---------------------------------------------------------------------------
__global__ __launch_bounds__(256) void transpose_bf16_kernel(
    const float* __restrict__ in, ushort* __restrict__ out,
    int K, int N, long in_bstride, long out_bstride)
{
    __shared__ float t[32][33];
    const float* ib = in + (size_t)blockIdx.z * in_bstride;
    ushort* ob = out + (size_t)blockIdx.z * out_bstride;
    int n0 = blockIdx.x * 32, k0 = blockIdx.y * 32;
    int tid = threadIdx.x;
    int r = tid >> 3, c4 = (tid & 7) * 4;
    float4 v = *(const float4*)(ib + (size_t)(k0 + r) * N + n0 + c4);
    t[r][c4] = v.x; t[r][c4+1] = v.y; t[r][c4+2] = v.z; t[r][c4+3] = v.w;
    __syncthreads();
    int n = tid >> 3, kc = (tid & 7) * 4;
    ushort4 o;
    o.x = f2bf(t[kc+0][n]); o.y = f2bf(t[kc+1][n]);
    o.z = f2bf(t[kc+2][n]); o.w = f2bf(t[kc+3][n]);
    *(ushort4*)(ob + (size_t)(n0 + n) * K + k0 + kc) = o;
}

// ---------------------------------------------------------------------------
// 256x256-tile NT GEMM, bf16 MFMA, BK=64, 512 threads (8 waves, 2Mx4N,
// per-wave 128x64 out). 8-PHASE SCHEDULE (T3+T4+T5, m201-style adapted to
// conflict-free kc-major LDS):
//   iter t: stage all 8 loads of tile t+1 -> buf[c^1]; s_waitcnt vmcnt(8)
//           (retires tile t, keeps t+1's 8 in flight -- never drains);
//           publish barrier; then 4 phases (ih,ks):
//             { ds_read frags ; barrier ; setprio(1) 16xMFMA setprio(0) ;
//               barrier }
//   B-fragments are reused across the two ih phases of each ks.
// LDS 128 KiB double-buffered. XCD swizzle. Split-K via blockIdx.z.
// ---------------------------------------------------------------------------
template<int OUT_BF16>
__global__ __launch_bounds__(512) void gemm256_kernel(
    const ushort* __restrict__ A, int lda,
    const ushort* __restrict__ Bt, int ldb,
    void* __restrict__ C, int ldc, int K,
    const float* __restrict__ bias,
    const float* __restrict__ resid, int relu,
    long aZoff, long bZoff, long cZoff)
{
    __shared__ __attribute__((aligned(16))) ushort As[2][8][256][8];
    __shared__ __attribute__((aligned(16))) ushort Bs[2][8][256][8];

    A  += (size_t)blockIdx.z * aZoff;
    Bt += (size_t)blockIdx.z * bZoff;
    char* Cb = (char*)C + (size_t)blockIdx.z * cZoff * (OUT_BF16 ? 2 : 4);

    // XCD swizzle over x,y (nwg per z-slice must be %8==0 -- true here)
    int nwg  = gridDim.x * gridDim.y;
    int orig = blockIdx.y * gridDim.x + blockIdx.x;
    int work = (orig & 7) * (nwg >> 3) + (orig >> 3);
    int bx = work % gridDim.x, by = work / gridDim.x;

    int row0 = by * 256, col0 = bx * 256;
    int tid = threadIdx.x;
    int l = tid & 63;
    int w = tid >> 6;
    int wr = (w >> 2) * 128, wc = (w & 3) * 64;

    // staging coords (proven R5/R6): m const per thread, kc = kc0 + 2p
    int m = tid & 255, kc0 = tid >> 8;
    const ushort* gA = A  + (size_t)(row0 + m) * lda + kc0 * 8;
    const ushort* gB = Bt + (size_t)(col0 + m) * ldb + kc0 * 8;

    f32x4 acc[8][4];
    #pragma unroll
    for (int i = 0; i < 8; ++i)
        #pragma unroll
        for (int j = 0; j < 4; ++j) acc[i][j] = (f32x4){0.f, 0.f, 0.f, 0.f};

    const int NT = K >> 6;

    // prologue: stage tile 0 -> buf 0 (8 loads in flight)
    #pragma unroll
    for (int p = 0; p < 4; ++p) {
        g2l16(gA + p*16, &As[0][kc0 + 2*p][m][0]);
        g2l16(gB + p*16, &Bs[0][kc0 + 2*p][m][0]);
    }

    for (int t = 0; t < NT; ++t) {
        int c = t & 1;
        // stage tile t+1 -> buf[c^1] (WAR safe: buf[c^1] reads finished
        // before prev iter's closing barrier)
        if (t + 1 < NT) {
            int k0 = (t + 1) << 6;
            #pragma unroll
            for (int p = 0; p < 4; ++p) {
                g2l16(gA + k0 + p*16, &As[c ^ 1][kc0 + 2*p][m][0]);
                g2l16(gB + k0 + p*16, &Bs[c ^ 1][kc0 + 2*p][m][0]);
            }
            __builtin_amdgcn_sched_barrier(0);
            asm volatile("s_waitcnt vmcnt(8)" ::: "memory");  // tile t landed
        } else {
            __builtin_amdgcn_sched_barrier(0);
            asm volatile("s_waitcnt vmcnt(0)" ::: "memory");  // final drain
        }
        __builtin_amdgcn_sched_barrier(0);
        __builtin_amdgcn_s_barrier();        // publish tile t to all waves
        __builtin_amdgcn_sched_barrier(0);

        bf16x8 bfr[4];
        #pragma unroll
        for (int ks = 0; ks < 2; ++ks) {
            #pragma unroll
            for (int ih = 0; ih < 2; ++ih) {
                // ---- phase (ks, ih) ----
                bf16x8 af[4];
                #pragma unroll
                for (int i = 0; i < 4; ++i)
                    af[i] = *(const bf16x8*)
                        &As[c][ks*4 + (l>>4)][wr + ih*64 + i*16 + (l & 15)][0];
                if (ih == 0) {
                    #pragma unroll
                    for (int j = 0; j < 4; ++j)
                        bfr[j] = *(const bf16x8*)
                            &Bs[c][ks*4 + (l>>4)][wc + j*16 + (l & 15)][0];
                }
                __builtin_amdgcn_sched_barrier(0);
                __builtin_amdgcn_s_barrier();
                __builtin_amdgcn_sched_barrier(0);
                __builtin_amdgcn_s_setprio(1);
                #pragma unroll
                for (int i = 0; i < 4; ++i)
                    #pragma unroll
                    for (int j = 0; j < 4; ++j)
                        acc[ih*4 + i][j] = __builtin_amdgcn_mfma_f32_16x16x32_bf16(
                            af[i], bfr[j], acc[ih*4 + i][j], 0, 0, 0);
                __builtin_amdgcn_s_setprio(0);
                __builtin_amdgcn_sched_barrier(0);
                __builtin_amdgcn_s_barrier();
                __builtin_amdgcn_sched_barrier(0);
            }
        }
    }

    #pragma unroll
    for (int i = 0; i < 8; ++i) {
        int rbase = row0 + wr + i*16 + (l >> 4) * 4;
        #pragma unroll
        for (int j = 0; j < 4; ++j) {
            int col = col0 + wc + j*16 + (l & 15);
            float bv = bias ? bias[col] : 0.f;
            #pragma unroll
            for (int r = 0; r < 4; ++r) {
                int row = rbase + r;
                float val = acc[i][j][r] + bv;
                if (resid) val += resid[(size_t)row * ldc + col];
                if (relu)  val = fmaxf(val, 0.f);
                if (OUT_BF16) ((ushort*)Cb)[(size_t)row * ldc + col] = f2bf(val);
                else          ((float*)Cb)[(size_t)row * ldc + col]  = val;
            }
        }
    }
}

// ---------------------------------------------------------------------------
// 128x128 NT GEMM (Wo: N=1024 -> 256 blocks). 2-phase, BK=32, 32KB dbuf.
// ---------------------------------------------------------------------------
template<int OUT_BF16>
__global__ __launch_bounds__(256) void gemm_nt_kernel(
    const ushort* __restrict__ A, int lda,
    const ushort* __restrict__ Bt, int ldb,
    void* __restrict__ C, int ldc, int K,
    const float* __restrict__ bias,
    const float* __restrict__ resid, int relu)
{
    __shared__ __attribute__((aligned(16))) ushort As[2][4][128][8];
    __shared__ __attribute__((aligned(16))) ushort Bs[2][4][128][8];

    int nwg  = gridDim.x * gridDim.y;
    int orig = blockIdx.y * gridDim.x + blockIdx.x;
    int work = (orig & 7) * (nwg >> 3) + (orig >> 3);
    int bx = work % gridDim.x, by = work / gridDim.x;

    int row0 = by * 128, col0 = bx * 128;
    int tid = threadIdx.x;
    int w = tid >> 6, l = tid & 63;
    int wr = (w >> 1) * 64, wc = (w & 1) * 64;

    int m0 = tid & 127, kc0 = tid >> 7;
    int m1 = (tid + 256) & 127, kc1 = (tid + 256) >> 7;
    const ushort* ga0 = A  + (size_t)(row0 + m0) * lda + kc0 * 8;
    const ushort* ga1 = A  + (size_t)(row0 + m1) * lda + kc1 * 8;
    const ushort* gb0 = Bt + (size_t)(col0 + m0) * ldb + kc0 * 8;
    const ushort* gb1 = Bt + (size_t)(col0 + m1) * ldb + kc1 * 8;

    f32x4 acc[4][4];
    #pragma unroll
    for (int i = 0; i < 4; ++i)
        #pragma unroll
        for (int j = 0; j < 4; ++j) acc[i][j] = (f32x4){0.f, 0.f, 0.f, 0.f};

    const int NT = K >> 5;
    g2l16(ga0, &As[0][kc0][m0][0]);
    g2l16(ga1, &As[0][kc1][m1][0]);
    g2l16(gb0, &Bs[0][kc0][m0][0]);
    g2l16(gb1, &Bs[0][kc1][m1][0]);
    __syncthreads();

    int cur = 0;
    for (int t = 0; t < NT; ++t) {
        if (t + 1 < NT) {
            int k0 = (t + 1) << 5;
            g2l16(ga0 + k0, &As[cur ^ 1][kc0][m0][0]);
            g2l16(ga1 + k0, &As[cur ^ 1][kc1][m1][0]);
            g2l16(gb0 + k0, &Bs[cur ^ 1][kc0][m0][0]);
            g2l16(gb1 + k0, &Bs[cur ^ 1][kc1][m1][0]);
        }
        int kc = l >> 4;
        bf16x8 af[4], bfr[4];
        #pragma unroll
        for (int i = 0; i < 4; ++i)
            af[i] = *(const bf16x8*)&As[cur][kc][wr + i*16 + (l & 15)][0];
        #pragma unroll
        for (int j = 0; j < 4; ++j)
            bfr[j] = *(const bf16x8*)&Bs[cur][kc][wc + j*16 + (l & 15)][0];
        #pragma unroll
        for (int i = 0; i < 4; ++i)
            #pragma unroll
            for (int j = 0; j < 4; ++j)
                acc[i][j] = __builtin_amdgcn_mfma_f32_16x16x32_bf16(
                    af[i], bfr[j], acc[i][j], 0, 0, 0);
        __syncthreads();
        cur ^= 1;
    }

    #pragma unroll
    for (int i = 0; i < 4; ++i) {
        int rbase = row0 + wr + i*16 + (l >> 4) * 4;
        #pragma unroll
        for (int j = 0; j < 4; ++j) {
            int col = col0 + wc + j*16 + (l & 15);
            float bv = bias ? bias[col] : 0.f;
            #pragma unroll
            for (int r = 0; r < 4; ++r) {
                int row = rbase + r;
                float val = acc[i][j][r] + bv;
                if (resid) val += resid[(size_t)row * ldc + col];
                if (relu)  val = fmaxf(val, 0.f);
                if (OUT_BF16) ((ushort*)C)[(size_t)row * ldc + col] = f2bf(val);
                else          ((float*)C)[(size_t)row * ldc + col]  = val;
            }
        }
    }
}

// ---------------------------------------------------------------------------
// colsum[s] = sum_q exp(q·k/8).  grid (T/128, B*H), 256 thr.
// qkv packed [bt][3072]: q at col 0, k at 1024, v at 2048 (+h*64).
// ---------------------------------------------------------------------------
__global__ __launch_bounds__(256) void csum_kernel(
    const ushort* __restrict__ qkv, float* __restrict__ col_sum)
{
    int bh = blockIdx.y, b = bh >> 4, h = bh & 15;
    int s0 = blockIdx.x * 128;
    const ushort* qb = qkv + (size_t)b * T_ * 3072 + h * 64;
    const ushort* kb = qb + 1024;
    __shared__ __attribute__((aligned(16))) ushort Ks[8][128][8];
    __shared__ __attribute__((aligned(16))) ushort Qs[8][64][8];
    int tid = threadIdx.x, w = tid >> 6, l = tid & 63;
    int scol = w * 32;

    #pragma unroll
    for (int p = 0; p < 4; ++p) {
        int idx = tid + p * 256;
        int s = idx & 127, kc = idx >> 7;
        *(uint4*)&Ks[kc][s][0] =
            *(const uint4*)(kb + (size_t)(s0 + s) * 3072 + kc * 8);
    }
    float cs[2] = {0.f, 0.f};
    for (int qt = 0; qt < T_ / 64; ++qt) {
        __syncthreads();
        #pragma unroll
        for (int p = 0; p < 2; ++p) {
            int idx = tid + p * 256;
            int qq = idx & 63, kc = idx >> 6;
            *(uint4*)&Qs[kc][qq][0] =
                *(const uint4*)(qb + (size_t)(qt*64 + qq) * 3072 + kc * 8);
        }
        __syncthreads();
        bf16x8 af[4][2], bfr[2][2];
        #pragma unroll
        for (int qi = 0; qi < 4; ++qi)
            #pragma unroll
            for (int ks = 0; ks < 2; ++ks)
                af[qi][ks] = *(const bf16x8*)&Qs[ks*4 + (l>>4)][qi*16 + (l & 15)][0];
        #pragma unroll
        for (int sj = 0; sj < 2; ++sj)
            #pragma unroll
            for (int ks = 0; ks < 2; ++ks)
                bfr[sj][ks] = *(const bf16x8*)&Ks[ks*4 + (l>>4)][scol + sj*16 + (l & 15)][0];
        #pragma unroll
        for (int qi = 0; qi < 4; ++qi)
            #pragma unroll
            for (int sj = 0; sj < 2; ++sj) {
                f32x4 d = (f32x4){0.f, 0.f, 0.f, 0.f};
                #pragma unroll
                for (int ks = 0; ks < 2; ++ks)
                    d = __builtin_amdgcn_mfma_f32_16x16x32_bf16(
                        af[qi][ks], bfr[sj][ks], d, 0, 0, 0);
                cs[sj] += __expf(d[0]*0.125f) + __expf(d[1]*0.125f)
                        + __expf(d[2]*0.125f) + __expf(d[3]*0.125f);
            }
    }
    #pragma unroll
    for (int sj = 0; sj < 2; ++sj) {
        float v = cs[sj];
        v += __shfl_down(v, 32, 64);
        v += __shfl_down(v, 16, 64);
        if (l < 16)
            col_sum[(size_t)bh * T_ + s0 + scol + sj*16 + l] = v;
    }
}

// ---------------------------------------------------------------------------
// vt[bh][dv][s] = v[bh][s][dv] / colsum[bh][s]   (bf16, transposed V)
// ---------------------------------------------------------------------------
__global__ __launch_bounds__(256) void vscale_kernel(
    const ushort* __restrict__ qkv, const float* __restrict__ col_sum,
    ushort* __restrict__ vt)
{
    int bh = blockIdx.y, b = bh >> 4, h = bh & 15;
    int s0 = blockIdx.x * 64;
    const ushort* vb = qkv + (size_t)b * T_ * 3072 + 2048 + h * 64;
    __shared__ float t[64][65];
    int tid = threadIdx.x;
    #pragma unroll
    for (int p = 0; p < 2; ++p) {
        int idx = tid + p * 256;
        int s = idx >> 3, c0 = (idx & 7) * 8;
        uint4 raw = *(const uint4*)(vb + (size_t)(s0 + s) * 3072 + c0);
        float rc = 1.0f / col_sum[(size_t)bh * T_ + s0 + s];
        ushort* u = (ushort*)&raw;
        #pragma unroll
        for (int i = 0; i < 8; ++i) t[s][c0 + i] = bf2f(u[i]) * rc;
    }
    __syncthreads();
    #pragma unroll
    for (int p = 0; p < 2; ++p) {
        int idx = tid + p * 256;
        int dv = idx >> 3, sc = (idx & 7) * 8;
        ushort o[8];
        #pragma unroll
        for (int i = 0; i < 8; ++i) o[i] = f2bf(t[sc + i][dv]);
        *(uint4*)(vt + ((size_t)bh * 64 + dv) * T_ + s0 + sc) = *(uint4*)o;
    }
}

// ---------------------------------------------------------------------------
// PV: O[q][dv] = sum_s exp(q·k/8) * vt[dv][s].  grid (T/64, B*H), 256 thr.
// ---------------------------------------------------------------------------
__global__ __launch_bounds__(256) void attn_pv_kernel(
    const ushort* __restrict__ qkv, const ushort* __restrict__ vt,
    ushort* __restrict__ attn_o)
{
    int bh = blockIdx.y, b = bh >> 4, h = bh & 15;
    int q0 = blockIdx.x * 64;
    const ushort* qb = qkv + (size_t)b * T_ * 3072 + h * 64;
    const ushort* kb = qb + 1024;
    const ushort* vtb = vt + (size_t)bh * 64 * T_;
    __shared__ __attribute__((aligned(16))) ushort Qs[8][64][8];
    __shared__ __attribute__((aligned(16))) ushort Ks[8][64][8];
    __shared__ __attribute__((aligned(16))) ushort Vs[8][64][8];
    __shared__ __attribute__((aligned(16))) ushort Es[8][64][8];
    int tid = threadIdx.x, w = tid >> 6, l = tid & 63;
    int qw = w * 16;

    #pragma unroll
    for (int p = 0; p < 2; ++p) {
        int idx = tid + p * 256;
        int qq = idx & 63, kc = idx >> 6;
        *(uint4*)&Qs[kc][qq][0] =
            *(const uint4*)(qb + (size_t)(q0 + qq) * 3072 + kc * 8);
    }
    __syncthreads();
    bf16x8 qf[2];
    #pragma unroll
    for (int ks = 0; ks < 2; ++ks)
        qf[ks] = *(const bf16x8*)&Qs[ks*4 + (l>>4)][qw + (l & 15)][0];

    f32x4 oacc[4];
    #pragma unroll
    for (int j = 0; j < 4; ++j) oacc[j] = (f32x4){0.f, 0.f, 0.f, 0.f};

    for (int st = 0; st < T_ / 64; ++st) {
        int s0 = st * 64;
        __syncthreads();
        #pragma unroll
        for (int p = 0; p < 2; ++p) {
            int idx = tid + p * 256;
            int rr = idx & 63, kc = idx >> 6;
            *(uint4*)&Ks[kc][rr][0] =
                *(const uint4*)(kb + (size_t)(s0 + rr) * 3072 + kc * 8);
            *(uint4*)&Vs[kc][rr][0] =
                *(const uint4*)(vtb + (size_t)rr * T_ + s0 + kc * 8);
        }
        __syncthreads();
        #pragma unroll
        for (int sj = 0; sj < 4; ++sj) {
            f32x4 d = (f32x4){0.f, 0.f, 0.f, 0.f};
            #pragma unroll
            for (int ks = 0; ks < 2; ++ks) {
                bf16x8 kf = *(const bf16x8*)&Ks[ks*4 + (l>>4)][sj*16 + (l & 15)][0];
                d = __builtin_amdgcn_mfma_f32_16x16x32_bf16(qf[ks], kf, d, 0, 0, 0);
            }
            #pragma unroll
            for (int r = 0; r < 4; ++r) {
                int qq = qw + (l>>4)*4 + r;
                int ss = sj*16 + (l & 15);
                Es[ss >> 3][qq][ss & 7] = f2bf(__expf(d[r] * 0.125f));
            }
        }
        bf16x8 ef[2];
        #pragma unroll
        for (int ks = 0; ks < 2; ++ks)
            ef[ks] = *(const bf16x8*)&Es[ks*4 + (l>>4)][qw + (l & 15)][0];
        #pragma unroll
        for (int j = 0; j < 4; ++j)
            #pragma unroll
            for (int ks = 0; ks < 2; ++ks) {
                bf16x8 vf = *(const bf16x8*)&Vs[ks*4 + (l>>4)][j*16 + (l & 15)][0];
                oacc[j] = __builtin_amdgcn_mfma_f32_16x16x32_bf16(ef[ks], vf, oacc[j], 0, 0, 0);
            }
    }
    #pragma unroll
    for (int j = 0; j < 4; ++j)
        #pragma unroll
        for (int r = 0; r < 4; ++r) {
            int qq = q0 + qw + (l>>4)*4 + r;
            int dv = j*16 + (l & 15);
            attn_o[(size_t)(b*T_ + qq) * 1024 + h*64 + dv] = f2bf(oacc[j][r]);
        }
}

// ---------------------------------------------------------------------------
// mean/std norm (Bessel), optional bf16 side-output.
// ---------------------------------------------------------------------------
__device__ __forceinline__ float block_reduce_sum_256(float v, float* tmp)
{
    #pragma unroll
    for (int off = 32; off; off >>= 1) v += __shfl_down(v, off, 64);
    int lane = threadIdx.x & 63, w = threadIdx.x >> 6;
    __syncthreads();
    if (lane == 0) tmp[w] = v;
    __syncthreads();
    return tmp[0] + tmp[1] + tmp[2] + tmp[3];
}

__global__ __launch_bounds__(256) void norm_kernel(
    const float* __restrict__ in, float* __restrict__ outf,
    ushort* __restrict__ outb)
{
    __shared__ float tmp[4];
    int row = blockIdx.x;
    const float* r = in + (size_t)row * D_;
    int tid = threadIdx.x;
    float vals[4];
    #pragma unroll
    for (int i = 0; i < 4; ++i) vals[i] = r[tid + i*256];
    float s = vals[0] + vals[1] + vals[2] + vals[3];
    s = block_reduce_sum_256(s, tmp);
    float m = s * (1.0f / (float)D_);
    float sq = 0.f;
    #pragma unroll
    for (int i = 0; i < 4; ++i) { float c = vals[i] - m; sq += c * c; }
    sq = block_reduce_sum_256(sq, tmp);
    float rs = rsqrtf(sq * (1.0f / (float)(D_ - 1)));
    #pragma unroll
    for (int i = 0; i < 4; ++i) {
        float o = (vals[i] - m) * rs;
        outf[(size_t)row * D_ + tid + i*256] = o;
        if (outb) outb[(size_t)row * D_ + tid + i*256] = f2bf(o);
    }
}

// ---------------------------------------------------------------------------
// norm2 fused: y = sum_{z<4} parts[z] (bf16 partials) + b2 + resid,
// then mean/std norm -> out f32.
// ---------------------------------------------------------------------------
__global__ __launch_bounds__(256) void norm2_fused_kernel(
    const ushort* __restrict__ parts, long zoff,
    const float* __restrict__ b2, const float* __restrict__ resid,
    float* __restrict__ outp)
{
    __shared__ float tmp[4];
    int row = blockIdx.x;
    int tid = threadIdx.x;
    int c0 = tid * 4;
    size_t idx = (size_t)row * D_ + c0;
    float vals[4] = {0.f, 0.f, 0.f, 0.f};
    #pragma unroll
    for (int z = 0; z < 4; ++z) {
        ushort4 p = *(const ushort4*)&parts[idx + (size_t)z * zoff];
        vals[0] += bf2f(p.x); vals[1] += bf2f(p.y);
        vals[2] += bf2f(p.z); vals[3] += bf2f(p.w);
    }
    float4 rv = *(const float4*)&resid[idx];
    float4 bv = *(const float4*)&b2[c0];
    vals[0] += bv.x + rv.x; vals[1] += bv.y + rv.y;
    vals[2] += bv.z + rv.z; vals[3] += bv.w + rv.w;
    float s = vals[0] + vals[1] + vals[2] + vals[3];
    s = block_reduce_sum_256(s, tmp);
    float m = s * (1.0f / (float)D_);
    float sq = 0.f;
    #pragma unroll
    for (int i = 0; i < 4; ++i) { float c = vals[i] - m; sq += c * c; }
    sq = block_reduce_sum_256(sq, tmp);
    float rs = rsqrtf(sq * (1.0f / (float)(D_ - 1)));
    float4 o;
    o.x = (vals[0] - m) * rs; o.y = (vals[1] - m) * rs;
    o.z = (vals[2] - m) * rs; o.w = (vals[3] - m) * rs;
    *(float4*)&outp[idx] = o;
}

// ---------------------------------------------------------------------------
extern "C" void kernel_launch(void* const* d_in, const int* in_sizes, int n_in,
                              void* d_out, int out_size, void* d_ws, size_t ws_size,
                              hipStream_t stream)
{
    const float* x  = (const float*)d_in[0];
    const float* Wq = (const float*)d_in[1];
    const float* Wk = (const float*)d_in[2];
    const float* Wv = (const float*)d_in[3];
    const float* Wo = (const float*)d_in[4];
    const float* W1 = (const float*)d_in[5];
    const float* b1 = (const float*)d_in[6];
    const float* W2 = (const float*)d_in[7];
    const float* b2 = (const float*)d_in[8];
    float* out = (float*)d_out;

    const size_t MB = (size_t)1 << 20;
    char* base = (char*)d_ws;
    // lifetimes (peak ~113MB at W2):
    ushort* qkv    = (ushort*)(base +   0*MB);  // 24MB  [QKV..PV]
    ushort* hid    = (ushort*)(base +   0*MB);  // 32MB  [W1..W2]     (reuses qkv+xb)
    ushort* xb     = (ushort*)(base +  24*MB);  //  8MB  [cvt..QKV]
    ushort* W2t    = (ushort*)(base +  32*MB);  //  8MB  [cvt..W2]
    ushort* Wqkvt  = (ushort*)(base +  40*MB);  //  6MB  [cvt..QKV]
    ushort* wpart  = (ushort*)(base +  40*MB);  // 32MB  [W2..norm2]  (reuses 40-72)
    ushort* vt     = (ushort*)(base +  46*MB);  //  8MB  [vscale..PV]
    float*  csum   = (float*) (base +  54*MB);  // .25MB [csum..vscale]
    ushort* Wot    = (ushort*)(base +  55*MB);  //  2MB  [cvt..Wo]
    ushort* W1t    = (ushort*)(base +  57*MB);  //  8MB  [cvt..W1]
    ushort* attn_o = (ushort*)(base +  65*MB);  //  8MB  [PV..Wo]
    float*  oproj  = (float*) (base +  73*MB);  // 16MB  [Wo..norm1]
    ushort* out1b  = (ushort*)(base +  89*MB);  //  8MB  [norm1..W1]
    float*  out1f  = (float*) (base +  97*MB);  // 16MB  [norm1..norm2]

    // 1. converts / transposes
    cvt_bf16_kernel<<<dim3(BT_*D_/1024), 256, 0, stream>>>(x, xb, BT_*D_);
    transpose_bf16_kernel<<<dim3(2, 32, 16), 256, 0, stream>>>(
        Wq, Wqkvt + 0*1048576, 1024, 64, 65536, 65536);
    transpose_bf16_kernel<<<dim3(2, 32, 16), 256, 0, stream>>>(
        Wk, Wqkvt + 1*1048576, 1024, 64, 65536, 65536);
    transpose_bf16_kernel<<<dim3(2, 32, 16), 256, 0, stream>>>(
        Wv, Wqkvt + 2*1048576, 1024, 64, 65536, 65536);
    transpose_bf16_kernel<<<dim3(32, 32, 1), 256, 0, stream>>>(
        Wo, Wot, 1024, 1024, 0, 0);
    transpose_bf16_kernel<<<dim3(128, 32, 1), 256, 0, stream>>>(
        W1, W1t, 1024, 4096, 0, 0);
    transpose_bf16_kernel<<<dim3(32, 128, 1), 256, 0, stream>>>(
        W2, W2t, 4096, 1024, 0, 0);

    // 2. QKV: [4096,1024] @ [3072,1024]^T -> qkv bf16 [4096,3072]
    gemm256_kernel<1><<<dim3(3072/256, 4096/256, 1), 512, 0, stream>>>(
        xb, 1024, Wqkvt, 1024, qkv, 3072, 1024, nullptr, nullptr, 0, 0, 0, 0);
    // 3. column sums of exp(scores)
    csum_kernel<<<dim3(T_/128, B_*H_), 256, 0, stream>>>(qkv, csum);
    // 4. vt = (v/colsum)^T
    vscale_kernel<<<dim3(T_/64, B_*H_), 256, 0, stream>>>(qkv, csum, vt);
    // 5. PV
    attn_pv_kernel<<<dim3(T_/64, B_*H_), 256, 0, stream>>>(qkv, vt, attn_o);
    // 6. Wo projection + residual x -> oproj f32 (128^2 tile: 256 blocks)
    gemm_nt_kernel<0><<<dim3(1024/128, 4096/128), 256, 0, stream>>>(
        attn_o, 1024, Wot, 1024, oproj, 1024, 1024, nullptr, x, 0);
    // 7. norm1 -> out1f (f32) + out1b (bf16)
    norm_kernel<<<dim3(BT_), 256, 0, stream>>>(oproj, out1f, out1b);
    // 8. FFN up + ReLU -> hid bf16 [4096,4096]
    gemm256_kernel<1><<<dim3(4096/256, 4096/256, 1), 512, 0, stream>>>(
        out1b, 1024, W1t, 1024, hid, 4096, 1024, b1, nullptr, 1, 0, 0, 0);
    // 9. FFN down, split-K4 -> bf16 partials wpart[z][4096][1024]
    gemm256_kernel<1><<<dim3(1024/256, 4096/256, 4), 512, 0, stream>>>(
        hid, 4096, W2t, 4096, wpart, 1024, 1024, nullptr, nullptr, 0,
        1024, 1024, (long)4096*1024);
    // 10. norm2 fused: sum 4 partials + b2 + out1 resid -> norm -> out
    norm2_fused_kernel<<<dim3(BT_), 256, 0, stream>>>(
        wpart, (long)4096*1024, b2, out1f, out);
}

// Round 9
// 439.876 us; speedup vs baseline: 1.1334x; 1.1334x over previous
//
#include <hip/hip_runtime.h>
#include <hip/hip_bf16.h>
#include <math.h>

#define B_  2
#define T_  2048
#define D_  1024
#define H_  16
#define DK_ 64
#define FF_ 4096
#define BT_ (B_*T_)

typedef __attribute__((ext_vector_type(8))) short bf16x8;
typedef __attribute__((ext_vector_type(4))) float f32x4;

__device__ __forceinline__ ushort f2bf(float f) {
    __hip_bfloat16 h = __float2bfloat16(f);
    return *reinterpret_cast<ushort*>(&h);
}
__device__ __forceinline__ float bf2f(ushort u) {
    __hip_bfloat16 h;
    *reinterpret_cast<ushort*>(&h) = u;
    return __bfloat162float(h);
}

// async global->LDS, 16B per lane. LDS dest must be wave-uniform base + lane*16.
__device__ __forceinline__ void g2l16(const ushort* g, ushort* l) {
    __builtin_amdgcn_global_load_lds(
        (const __attribute__((address_space(1))) void*)g,
        (__attribute__((address_space(3))) void*)l, 16, 0, 0);
}

// ---------------------------------------------------------------------------
// f32 -> bf16 elementwise (vectorized, n multiple of 1024)
// ---------------------------------------------------------------------------
__global__ __launch_bounds__(256) void cvt_bf16_kernel(
    const float* __restrict__ in, ushort* __restrict__ out, int n)
{
    int i = (blockIdx.x * 256 + threadIdx.x) * 4;
    if (i >= n) return;
    float4 v = *(const float4*)(in + i);
    ushort4 o;
    o.x = f2bf(v.x); o.y = f2bf(v.y); o.z = f2bf(v.z); o.w = f2bf(v.w);
    *(ushort4*)(out + i) = o;
}

// ---------------------------------------------------------------------------
// transpose + convert: in f32 [K][N] -> out bf16 [N][K]; batched over z.
// ---------------------------------------------------------------------------
__global__ __launch_bounds__(256) void transpose_bf16_kernel(
    const float* __restrict__ in, ushort* __restrict__ out,
    int K, int N, long in_bstride, long out_bstride)
{
    __shared__ float t[32][33];
    const float* ib = in + (size_t)blockIdx.z * in_bstride;
    ushort* ob = out + (size_t)blockIdx.z * out_bstride;
    int n0 = blockIdx.x * 32, k0 = blockIdx.y * 32;
    int tid = threadIdx.x;
    int r = tid >> 3, c4 = (tid & 7) * 4;
    float4 v = *(const float4*)(ib + (size_t)(k0 + r) * N + n0 + c4);
    t[r][c4] = v.x; t[r][c4+1] = v.y; t[r][c4+2] = v.z; t[r][c4+3] = v.w;
    __syncthreads();
    int n = tid >> 3, kc = (tid & 7) * 4;
    ushort4 o;
    o.x = f2bf(t[kc+0][n]); o.y = f2bf(t[kc+1][n]);
    o.z = f2bf(t[kc+2][n]); o.w = f2bf(t[kc+3][n]);
    *(ushort4*)(ob + (size_t)(n0 + n) * K + k0 + kc) = o;
}

// ---------------------------------------------------------------------------
// 128x128 NT GEMM, bf16 MFMA, BK=32, 256 thr (4 waves, 2x2 of 64x64).
// 2-phase dbuf (stage-next -> ds_read+MFMA -> one __syncthreads per K-tile).
// 32KB LDS -> up to 5 blocks/CU: grids are sized for >=2 blocks/CU so
// inter-block wave overlap hides the barrier drain (m114/m102 mechanism).
// Split-K via blockIdx.z (aZoff/bZoff/cZoff in elements).
// ---------------------------------------------------------------------------
template<int OUT_BF16>
__global__ __launch_bounds__(256) void gemm_nt_kernel(
    const ushort* __restrict__ A, int lda,
    const ushort* __restrict__ Bt, int ldb,
    void* __restrict__ C, int ldc, int K,
    const float* __restrict__ bias,
    const float* __restrict__ resid, int relu,
    long aZoff, long bZoff, long cZoff)
{
    __shared__ __attribute__((aligned(16))) ushort As[2][4][128][8];
    __shared__ __attribute__((aligned(16))) ushort Bs[2][4][128][8];

    A  += (size_t)blockIdx.z * aZoff;
    Bt += (size_t)blockIdx.z * bZoff;
    char* Cb = (char*)C + (size_t)blockIdx.z * cZoff * (OUT_BF16 ? 2 : 4);

    // XCD swizzle per z-slice (nwg % 8 == 0 for all launches here)
    int nwg  = gridDim.x * gridDim.y;
    int orig = blockIdx.y * gridDim.x + blockIdx.x;
    int work = (orig & 7) * (nwg >> 3) + (orig >> 3);
    int bx = work % gridDim.x, by = work / gridDim.x;

    int row0 = by * 128, col0 = bx * 128;
    int tid = threadIdx.x;
    int w = tid >> 6, l = tid & 63;
    int wr = (w >> 1) * 64, wc = (w & 1) * 64;

    int m0 = tid & 127, kc0 = tid >> 7;           // kc0 in {0,1}
    const ushort* ga0 = A  + (size_t)(row0 + m0) * lda + kc0 * 8;
    const ushort* gb0 = Bt + (size_t)(col0 + m0) * ldb + kc0 * 8;

    f32x4 acc[4][4];
    #pragma unroll
    for (int i = 0; i < 4; ++i)
        #pragma unroll
        for (int j = 0; j < 4; ++j) acc[i][j] = (f32x4){0.f, 0.f, 0.f, 0.f};

    const int NT = K >> 5;
    g2l16(ga0,      &As[0][kc0    ][m0][0]);
    g2l16(ga0 + 16, &As[0][kc0 + 2][m0][0]);
    g2l16(gb0,      &Bs[0][kc0    ][m0][0]);
    g2l16(gb0 + 16, &Bs[0][kc0 + 2][m0][0]);
    __syncthreads();

    int cur = 0;
    for (int t = 0; t < NT; ++t) {
        if (t + 1 < NT) {               // stage next tile into buf^1
            int k0 = (t + 1) << 5;
            g2l16(ga0 + k0,      &As[cur ^ 1][kc0    ][m0][0]);
            g2l16(ga0 + k0 + 16, &As[cur ^ 1][kc0 + 2][m0][0]);
            g2l16(gb0 + k0,      &Bs[cur ^ 1][kc0    ][m0][0]);
            g2l16(gb0 + k0 + 16, &Bs[cur ^ 1][kc0 + 2][m0][0]);
        }
        int kc = l >> 4;
        bf16x8 af[4], bfr[4];
        #pragma unroll
        for (int i = 0; i < 4; ++i)
            af[i] = *(const bf16x8*)&As[cur][kc][wr + i*16 + (l & 15)][0];
        #pragma unroll
        for (int j = 0; j < 4; ++j)
            bfr[j] = *(const bf16x8*)&Bs[cur][kc][wc + j*16 + (l & 15)][0];
        #pragma unroll
        for (int i = 0; i < 4; ++i)
            #pragma unroll
            for (int j = 0; j < 4; ++j)
                acc[i][j] = __builtin_amdgcn_mfma_f32_16x16x32_bf16(
                    af[i], bfr[j], acc[i][j], 0, 0, 0);
        __syncthreads();                // publish stage + WAR protect
        cur ^= 1;
    }

    #pragma unroll
    for (int i = 0; i < 4; ++i) {
        int rbase = row0 + wr + i*16 + (l >> 4) * 4;
        #pragma unroll
        for (int j = 0; j < 4; ++j) {
            int col = col0 + wc + j*16 + (l & 15);
            float bv = bias ? bias[col] : 0.f;
            #pragma unroll
            for (int r = 0; r < 4; ++r) {
                int row = rbase + r;
                float val = acc[i][j][r] + bv;
                if (resid) val += resid[(size_t)row * ldc + col];
                if (relu)  val = fmaxf(val, 0.f);
                if (OUT_BF16) ((ushort*)Cb)[(size_t)row * ldc + col] = f2bf(val);
                else          ((float*)Cb)[(size_t)row * ldc + col]  = val;
            }
        }
    }
}

// ---------------------------------------------------------------------------
// colsum[s] = sum_q exp(q·k/8).  grid (T/128, B*H), 256 thr.
// qkv packed [bt][3072]: q at col 0, k at 1024, v at 2048 (+h*64).
// ---------------------------------------------------------------------------
__global__ __launch_bounds__(256) void csum_kernel(
    const ushort* __restrict__ qkv, float* __restrict__ col_sum)
{
    int bh = blockIdx.y, b = bh >> 4, h = bh & 15;
    int s0 = blockIdx.x * 128;
    const ushort* qb = qkv + (size_t)b * T_ * 3072 + h * 64;
    const ushort* kb = qb + 1024;
    __shared__ __attribute__((aligned(16))) ushort Ks[8][128][8];
    __shared__ __attribute__((aligned(16))) ushort Qs[8][64][8];
    int tid = threadIdx.x, w = tid >> 6, l = tid & 63;
    int scol = w * 32;

    #pragma unroll
    for (int p = 0; p < 4; ++p) {
        int idx = tid + p * 256;
        int s = idx & 127, kc = idx >> 7;
        *(uint4*)&Ks[kc][s][0] =
            *(const uint4*)(kb + (size_t)(s0 + s) * 3072 + kc * 8);
    }
    float cs[2] = {0.f, 0.f};
    for (int qt = 0; qt < T_ / 64; ++qt) {
        __syncthreads();
        #pragma unroll
        for (int p = 0; p < 2; ++p) {
            int idx = tid + p * 256;
            int qq = idx & 63, kc = idx >> 6;
            *(uint4*)&Qs[kc][qq][0] =
                *(const uint4*)(qb + (size_t)(qt*64 + qq) * 3072 + kc * 8);
        }
        __syncthreads();
        bf16x8 af[4][2], bfr[2][2];
        #pragma unroll
        for (int qi = 0; qi < 4; ++qi)
            #pragma unroll
            for (int ks = 0; ks < 2; ++ks)
                af[qi][ks] = *(const bf16x8*)&Qs[ks*4 + (l>>4)][qi*16 + (l & 15)][0];
        #pragma unroll
        for (int sj = 0; sj < 2; ++sj)
            #pragma unroll
            for (int ks = 0; ks < 2; ++ks)
                bfr[sj][ks] = *(const bf16x8*)&Ks[ks*4 + (l>>4)][scol + sj*16 + (l & 15)][0];
        #pragma unroll
        for (int qi = 0; qi < 4; ++qi)
            #pragma unroll
            for (int sj = 0; sj < 2; ++sj) {
                f32x4 d = (f32x4){0.f, 0.f, 0.f, 0.f};
                #pragma unroll
                for (int ks = 0; ks < 2; ++ks)
                    d = __builtin_amdgcn_mfma_f32_16x16x32_bf16(
                        af[qi][ks], bfr[sj][ks], d, 0, 0, 0);
                cs[sj] += __expf(d[0]*0.125f) + __expf(d[1]*0.125f)
                        + __expf(d[2]*0.125f) + __expf(d[3]*0.125f);
            }
    }
    #pragma unroll
    for (int sj = 0; sj < 2; ++sj) {
        float v = cs[sj];
        v += __shfl_down(v, 32, 64);
        v += __shfl_down(v, 16, 64);
        if (l < 16)
            col_sum[(size_t)bh * T_ + s0 + scol + sj*16 + l] = v;
    }
}

// ---------------------------------------------------------------------------
// vt[bh][dv][s] = v[bh][s][dv] / colsum[bh][s]   (bf16, transposed V)
// ---------------------------------------------------------------------------
__global__ __launch_bounds__(256) void vscale_kernel(
    const ushort* __restrict__ qkv, const float* __restrict__ col_sum,
    ushort* __restrict__ vt)
{
    int bh = blockIdx.y, b = bh >> 4, h = bh & 15;
    int s0 = blockIdx.x * 64;
    const ushort* vb = qkv + (size_t)b * T_ * 3072 + 2048 + h * 64;
    __shared__ float t[64][65];
    int tid = threadIdx.x;
    #pragma unroll
    for (int p = 0; p < 2; ++p) {
        int idx = tid + p * 256;
        int s = idx >> 3, c0 = (idx & 7) * 8;
        uint4 raw = *(const uint4*)(vb + (size_t)(s0 + s) * 3072 + c0);
        float rc = 1.0f / col_sum[(size_t)bh * T_ + s0 + s];
        ushort* u = (ushort*)&raw;
        #pragma unroll
        for (int i = 0; i < 8; ++i) t[s][c0 + i] = bf2f(u[i]) * rc;
    }
    __syncthreads();
    #pragma unroll
    for (int p = 0; p < 2; ++p) {
        int idx = tid + p * 256;
        int dv = idx >> 3, sc = (idx & 7) * 8;
        ushort o[8];
        #pragma unroll
        for (int i = 0; i < 8; ++i) o[i] = f2bf(t[sc + i][dv]);
        *(uint4*)(vt + ((size_t)bh * 64 + dv) * T_ + s0 + sc) = *(uint4*)o;
    }
}

// ---------------------------------------------------------------------------
// PV: O[q][dv] = sum_s exp(q·k/8) * vt[dv][s].  grid (T/64, B*H), 256 thr.
// ---------------------------------------------------------------------------
__global__ __launch_bounds__(256) void attn_pv_kernel(
    const ushort* __restrict__ qkv, const ushort* __restrict__ vt,
    ushort* __restrict__ attn_o)
{
    int bh = blockIdx.y, b = bh >> 4, h = bh & 15;
    int q0 = blockIdx.x * 64;
    const ushort* qb = qkv + (size_t)b * T_ * 3072 + h * 64;
    const ushort* kb = qb + 1024;
    const ushort* vtb = vt + (size_t)bh * 64 * T_;
    __shared__ __attribute__((aligned(16))) ushort Qs[8][64][8];
    __shared__ __attribute__((aligned(16))) ushort Ks[8][64][8];
    __shared__ __attribute__((aligned(16))) ushort Vs[8][64][8];
    __shared__ __attribute__((aligned(16))) ushort Es[8][64][8];
    int tid = threadIdx.x, w = tid >> 6, l = tid & 63;
    int qw = w * 16;

    #pragma unroll
    for (int p = 0; p < 2; ++p) {
        int idx = tid + p * 256;
        int qq = idx & 63, kc = idx >> 6;
        *(uint4*)&Qs[kc][qq][0] =
            *(const uint4*)(qb + (size_t)(q0 + qq) * 3072 + kc * 8);
    }
    __syncthreads();
    bf16x8 qf[2];
    #pragma unroll
    for (int ks = 0; ks < 2; ++ks)
        qf[ks] = *(const bf16x8*)&Qs[ks*4 + (l>>4)][qw + (l & 15)][0];

    f32x4 oacc[4];
    #pragma unroll
    for (int j = 0; j < 4; ++j) oacc[j] = (f32x4){0.f, 0.f, 0.f, 0.f};

    for (int st = 0; st < T_ / 64; ++st) {
        int s0 = st * 64;
        __syncthreads();
        #pragma unroll
        for (int p = 0; p < 2; ++p) {
            int idx = tid + p * 256;
            int rr = idx & 63, kc = idx >> 6;
            *(uint4*)&Ks[kc][rr][0] =
                *(const uint4*)(kb + (size_t)(s0 + rr) * 3072 + kc * 8);
            *(uint4*)&Vs[kc][rr][0] =
                *(const uint4*)(vtb + (size_t)rr * T_ + s0 + kc * 8);
        }
        __syncthreads();
        #pragma unroll
        for (int sj = 0; sj < 4; ++sj) {
            f32x4 d = (f32x4){0.f, 0.f, 0.f, 0.f};
            #pragma unroll
            for (int ks = 0; ks < 2; ++ks) {
                bf16x8 kf = *(const bf16x8*)&Ks[ks*4 + (l>>4)][sj*16 + (l & 15)][0];
                d = __builtin_amdgcn_mfma_f32_16x16x32_bf16(qf[ks], kf, d, 0, 0, 0);
            }
            #pragma unroll
            for (int r = 0; r < 4; ++r) {
                int qq = qw + (l>>4)*4 + r;
                int ss = sj*16 + (l & 15);
                Es[ss >> 3][qq][ss & 7] = f2bf(__expf(d[r] * 0.125f));
            }
        }
        bf16x8 ef[2];
        #pragma unroll
        for (int ks = 0; ks < 2; ++ks)
            ef[ks] = *(const bf16x8*)&Es[ks*4 + (l>>4)][qw + (l & 15)][0];
        #pragma unroll
        for (int j = 0; j < 4; ++j)
            #pragma unroll
            for (int ks = 0; ks < 2; ++ks) {
                bf16x8 vf = *(const bf16x8*)&Vs[ks*4 + (l>>4)][j*16 + (l & 15)][0];
                oacc[j] = __builtin_amdgcn_mfma_f32_16x16x32_bf16(ef[ks], vf, oacc[j], 0, 0, 0);
            }
    }
    #pragma unroll
    for (int j = 0; j < 4; ++j)
        #pragma unroll
        for (int r = 0; r < 4; ++r) {
            int qq = q0 + qw + (l>>4)*4 + r;
            int dv = j*16 + (l & 15);
            attn_o[(size_t)(b*T_ + qq) * 1024 + h*64 + dv] = f2bf(oacc[j][r]);
        }
}

// ---------------------------------------------------------------------------
// fused norm: y = sum_{z<Z} parts[z] (bf16 partials) (+bias) + resid(f32),
// then mean/std norm (Bessel) -> outf (f32) and optional outb (bf16).
// ---------------------------------------------------------------------------
__device__ __forceinline__ float block_reduce_sum_256(float v, float* tmp)
{
    #pragma unroll
    for (int off = 32; off; off >>= 1) v += __shfl_down(v, off, 64);
    int lane = threadIdx.x & 63, w = threadIdx.x >> 6;
    __syncthreads();
    if (lane == 0) tmp[w] = v;
    __syncthreads();
    return tmp[0] + tmp[1] + tmp[2] + tmp[3];
}

template<int Z>
__global__ __launch_bounds__(256) void normZ_fused_kernel(
    const ushort* __restrict__ parts, long zoff,
    const float* __restrict__ bias, const float* __restrict__ resid,
    float* __restrict__ outf, ushort* __restrict__ outb)
{
    __shared__ float tmp[4];
    int row = blockIdx.x;
    int tid = threadIdx.x;
    int c0 = tid * 4;
    size_t idx = (size_t)row * D_ + c0;
    float vals[4] = {0.f, 0.f, 0.f, 0.f};
    #pragma unroll
    for (int z = 0; z < Z; ++z) {
        ushort4 p = *(const ushort4*)&parts[idx + (size_t)z * zoff];
        vals[0] += bf2f(p.x); vals[1] += bf2f(p.y);
        vals[2] += bf2f(p.z); vals[3] += bf2f(p.w);
    }
    float4 rv = *(const float4*)&resid[idx];
    vals[0] += rv.x; vals[1] += rv.y; vals[2] += rv.z; vals[3] += rv.w;
    if (bias) {
        float4 bv = *(const float4*)&bias[c0];
        vals[0] += bv.x; vals[1] += bv.y; vals[2] += bv.z; vals[3] += bv.w;
    }
    float s = vals[0] + vals[1] + vals[2] + vals[3];
    s = block_reduce_sum_256(s, tmp);
    float m = s * (1.0f / (float)D_);
    float sq = 0.f;
    #pragma unroll
    for (int i = 0; i < 4; ++i) { float c = vals[i] - m; sq += c * c; }
    sq = block_reduce_sum_256(sq, tmp);
    float rs = rsqrtf(sq * (1.0f / (float)(D_ - 1)));
    float4 o;
    o.x = (vals[0] - m) * rs; o.y = (vals[1] - m) * rs;
    o.z = (vals[2] - m) * rs; o.w = (vals[3] - m) * rs;
    *(float4*)&outf[idx] = o;
    if (outb) {
        ushort4 ob;
        ob.x = f2bf(o.x); ob.y = f2bf(o.y); ob.z = f2bf(o.z); ob.w = f2bf(o.w);
        *(ushort4*)&outb[idx] = ob;
    }
}

// ---------------------------------------------------------------------------
extern "C" void kernel_launch(void* const* d_in, const int* in_sizes, int n_in,
                              void* d_out, int out_size, void* d_ws, size_t ws_size,
                              hipStream_t stream)
{
    const float* x  = (const float*)d_in[0];
    const float* Wq = (const float*)d_in[1];
    const float* Wk = (const float*)d_in[2];
    const float* Wv = (const float*)d_in[3];
    const float* Wo = (const float*)d_in[4];
    const float* W1 = (const float*)d_in[5];
    const float* b1 = (const float*)d_in[6];
    const float* W2 = (const float*)d_in[7];
    const float* b2 = (const float*)d_in[8];
    float* out = (float*)d_out;

    const size_t MB = (size_t)1 << 20;
    char* base = (char*)d_ws;
    // lifetimes (peak ~113MB):
    ushort* qkv    = (ushort*)(base +   0*MB);  // 24MB  [QKV..PV]
    ushort* hid    = (ushort*)(base +   0*MB);  // 32MB  [W1..W2]     (reuses qkv+xb)
    ushort* xb     = (ushort*)(base +  24*MB);  //  8MB  [cvt..QKV]
    ushort* W2t    = (ushort*)(base +  32*MB);  //  8MB  [cvt..W2]
    ushort* Wqkvt  = (ushort*)(base +  40*MB);  //  6MB  [cvt..QKV]
    ushort* wpart  = (ushort*)(base +  40*MB);  // 32MB  [W2..norm2]  (reuses 40-72)
    ushort* vt     = (ushort*)(base +  46*MB);  //  8MB  [vscale..PV]
    float*  csum   = (float*) (base +  54*MB);  // .25MB [csum..vscale]
    ushort* Wot    = (ushort*)(base +  55*MB);  //  2MB  [cvt..Wo]
    ushort* W1t    = (ushort*)(base +  57*MB);  //  8MB  [cvt..W1]
    ushort* attn_o = (ushort*)(base +  65*MB);  //  8MB  [PV..Wo]
    ushort* wopart = (ushort*)(base +  73*MB);  // 16MB  [Wo..norm1]  (2x bf16 partials)
    ushort* out1b  = (ushort*)(base +  89*MB);  //  8MB  [norm1..W1]
    float*  out1f  = (float*) (base +  97*MB);  // 16MB  [norm1..norm2]

    // 1. converts / transposes
    cvt_bf16_kernel<<<dim3(BT_*D_/1024), 256, 0, stream>>>(x, xb, BT_*D_);
    transpose_bf16_kernel<<<dim3(2, 32, 16), 256, 0, stream>>>(
        Wq, Wqkvt + 0*1048576, 1024, 64, 65536, 65536);
    transpose_bf16_kernel<<<dim3(2, 32, 16), 256, 0, stream>>>(
        Wk, Wqkvt + 1*1048576, 1024, 64, 65536, 65536);
    transpose_bf16_kernel<<<dim3(2, 32, 16), 256, 0, stream>>>(
        Wv, Wqkvt + 2*1048576, 1024, 64, 65536, 65536);
    transpose_bf16_kernel<<<dim3(32, 32, 1), 256, 0, stream>>>(
        Wo, Wot, 1024, 1024, 0, 0);
    transpose_bf16_kernel<<<dim3(128, 32, 1), 256, 0, stream>>>(
        W1, W1t, 1024, 4096, 0, 0);
    transpose_bf16_kernel<<<dim3(32, 128, 1), 256, 0, stream>>>(
        W2, W2t, 4096, 1024, 0, 0);

    // 2. QKV: [4096,1024]@[3072,1024]^T -> qkv. 768 blocks = 3/CU.
    gemm_nt_kernel<1><<<dim3(3072/128, 4096/128, 1), 256, 0, stream>>>(
        xb, 1024, Wqkvt, 1024, qkv, 3072, 1024, nullptr, nullptr, 0, 0, 0, 0);
    // 3. column sums of exp(scores)
    csum_kernel<<<dim3(T_/128, B_*H_), 256, 0, stream>>>(qkv, csum);
    // 4. vt = (v/colsum)^T
    vscale_kernel<<<dim3(T_/64, B_*H_), 256, 0, stream>>>(qkv, csum, vt);
    // 5. PV
    attn_pv_kernel<<<dim3(T_/64, B_*H_), 256, 0, stream>>>(qkv, vt, attn_o);
    // 6. Wo split-K2 -> bf16 partials wopart[z][4096][1024]. 512 blocks = 2/CU.
    gemm_nt_kernel<1><<<dim3(1024/128, 4096/128, 2), 256, 0, stream>>>(
        attn_o, 1024, Wot, 1024, wopart, 1024, 512, nullptr, nullptr, 0,
        512, 512, (long)4096*1024);
    // 7. norm1 fused: sum 2 partials + x resid -> norm -> out1f + out1b
    normZ_fused_kernel<2><<<dim3(BT_), 256, 0, stream>>>(
        wopart, (long)4096*1024, nullptr, x, out1f, out1b);
    // 8. FFN up + ReLU -> hid. 1024 blocks = 4/CU.
    gemm_nt_kernel<1><<<dim3(4096/128, 4096/128, 1), 256, 0, stream>>>(
        out1b, 1024, W1t, 1024, hid, 4096, 1024, b1, nullptr, 1, 0, 0, 0);
    // 9. FFN down split-K4 -> bf16 partials wpart[z][4096][1024]. 1024 blocks.
    gemm_nt_kernel<1><<<dim3(1024/128, 4096/128, 4), 256, 0, stream>>>(
        hid, 4096, W2t, 4096, wpart, 1024, 1024, nullptr, nullptr, 0,
        1024, 1024, (long)4096*1024);
    // 10. norm2 fused: sum 4 partials + b2 + out1 resid -> norm -> out
    normZ_fused_kernel<4><<<dim3(BT_), 256, 0, stream>>>(
        wpart, (long)4096*1024, b2, out1f, out, nullptr);
}

// Round 10
// 390.670 us; speedup vs baseline: 1.2761x; 1.1260x over previous
//
#include <hip/hip_runtime.h>
#include <hip/hip_bf16.h>
#include <math.h>

#define B_  2
#define T_  2048
#define D_  1024
#define H_  16
#define DK_ 64
#define FF_ 4096
#define BT_ (B_*T_)

typedef __attribute__((ext_vector_type(8))) short bf16x8;
typedef __attribute__((ext_vector_type(4))) float f32x4;

__device__ __forceinline__ ushort f2bf(float f) {
    __hip_bfloat16 h = __float2bfloat16(f);
    return *reinterpret_cast<ushort*>(&h);
}
__device__ __forceinline__ float bf2f(ushort u) {
    __hip_bfloat16 h;
    *reinterpret_cast<ushort*>(&h) = u;
    return __bfloat162float(h);
}

// async global->LDS, 16B per lane. LDS dest must be wave-uniform base + lane*16.
__device__ __forceinline__ void g2l16(const ushort* g, ushort* l) {
    __builtin_amdgcn_global_load_lds(
        (const __attribute__((address_space(1))) void*)g,
        (__attribute__((address_space(3))) void*)l, 16, 0, 0);
}

// ---------------------------------------------------------------------------
// f32 -> bf16 elementwise
// ---------------------------------------------------------------------------
__global__ __launch_bounds__(256) void cvt_bf16_kernel(
    const float* __restrict__ in, ushort* __restrict__ out, int n)
{
    int i = (blockIdx.x * 256 + threadIdx.x) * 4;
    if (i >= n) return;
    float4 v = *(const float4*)(in + i);
    ushort4 o;
    o.x = f2bf(v.x); o.y = f2bf(v.y); o.z = f2bf(v.z); o.w = f2bf(v.w);
    *(ushort4*)(out + i) = o;
}

// ---------------------------------------------------------------------------
// transpose + convert: in f32 [K][N] -> out bf16 [N][K]; batched over z.
// ---------------------------------------------------------------------------
__global__ __launch_bounds__(256) void transpose_bf16_kernel(
    const float* __restrict__ in, ushort* __restrict__ out,
    int K, int N, long in_bstride, long out_bstride)
{
    __shared__ float t[32][33];
    const float* ib = in + (size_t)blockIdx.z * in_bstride;
    ushort* ob = out + (size_t)blockIdx.z * out_bstride;
    int n0 = blockIdx.x * 32, k0 = blockIdx.y * 32;
    int tid = threadIdx.x;
    int r = tid >> 3, c4 = (tid & 7) * 4;
    float4 v = *(const float4*)(ib + (size_t)(k0 + r) * N + n0 + c4);
    t[r][c4] = v.x; t[r][c4+1] = v.y; t[r][c4+2] = v.z; t[r][c4+3] = v.w;
    __syncthreads();
    int n = tid >> 3, kc = (tid & 7) * 4;
    ushort4 o;
    o.x = f2bf(t[kc+0][n]); o.y = f2bf(t[kc+1][n]);
    o.z = f2bf(t[kc+2][n]); o.w = f2bf(t[kc+3][n]);
    *(ushort4*)(ob + (size_t)(n0 + n) * K + k0 + kc) = o;
}

// ---------------------------------------------------------------------------
// WIDE 128(M)x256(N) NT GEMM, bf16 MFMA, BK=32, 256 thr (4 waves of 64x128).
// 2-phase dbuf, 48KB LDS. 32 MFMA/wave/K-tile: doubles compute per barrier
// vs 128^2 to amortize the measured per-block fixed cost (R9 F-model).
// ---------------------------------------------------------------------------
template<int OUT_BF16>
__global__ __launch_bounds__(256, 2) void gemm_ntw_kernel(
    const ushort* __restrict__ A, int lda,
    const ushort* __restrict__ Bt, int ldb,
    void* __restrict__ C, int ldc, int K,
    const float* __restrict__ bias,
    const float* __restrict__ resid, int relu)
{
    __shared__ __attribute__((aligned(16))) ushort As[2][4][128][8];
    __shared__ __attribute__((aligned(16))) ushort Bs[2][4][256][8];

    int nwg  = gridDim.x * gridDim.y;
    int orig = blockIdx.y * gridDim.x + blockIdx.x;
    int work = (orig & 7) * (nwg >> 3) + (orig >> 3);
    int bx = work % gridDim.x, by = work / gridDim.x;

    int row0 = by * 128, col0 = bx * 256;
    int tid = threadIdx.x;
    int w = tid >> 6, l = tid & 63;
    int wr = (w >> 1) * 64, wc = (w & 1) * 128;

    int m0 = tid & 127, kc0 = tid >> 7;          // A: kc0 in {0,1}
    const ushort* gA = A  + (size_t)(row0 + m0) * lda + kc0 * 8;
    const ushort* gB = Bt + (size_t)(col0 + tid) * ldb;   // B: m = tid, kc = p

    f32x4 acc[4][8];
    #pragma unroll
    for (int i = 0; i < 4; ++i)
        #pragma unroll
        for (int j = 0; j < 8; ++j) acc[i][j] = (f32x4){0.f, 0.f, 0.f, 0.f};

    const int NT = K >> 5;
    // prologue: tile 0 -> buf 0 (A: 2 loads, B: 4 loads per thread)
    g2l16(gA,      &As[0][kc0    ][m0][0]);
    g2l16(gA + 16, &As[0][kc0 + 2][m0][0]);
    #pragma unroll
    for (int p = 0; p < 4; ++p)
        g2l16(gB + p*8, &Bs[0][p][tid][0]);
    __syncthreads();

    int cur = 0;
    for (int t = 0; t < NT; ++t) {
        if (t + 1 < NT) {
            int k0 = (t + 1) << 5;
            g2l16(gA + k0,      &As[cur ^ 1][kc0    ][m0][0]);
            g2l16(gA + k0 + 16, &As[cur ^ 1][kc0 + 2][m0][0]);
            #pragma unroll
            for (int p = 0; p < 4; ++p)
                g2l16(gB + k0 + p*8, &Bs[cur ^ 1][p][tid][0]);
        }
        int kc = l >> 4;
        bf16x8 bfr[8];
        #pragma unroll
        for (int j = 0; j < 8; ++j)
            bfr[j] = *(const bf16x8*)&Bs[cur][kc][wc + j*16 + (l & 15)][0];
        #pragma unroll
        for (int i = 0; i < 4; ++i) {
            bf16x8 a = *(const bf16x8*)&As[cur][kc][wr + i*16 + (l & 15)][0];
            #pragma unroll
            for (int j = 0; j < 8; ++j)
                acc[i][j] = __builtin_amdgcn_mfma_f32_16x16x32_bf16(
                    a, bfr[j], acc[i][j], 0, 0, 0);
        }
        __syncthreads();
        cur ^= 1;
    }

    #pragma unroll
    for (int i = 0; i < 4; ++i) {
        int rbase = row0 + wr + i*16 + (l >> 4) * 4;
        #pragma unroll
        for (int j = 0; j < 8; ++j) {
            int col = col0 + wc + j*16 + (l & 15);
            float bv = bias ? bias[col] : 0.f;
            #pragma unroll
            for (int r = 0; r < 4; ++r) {
                int row = rbase + r;
                float val = acc[i][j][r] + bv;
                if (resid) val += resid[(size_t)row * ldc + col];
                if (relu)  val = fmaxf(val, 0.f);
                if (OUT_BF16) ((ushort*)C)[(size_t)row * ldc + col] = f2bf(val);
                else          ((float*)C)[(size_t)row * ldc + col]  = val;
            }
        }
    }
}

// ---------------------------------------------------------------------------
// 128x128 NT GEMM, BK=32, 2-phase dbuf, 32KB LDS, split-K via blockIdx.z.
// Used for Wo (split2) and W2 (split2) where N=1024 limits the wide tile.
// ---------------------------------------------------------------------------
template<int OUT_BF16>
__global__ __launch_bounds__(256) void gemm_nt_kernel(
    const ushort* __restrict__ A, int lda,
    const ushort* __restrict__ Bt, int ldb,
    void* __restrict__ C, int ldc, int K,
    const float* __restrict__ bias,
    const float* __restrict__ resid, int relu,
    long aZoff, long bZoff, long cZoff)
{
    __shared__ __attribute__((aligned(16))) ushort As[2][4][128][8];
    __shared__ __attribute__((aligned(16))) ushort Bs[2][4][128][8];

    A  += (size_t)blockIdx.z * aZoff;
    Bt += (size_t)blockIdx.z * bZoff;
    char* Cb = (char*)C + (size_t)blockIdx.z * cZoff * (OUT_BF16 ? 2 : 4);

    int nwg  = gridDim.x * gridDim.y;
    int orig = blockIdx.y * gridDim.x + blockIdx.x;
    int work = (orig & 7) * (nwg >> 3) + (orig >> 3);
    int bx = work % gridDim.x, by = work / gridDim.x;

    int row0 = by * 128, col0 = bx * 128;
    int tid = threadIdx.x;
    int w = tid >> 6, l = tid & 63;
    int wr = (w >> 1) * 64, wc = (w & 1) * 64;

    int m0 = tid & 127, kc0 = tid >> 7;
    const ushort* ga0 = A  + (size_t)(row0 + m0) * lda + kc0 * 8;
    const ushort* gb0 = Bt + (size_t)(col0 + m0) * ldb + kc0 * 8;

    f32x4 acc[4][4];
    #pragma unroll
    for (int i = 0; i < 4; ++i)
        #pragma unroll
        for (int j = 0; j < 4; ++j) acc[i][j] = (f32x4){0.f, 0.f, 0.f, 0.f};

    const int NT = K >> 5;
    g2l16(ga0,      &As[0][kc0    ][m0][0]);
    g2l16(ga0 + 16, &As[0][kc0 + 2][m0][0]);
    g2l16(gb0,      &Bs[0][kc0    ][m0][0]);
    g2l16(gb0 + 16, &Bs[0][kc0 + 2][m0][0]);
    __syncthreads();

    int cur = 0;
    for (int t = 0; t < NT; ++t) {
        if (t + 1 < NT) {
            int k0 = (t + 1) << 5;
            g2l16(ga0 + k0,      &As[cur ^ 1][kc0    ][m0][0]);
            g2l16(ga0 + k0 + 16, &As[cur ^ 1][kc0 + 2][m0][0]);
            g2l16(gb0 + k0,      &Bs[cur ^ 1][kc0    ][m0][0]);
            g2l16(gb0 + k0 + 16, &Bs[cur ^ 1][kc0 + 2][m0][0]);
        }
        int kc = l >> 4;
        bf16x8 af[4], bfr[4];
        #pragma unroll
        for (int i = 0; i < 4; ++i)
            af[i] = *(const bf16x8*)&As[cur][kc][wr + i*16 + (l & 15)][0];
        #pragma unroll
        for (int j = 0; j < 4; ++j)
            bfr[j] = *(const bf16x8*)&Bs[cur][kc][wc + j*16 + (l & 15)][0];
        #pragma unroll
        for (int i = 0; i < 4; ++i)
            #pragma unroll
            for (int j = 0; j < 4; ++j)
                acc[i][j] = __builtin_amdgcn_mfma_f32_16x16x32_bf16(
                    af[i], bfr[j], acc[i][j], 0, 0, 0);
        __syncthreads();
        cur ^= 1;
    }

    #pragma unroll
    for (int i = 0; i < 4; ++i) {
        int rbase = row0 + wr + i*16 + (l >> 4) * 4;
        #pragma unroll
        for (int j = 0; j < 4; ++j) {
            int col = col0 + wc + j*16 + (l & 15);
            float bv = bias ? bias[col] : 0.f;
            #pragma unroll
            for (int r = 0; r < 4; ++r) {
                int row = rbase + r;
                float val = acc[i][j][r] + bv;
                if (resid) val += resid[(size_t)row * ldc + col];
                if (relu)  val = fmaxf(val, 0.f);
                if (OUT_BF16) ((ushort*)Cb)[(size_t)row * ldc + col] = f2bf(val);
                else          ((float*)Cb)[(size_t)row * ldc + col]  = val;
            }
        }
    }
}

// ---------------------------------------------------------------------------
// csum + vscale fused: per s-tile of 128, compute colsum[s] = sum_q exp(qk/8)
// (kept in LDS), then scale+transpose this block's V rows -> vt.
// grid (T/128, B*H), 256 thr.
// ---------------------------------------------------------------------------
__global__ __launch_bounds__(256) void csumv_kernel(
    const ushort* __restrict__ qkv, ushort* __restrict__ vt)
{
    int bh = blockIdx.y, b = bh >> 4, h = bh & 15;
    int s0 = blockIdx.x * 128;
    const ushort* qb = qkv + (size_t)b * T_ * 3072 + h * 64;
    const ushort* kb = qb + 1024;
    const ushort* vb = qb + 2048;
    __shared__ __attribute__((aligned(16))) ushort Ks[8][128][8];
    __shared__ __attribute__((aligned(16))) ushort Qs[8][64][8];
    __shared__ float csl[128];
    __shared__ float t[64][65];
    int tid = threadIdx.x, w = tid >> 6, l = tid & 63;
    int scol = w * 32;

    #pragma unroll
    for (int p = 0; p < 4; ++p) {
        int idx = tid + p * 256;
        int s = idx & 127, kc = idx >> 7;
        *(uint4*)&Ks[kc][s][0] =
            *(const uint4*)(kb + (size_t)(s0 + s) * 3072 + kc * 8);
    }
    float cs[2] = {0.f, 0.f};
    for (int qt = 0; qt < T_ / 64; ++qt) {
        __syncthreads();
        #pragma unroll
        for (int p = 0; p < 2; ++p) {
            int idx = tid + p * 256;
            int qq = idx & 63, kc = idx >> 6;
            *(uint4*)&Qs[kc][qq][0] =
                *(const uint4*)(qb + (size_t)(qt*64 + qq) * 3072 + kc * 8);
        }
        __syncthreads();
        bf16x8 af[4][2], bfr[2][2];
        #pragma unroll
        for (int qi = 0; qi < 4; ++qi)
            #pragma unroll
            for (int ks = 0; ks < 2; ++ks)
                af[qi][ks] = *(const bf16x8*)&Qs[ks*4 + (l>>4)][qi*16 + (l & 15)][0];
        #pragma unroll
        for (int sj = 0; sj < 2; ++sj)
            #pragma unroll
            for (int ks = 0; ks < 2; ++ks)
                bfr[sj][ks] = *(const bf16x8*)&Ks[ks*4 + (l>>4)][scol + sj*16 + (l & 15)][0];
        #pragma unroll
        for (int qi = 0; qi < 4; ++qi)
            #pragma unroll
            for (int sj = 0; sj < 2; ++sj) {
                f32x4 d = (f32x4){0.f, 0.f, 0.f, 0.f};
                #pragma unroll
                for (int ks = 0; ks < 2; ++ks)
                    d = __builtin_amdgcn_mfma_f32_16x16x32_bf16(
                        af[qi][ks], bfr[sj][ks], d, 0, 0, 0);
                cs[sj] += __expf(d[0]*0.125f) + __expf(d[1]*0.125f)
                        + __expf(d[2]*0.125f) + __expf(d[3]*0.125f);
            }
    }
    #pragma unroll
    for (int sj = 0; sj < 2; ++sj) {
        float v = cs[sj];
        v += __shfl_down(v, 32, 64);
        v += __shfl_down(v, 16, 64);
        if (l < 16) csl[scol + sj*16 + l] = v;
    }
    __syncthreads();

    // scale + transpose V rows [s0, s0+128) -> vt[bh][dv][s]
    #pragma unroll
    for (int p2 = 0; p2 < 2; ++p2) {
        int sb = s0 + p2 * 64;
        #pragma unroll
        for (int p = 0; p < 2; ++p) {
            int idx = tid + p * 256;
            int s = idx >> 3, c0 = (idx & 7) * 8;
            uint4 raw = *(const uint4*)(vb + (size_t)(sb + s) * 3072 + c0);
            float rc = 1.0f / csl[p2 * 64 + s];
            ushort* u = (ushort*)&raw;
            #pragma unroll
            for (int i = 0; i < 8; ++i) t[s][c0 + i] = bf2f(u[i]) * rc;
        }
        __syncthreads();
        #pragma unroll
        for (int p = 0; p < 2; ++p) {
            int idx = tid + p * 256;
            int dv = idx >> 3, sc = (idx & 7) * 8;
            ushort o[8];
            #pragma unroll
            for (int i = 0; i < 8; ++i) o[i] = f2bf(t[sc + i][dv]);
            *(uint4*)(vt + ((size_t)bh * 64 + dv) * T_ + sb + sc) = *(uint4*)o;
        }
        __syncthreads();
    }
}

// ---------------------------------------------------------------------------
// PV: O[q][dv] = sum_s exp(q·k/8) * vt[dv][s].  grid (T/64, B*H), 256 thr.
// ---------------------------------------------------------------------------
__global__ __launch_bounds__(256) void attn_pv_kernel(
    const ushort* __restrict__ qkv, const ushort* __restrict__ vt,
    ushort* __restrict__ attn_o)
{
    int bh = blockIdx.y, b = bh >> 4, h = bh & 15;
    int q0 = blockIdx.x * 64;
    const ushort* qb = qkv + (size_t)b * T_ * 3072 + h * 64;
    const ushort* kb = qb + 1024;
    const ushort* vtb = vt + (size_t)bh * 64 * T_;
    __shared__ __attribute__((aligned(16))) ushort Qs[8][64][8];
    __shared__ __attribute__((aligned(16))) ushort Ks[8][64][8];
    __shared__ __attribute__((aligned(16))) ushort Vs[8][64][8];
    __shared__ __attribute__((aligned(16))) ushort Es[8][64][8];
    int tid = threadIdx.x, w = tid >> 6, l = tid & 63;
    int qw = w * 16;

    #pragma unroll
    for (int p = 0; p < 2; ++p) {
        int idx = tid + p * 256;
        int qq = idx & 63, kc = idx >> 6;
        *(uint4*)&Qs[kc][qq][0] =
            *(const uint4*)(qb + (size_t)(q0 + qq) * 3072 + kc * 8);
    }
    __syncthreads();
    bf16x8 qf[2];
    #pragma unroll
    for (int ks = 0; ks < 2; ++ks)
        qf[ks] = *(const bf16x8*)&Qs[ks*4 + (l>>4)][qw + (l & 15)][0];

    f32x4 oacc[4];
    #pragma unroll
    for (int j = 0; j < 4; ++j) oacc[j] = (f32x4){0.f, 0.f, 0.f, 0.f};

    for (int st = 0; st < T_ / 64; ++st) {
        int s0 = st * 64;
        __syncthreads();
        #pragma unroll
        for (int p = 0; p < 2; ++p) {
            int idx = tid + p * 256;
            int rr = idx & 63, kc = idx >> 6;
            *(uint4*)&Ks[kc][rr][0] =
                *(const uint4*)(kb + (size_t)(s0 + rr) * 3072 + kc * 8);
            *(uint4*)&Vs[kc][rr][0] =
                *(const uint4*)(vtb + (size_t)rr * T_ + s0 + kc * 8);
        }
        __syncthreads();
        #pragma unroll
        for (int sj = 0; sj < 4; ++sj) {
            f32x4 d = (f32x4){0.f, 0.f, 0.f, 0.f};
            #pragma unroll
            for (int ks = 0; ks < 2; ++ks) {
                bf16x8 kf = *(const bf16x8*)&Ks[ks*4 + (l>>4)][sj*16 + (l & 15)][0];
                d = __builtin_amdgcn_mfma_f32_16x16x32_bf16(qf[ks], kf, d, 0, 0, 0);
            }
            #pragma unroll
            for (int r = 0; r < 4; ++r) {
                int qq = qw + (l>>4)*4 + r;
                int ss = sj*16 + (l & 15);
                Es[ss >> 3][qq][ss & 7] = f2bf(__expf(d[r] * 0.125f));
            }
        }
        bf16x8 ef[2];
        #pragma unroll
        for (int ks = 0; ks < 2; ++ks)
            ef[ks] = *(const bf16x8*)&Es[ks*4 + (l>>4)][qw + (l & 15)][0];
        #pragma unroll
        for (int j = 0; j < 4; ++j)
            #pragma unroll
            for (int ks = 0; ks < 2; ++ks) {
                bf16x8 vf = *(const bf16x8*)&Vs[ks*4 + (l>>4)][j*16 + (l & 15)][0];
                oacc[j] = __builtin_amdgcn_mfma_f32_16x16x32_bf16(ef[ks], vf, oacc[j], 0, 0, 0);
            }
    }
    #pragma unroll
    for (int j = 0; j < 4; ++j)
        #pragma unroll
        for (int r = 0; r < 4; ++r) {
            int qq = q0 + qw + (l>>4)*4 + r;
            int dv = j*16 + (l & 15);
            attn_o[(size_t)(b*T_ + qq) * 1024 + h*64 + dv] = f2bf(oacc[j][r]);
        }
}

// ---------------------------------------------------------------------------
// fused norm: y = sum_{z<Z} parts[z] (bf16 partials) (+bias) + resid(f32),
// then mean/std norm (Bessel) -> outf (f32) and optional outb (bf16).
// ---------------------------------------------------------------------------
__device__ __forceinline__ float block_reduce_sum_256(float v, float* tmp)
{
    #pragma unroll
    for (int off = 32; off; off >>= 1) v += __shfl_down(v, off, 64);
    int lane = threadIdx.x & 63, w = threadIdx.x >> 6;
    __syncthreads();
    if (lane == 0) tmp[w] = v;
    __syncthreads();
    return tmp[0] + tmp[1] + tmp[2] + tmp[3];
}

template<int Z>
__global__ __launch_bounds__(256) void normZ_fused_kernel(
    const ushort* __restrict__ parts, long zoff,
    const float* __restrict__ bias, const float* __restrict__ resid,
    float* __restrict__ outf, ushort* __restrict__ outb)
{
    __shared__ float tmp[4];
    int row = blockIdx.x;
    int tid = threadIdx.x;
    int c0 = tid * 4;
    size_t idx = (size_t)row * D_ + c0;
    float vals[4] = {0.f, 0.f, 0.f, 0.f};
    #pragma unroll
    for (int z = 0; z < Z; ++z) {
        ushort4 p = *(const ushort4*)&parts[idx + (size_t)z * zoff];
        vals[0] += bf2f(p.x); vals[1] += bf2f(p.y);
        vals[2] += bf2f(p.z); vals[3] += bf2f(p.w);
    }
    float4 rv = *(const float4*)&resid[idx];
    vals[0] += rv.x; vals[1] += rv.y; vals[2] += rv.z; vals[3] += rv.w;
    if (bias) {
        float4 bv = *(const float4*)&bias[c0];
        vals[0] += bv.x; vals[1] += bv.y; vals[2] += bv.z; vals[3] += bv.w;
    }
    float s = vals[0] + vals[1] + vals[2] + vals[3];
    s = block_reduce_sum_256(s, tmp);
    float m = s * (1.0f / (float)D_);
    float sq = 0.f;
    #pragma unroll
    for (int i = 0; i < 4; ++i) { float c = vals[i] - m; sq += c * c; }
    sq = block_reduce_sum_256(sq, tmp);
    float rs = rsqrtf(sq * (1.0f / (float)(D_ - 1)));
    float4 o;
    o.x = (vals[0] - m) * rs; o.y = (vals[1] - m) * rs;
    o.z = (vals[2] - m) * rs; o.w = (vals[3] - m) * rs;
    *(float4*)&outf[idx] = o;
    if (outb) {
        ushort4 ob;
        ob.x = f2bf(o.x); ob.y = f2bf(o.y); ob.z = f2bf(o.z); ob.w = f2bf(o.w);
        *(ushort4*)&outb[idx] = ob;
    }
}

// ---------------------------------------------------------------------------
extern "C" void kernel_launch(void* const* d_in, const int* in_sizes, int n_in,
                              void* d_out, int out_size, void* d_ws, size_t ws_size,
                              hipStream_t stream)
{
    const float* x  = (const float*)d_in[0];
    const float* Wq = (const float*)d_in[1];
    const float* Wk = (const float*)d_in[2];
    const float* Wv = (const float*)d_in[3];
    const float* Wo = (const float*)d_in[4];
    const float* W1 = (const float*)d_in[5];
    const float* b1 = (const float*)d_in[6];
    const float* W2 = (const float*)d_in[7];
    const float* b2 = (const float*)d_in[8];
    float* out = (float*)d_out;

    const size_t MB = (size_t)1 << 20;
    char* base = (char*)d_ws;
    // lifetimes (peak ~113MB):
    ushort* qkv    = (ushort*)(base +   0*MB);  // 24MB  [QKV..PV]
    ushort* hid    = (ushort*)(base +   0*MB);  // 32MB  [W1..W2]     (reuses qkv+xb)
    ushort* xb     = (ushort*)(base +  24*MB);  //  8MB  [cvt..QKV]
    ushort* W2t    = (ushort*)(base +  32*MB);  //  8MB  [cvt..W2]
    ushort* Wqkvt  = (ushort*)(base +  40*MB);  //  6MB  [cvt..QKV]
    ushort* wpart  = (ushort*)(base +  40*MB);  // 16MB  [W2..norm2]  (reuses 40-56)
    ushort* vt     = (ushort*)(base +  46*MB);  //  8MB  [csumv..PV]  (dead before W2)
    ushort* Wot    = (ushort*)(base +  55*MB);  //  2MB  [cvt..Wo]
    ushort* W1t    = (ushort*)(base +  57*MB);  //  8MB  [cvt..W1]
    ushort* attn_o = (ushort*)(base +  65*MB);  //  8MB  [PV..Wo]
    ushort* wopart = (ushort*)(base +  73*MB);  // 16MB  [Wo..norm1]  (2x bf16 partials)
    ushort* out1b  = (ushort*)(base +  89*MB);  //  8MB  [norm1..W1]
    float*  out1f  = (float*) (base +  97*MB);  // 16MB  [norm1..norm2]

    // 1. converts / transposes
    cvt_bf16_kernel<<<dim3(BT_*D_/1024), 256, 0, stream>>>(x, xb, BT_*D_);
    transpose_bf16_kernel<<<dim3(2, 32, 16), 256, 0, stream>>>(
        Wq, Wqkvt + 0*1048576, 1024, 64, 65536, 65536);
    transpose_bf16_kernel<<<dim3(2, 32, 16), 256, 0, stream>>>(
        Wk, Wqkvt + 1*1048576, 1024, 64, 65536, 65536);
    transpose_bf16_kernel<<<dim3(2, 32, 16), 256, 0, stream>>>(
        Wv, Wqkvt + 2*1048576, 1024, 64, 65536, 65536);
    transpose_bf16_kernel<<<dim3(32, 32, 1), 256, 0, stream>>>(
        Wo, Wot, 1024, 1024, 0, 0);
    transpose_bf16_kernel<<<dim3(128, 32, 1), 256, 0, stream>>>(
        W1, W1t, 1024, 4096, 0, 0);
    transpose_bf16_kernel<<<dim3(32, 128, 1), 256, 0, stream>>>(
        W2, W2t, 4096, 1024, 0, 0);

    // 2. QKV: wide tile, 384 blocks.
    gemm_ntw_kernel<1><<<dim3(3072/256, 4096/128), 256, 0, stream>>>(
        xb, 1024, Wqkvt, 1024, qkv, 3072, 1024, nullptr, nullptr, 0);
    // 3. colsum + V-scale/transpose fused
    csumv_kernel<<<dim3(T_/128, B_*H_), 256, 0, stream>>>(qkv, vt);
    // 4. PV
    attn_pv_kernel<<<dim3(T_/64, B_*H_), 256, 0, stream>>>(qkv, vt, attn_o);
    // 5. Wo split-K2 -> bf16 partials. 512 blocks.
    gemm_nt_kernel<1><<<dim3(1024/128, 4096/128, 2), 256, 0, stream>>>(
        attn_o, 1024, Wot, 1024, wopart, 1024, 512, nullptr, nullptr, 0,
        512, 512, (long)4096*1024);
    // 6. norm1 fused: sum 2 partials + x resid -> out1f + out1b
    normZ_fused_kernel<2><<<dim3(BT_), 256, 0, stream>>>(
        wopart, (long)4096*1024, nullptr, x, out1f, out1b);
    // 7. FFN up + ReLU: wide tile, 512 blocks.
    gemm_ntw_kernel<1><<<dim3(4096/256, 4096/128), 256, 0, stream>>>(
        out1b, 1024, W1t, 1024, hid, 4096, 1024, b1, nullptr, 1);
    // 8. FFN down split-K2 -> bf16 partials. 512 blocks, NT=64.
    gemm_nt_kernel<1><<<dim3(1024/128, 4096/128, 2), 256, 0, stream>>>(
        hid, 4096, W2t, 4096, wpart, 1024, 2048, nullptr, nullptr, 0,
        2048, 2048, (long)4096*1024);
    // 9. norm2 fused: sum 2 partials + b2 + out1 resid -> out
    normZ_fused_kernel<2><<<dim3(BT_), 256, 0, stream>>>(
        wpart, (long)4096*1024, b2, out1f, out, nullptr);
}

// Round 11
// 390.650 us; speedup vs baseline: 1.2762x; 1.0001x over previous
//
#include <hip/hip_runtime.h>
#include <hip/hip_bf16.h>
#include <math.h>

#define B_  2
#define T_  2048
#define D_  1024
#define H_  16
#define DK_ 64
#define FF_ 4096
#define BT_ (B_*T_)

typedef __attribute__((ext_vector_type(8))) short bf16x8;
typedef __attribute__((ext_vector_type(4))) float f32x4;

__device__ __forceinline__ ushort f2bf(float f) {
    __hip_bfloat16 h = __float2bfloat16(f);
    return *reinterpret_cast<ushort*>(&h);
}
__device__ __forceinline__ float bf2f(ushort u) {
    __hip_bfloat16 h;
    *reinterpret_cast<ushort*>(&h) = u;
    return __bfloat162float(h);
}

// async global->LDS, 16B per lane. LDS dest must be wave-uniform base + lane*16.
__device__ __forceinline__ void g2l16(const ushort* g, ushort* l) {
    __builtin_amdgcn_global_load_lds(
        (const __attribute__((address_space(1))) void*)g,
        (__attribute__((address_space(3))) void*)l, 16, 0, 0);
}

// ---------------------------------------------------------------------------
// f32 -> bf16 elementwise
// ---------------------------------------------------------------------------
__global__ __launch_bounds__(256) void cvt_bf16_kernel(
    const float* __restrict__ in, ushort* __restrict__ out, int n)
{
    int i = (blockIdx.x * 256 + threadIdx.x) * 4;
    if (i >= n) return;
    float4 v = *(const float4*)(in + i);
    ushort4 o;
    o.x = f2bf(v.x); o.y = f2bf(v.y); o.z = f2bf(v.z); o.w = f2bf(v.w);
    *(ushort4*)(out + i) = o;
}

// ---------------------------------------------------------------------------
// transpose + convert: in f32 [K][N] -> out bf16 [N][K]; batched over z.
// ---------------------------------------------------------------------------
__global__ __launch_bounds__(256) void transpose_bf16_kernel(
    const float* __restrict__ in, ushort* __restrict__ out,
    int K, int N, long in_bstride, long out_bstride)
{
    __shared__ float t[32][33];
    const float* ib = in + (size_t)blockIdx.z * in_bstride;
    ushort* ob = out + (size_t)blockIdx.z * out_bstride;
    int n0 = blockIdx.x * 32, k0 = blockIdx.y * 32;
    int tid = threadIdx.x;
    int r = tid >> 3, c4 = (tid & 7) * 4;
    float4 v = *(const float4*)(ib + (size_t)(k0 + r) * N + n0 + c4);
    t[r][c4] = v.x; t[r][c4+1] = v.y; t[r][c4+2] = v.z; t[r][c4+3] = v.w;
    __syncthreads();
    int n = tid >> 3, kc = (tid & 7) * 4;
    ushort4 o;
    o.x = f2bf(t[kc+0][n]); o.y = f2bf(t[kc+1][n]);
    o.z = f2bf(t[kc+2][n]); o.w = f2bf(t[kc+3][n]);
    *(ushort4*)(ob + (size_t)(n0 + n) * K + k0 + kc) = o;
}

// ---------------------------------------------------------------------------
// WIDE 128(M)x256(N) NT GEMM, bf16 MFMA, BK=32, 256 thr (4 waves of 64x128).
// 2-phase dbuf, 48KB LDS.
// ---------------------------------------------------------------------------
template<int OUT_BF16>
__global__ __launch_bounds__(256, 2) void gemm_ntw_kernel(
    const ushort* __restrict__ A, int lda,
    const ushort* __restrict__ Bt, int ldb,
    void* __restrict__ C, int ldc, int K,
    const float* __restrict__ bias,
    const float* __restrict__ resid, int relu)
{
    __shared__ __attribute__((aligned(16))) ushort As[2][4][128][8];
    __shared__ __attribute__((aligned(16))) ushort Bs[2][4][256][8];

    int nwg  = gridDim.x * gridDim.y;
    int orig = blockIdx.y * gridDim.x + blockIdx.x;
    int work = (orig & 7) * (nwg >> 3) + (orig >> 3);
    int bx = work % gridDim.x, by = work / gridDim.x;

    int row0 = by * 128, col0 = bx * 256;
    int tid = threadIdx.x;
    int w = tid >> 6, l = tid & 63;
    int wr = (w >> 1) * 64, wc = (w & 1) * 128;

    int m0 = tid & 127, kc0 = tid >> 7;
    const ushort* gA = A  + (size_t)(row0 + m0) * lda + kc0 * 8;
    const ushort* gB = Bt + (size_t)(col0 + tid) * ldb;

    f32x4 acc[4][8];
    #pragma unroll
    for (int i = 0; i < 4; ++i)
        #pragma unroll
        for (int j = 0; j < 8; ++j) acc[i][j] = (f32x4){0.f, 0.f, 0.f, 0.f};

    const int NT = K >> 5;
    g2l16(gA,      &As[0][kc0    ][m0][0]);
    g2l16(gA + 16, &As[0][kc0 + 2][m0][0]);
    #pragma unroll
    for (int p = 0; p < 4; ++p)
        g2l16(gB + p*8, &Bs[0][p][tid][0]);
    __syncthreads();

    int cur = 0;
    for (int t = 0; t < NT; ++t) {
        if (t + 1 < NT) {
            int k0 = (t + 1) << 5;
            g2l16(gA + k0,      &As[cur ^ 1][kc0    ][m0][0]);
            g2l16(gA + k0 + 16, &As[cur ^ 1][kc0 + 2][m0][0]);
            #pragma unroll
            for (int p = 0; p < 4; ++p)
                g2l16(gB + k0 + p*8, &Bs[cur ^ 1][p][tid][0]);
        }
        int kc = l >> 4;
        bf16x8 bfr[8];
        #pragma unroll
        for (int j = 0; j < 8; ++j)
            bfr[j] = *(const bf16x8*)&Bs[cur][kc][wc + j*16 + (l & 15)][0];
        #pragma unroll
        for (int i = 0; i < 4; ++i) {
            bf16x8 a = *(const bf16x8*)&As[cur][kc][wr + i*16 + (l & 15)][0];
            #pragma unroll
            for (int j = 0; j < 8; ++j)
                acc[i][j] = __builtin_amdgcn_mfma_f32_16x16x32_bf16(
                    a, bfr[j], acc[i][j], 0, 0, 0);
        }
        __syncthreads();
        cur ^= 1;
    }

    #pragma unroll
    for (int i = 0; i < 4; ++i) {
        int rbase = row0 + wr + i*16 + (l >> 4) * 4;
        #pragma unroll
        for (int j = 0; j < 8; ++j) {
            int col = col0 + wc + j*16 + (l & 15);
            float bv = bias ? bias[col] : 0.f;
            #pragma unroll
            for (int r = 0; r < 4; ++r) {
                int row = rbase + r;
                float val = acc[i][j][r] + bv;
                if (resid) val += resid[(size_t)row * ldc + col];
                if (relu)  val = fmaxf(val, 0.f);
                if (OUT_BF16) ((ushort*)C)[(size_t)row * ldc + col] = f2bf(val);
                else          ((float*)C)[(size_t)row * ldc + col]  = val;
            }
        }
    }
}

// ---------------------------------------------------------------------------
// 128x128 NT GEMM, BK=32, 2-phase dbuf, 32KB LDS, split-K via blockIdx.z.
// ---------------------------------------------------------------------------
template<int OUT_BF16>
__global__ __launch_bounds__(256) void gemm_nt_kernel(
    const ushort* __restrict__ A, int lda,
    const ushort* __restrict__ Bt, int ldb,
    void* __restrict__ C, int ldc, int K,
    const float* __restrict__ bias,
    const float* __restrict__ resid, int relu,
    long aZoff, long bZoff, long cZoff)
{
    __shared__ __attribute__((aligned(16))) ushort As[2][4][128][8];
    __shared__ __attribute__((aligned(16))) ushort Bs[2][4][128][8];

    A  += (size_t)blockIdx.z * aZoff;
    Bt += (size_t)blockIdx.z * bZoff;
    char* Cb = (char*)C + (size_t)blockIdx.z * cZoff * (OUT_BF16 ? 2 : 4);

    int nwg  = gridDim.x * gridDim.y;
    int orig = blockIdx.y * gridDim.x + blockIdx.x;
    int work = (orig & 7) * (nwg >> 3) + (orig >> 3);
    int bx = work % gridDim.x, by = work / gridDim.x;

    int row0 = by * 128, col0 = bx * 128;
    int tid = threadIdx.x;
    int w = tid >> 6, l = tid & 63;
    int wr = (w >> 1) * 64, wc = (w & 1) * 64;

    int m0 = tid & 127, kc0 = tid >> 7;
    const ushort* ga0 = A  + (size_t)(row0 + m0) * lda + kc0 * 8;
    const ushort* gb0 = Bt + (size_t)(col0 + m0) * ldb + kc0 * 8;

    f32x4 acc[4][4];
    #pragma unroll
    for (int i = 0; i < 4; ++i)
        #pragma unroll
        for (int j = 0; j < 4; ++j) acc[i][j] = (f32x4){0.f, 0.f, 0.f, 0.f};

    const int NT = K >> 5;
    g2l16(ga0,      &As[0][kc0    ][m0][0]);
    g2l16(ga0 + 16, &As[0][kc0 + 2][m0][0]);
    g2l16(gb0,      &Bs[0][kc0    ][m0][0]);
    g2l16(gb0 + 16, &Bs[0][kc0 + 2][m0][0]);
    __syncthreads();

    int cur = 0;
    for (int t = 0; t < NT; ++t) {
        if (t + 1 < NT) {
            int k0 = (t + 1) << 5;
            g2l16(ga0 + k0,      &As[cur ^ 1][kc0    ][m0][0]);
            g2l16(ga0 + k0 + 16, &As[cur ^ 1][kc0 + 2][m0][0]);
            g2l16(gb0 + k0,      &Bs[cur ^ 1][kc0    ][m0][0]);
            g2l16(gb0 + k0 + 16, &Bs[cur ^ 1][kc0 + 2][m0][0]);
        }
        int kc = l >> 4;
        bf16x8 af[4], bfr[4];
        #pragma unroll
        for (int i = 0; i < 4; ++i)
            af[i] = *(const bf16x8*)&As[cur][kc][wr + i*16 + (l & 15)][0];
        #pragma unroll
        for (int j = 0; j < 4; ++j)
            bfr[j] = *(const bf16x8*)&Bs[cur][kc][wc + j*16 + (l & 15)][0];
        #pragma unroll
        for (int i = 0; i < 4; ++i)
            #pragma unroll
            for (int j = 0; j < 4; ++j)
                acc[i][j] = __builtin_amdgcn_mfma_f32_16x16x32_bf16(
                    af[i], bfr[j], acc[i][j], 0, 0, 0);
        __syncthreads();
        cur ^= 1;
    }

    #pragma unroll
    for (int i = 0; i < 4; ++i) {
        int rbase = row0 + wr + i*16 + (l >> 4) * 4;
        #pragma unroll
        for (int j = 0; j < 4; ++j) {
            int col = col0 + wc + j*16 + (l & 15);
            float bv = bias ? bias[col] : 0.f;
            #pragma unroll
            for (int r = 0; r < 4; ++r) {
                int row = rbase + r;
                float val = acc[i][j][r] + bv;
                if (resid) val += resid[(size_t)row * ldc + col];
                if (relu)  val = fmaxf(val, 0.f);
                if (OUT_BF16) ((ushort*)Cb)[(size_t)row * ldc + col] = f2bf(val);
                else          ((float*)Cb)[(size_t)row * ldc + col]  = val;
            }
        }
    }
}

// ---------------------------------------------------------------------------
// csum + vscale fused, Q-tile double-buffered via global_load_lds.
// grid (T/128, B*H), 256 thr.
// ---------------------------------------------------------------------------
__global__ __launch_bounds__(256) void csumv_kernel(
    const ushort* __restrict__ qkv, ushort* __restrict__ vt)
{
    int bh = blockIdx.y, b = bh >> 4, h = bh & 15;
    int s0 = blockIdx.x * 128;
    const ushort* qb = qkv + (size_t)b * T_ * 3072 + h * 64;
    const ushort* kb = qb + 1024;
    const ushort* vb = qb + 2048;
    __shared__ __attribute__((aligned(16))) ushort Ks[8][128][8];
    __shared__ __attribute__((aligned(16))) ushort Qs[2][8][64][8];
    __shared__ float csl[128];
    __shared__ float t[64][65];
    int tid = threadIdx.x, w = tid >> 6, l = tid & 63;
    int scol = w * 32;
    int qq0 = l, kcA = w, kcB = w + 4;   // staging coords (wave-uniform dest)

    #pragma unroll
    for (int p = 0; p < 4; ++p) {
        int idx = tid + p * 256;
        int s = idx & 127, kc = idx >> 7;
        *(uint4*)&Ks[kc][s][0] =
            *(const uint4*)(kb + (size_t)(s0 + s) * 3072 + kc * 8);
    }
    // prologue: stage Q tile 0 into buf 0
    g2l16(qb + (size_t)qq0 * 3072 + kcA * 8, &Qs[0][kcA][qq0][0]);
    g2l16(qb + (size_t)qq0 * 3072 + kcB * 8, &Qs[0][kcB][qq0][0]);
    __syncthreads();

    float cs[2] = {0.f, 0.f};
    int cur = 0;
    for (int qt = 0; qt < T_ / 64; ++qt) {
        if (qt + 1 < T_ / 64) {
            const ushort* qn = qb + (size_t)((qt + 1) * 64 + qq0) * 3072;
            g2l16(qn + kcA * 8, &Qs[cur ^ 1][kcA][qq0][0]);
            g2l16(qn + kcB * 8, &Qs[cur ^ 1][kcB][qq0][0]);
        }
        bf16x8 af[4][2], bfr[2][2];
        #pragma unroll
        for (int qi = 0; qi < 4; ++qi)
            #pragma unroll
            for (int ks = 0; ks < 2; ++ks)
                af[qi][ks] = *(const bf16x8*)&Qs[cur][ks*4 + (l>>4)][qi*16 + (l & 15)][0];
        #pragma unroll
        for (int sj = 0; sj < 2; ++sj)
            #pragma unroll
            for (int ks = 0; ks < 2; ++ks)
                bfr[sj][ks] = *(const bf16x8*)&Ks[ks*4 + (l>>4)][scol + sj*16 + (l & 15)][0];
        #pragma unroll
        for (int qi = 0; qi < 4; ++qi)
            #pragma unroll
            for (int sj = 0; sj < 2; ++sj) {
                f32x4 d = (f32x4){0.f, 0.f, 0.f, 0.f};
                #pragma unroll
                for (int ks = 0; ks < 2; ++ks)
                    d = __builtin_amdgcn_mfma_f32_16x16x32_bf16(
                        af[qi][ks], bfr[sj][ks], d, 0, 0, 0);
                cs[sj] += __expf(d[0]*0.125f) + __expf(d[1]*0.125f)
                        + __expf(d[2]*0.125f) + __expf(d[3]*0.125f);
            }
        __syncthreads();
        cur ^= 1;
    }
    #pragma unroll
    for (int sj = 0; sj < 2; ++sj) {
        float v = cs[sj];
        v += __shfl_down(v, 32, 64);
        v += __shfl_down(v, 16, 64);
        if (l < 16) csl[scol + sj*16 + l] = v;
    }
    __syncthreads();

    // scale + transpose V rows [s0, s0+128) -> vt[bh][dv][s]
    #pragma unroll
    for (int p2 = 0; p2 < 2; ++p2) {
        int sb = s0 + p2 * 64;
        #pragma unroll
        for (int p = 0; p < 2; ++p) {
            int idx = tid + p * 256;
            int s = idx >> 3, c0 = (idx & 7) * 8;
            uint4 raw = *(const uint4*)(vb + (size_t)(sb + s) * 3072 + c0);
            float rc = 1.0f / csl[p2 * 64 + s];
            ushort* u = (ushort*)&raw;
            #pragma unroll
            for (int i = 0; i < 8; ++i) t[s][c0 + i] = bf2f(u[i]) * rc;
        }
        __syncthreads();
        #pragma unroll
        for (int p = 0; p < 2; ++p) {
            int idx = tid + p * 256;
            int dv = idx >> 3, sc = (idx & 7) * 8;
            ushort o[8];
            #pragma unroll
            for (int i = 0; i < 8; ++i) o[i] = f2bf(t[sc + i][dv]);
            *(uint4*)(vt + ((size_t)bh * 64 + dv) * T_ + sb + sc) = *(uint4*)o;
        }
        __syncthreads();
    }
}

// ---------------------------------------------------------------------------
// PV: O[q][dv] = sum_s exp(q·k/8) * vt[dv][s].
// QBLK=128 (wave owns 32 q-rows), K/V double-buffered via global_load_lds,
// 2-phase (stage s-tile t+1 -> compute t -> one barrier). Q in registers.
// grid (T/128, B*H), 256 thr. LDS 48KB -> 3 blocks/CU capacity.
// ---------------------------------------------------------------------------
__global__ __launch_bounds__(256) void attn_pv_kernel(
    const ushort* __restrict__ qkv, const ushort* __restrict__ vt,
    ushort* __restrict__ attn_o)
{
    int bh = blockIdx.y, b = bh >> 4, h = bh & 15;
    int q0 = blockIdx.x * 128;
    const ushort* qb = qkv + (size_t)b * T_ * 3072 + h * 64;
    const ushort* kb = qb + 1024;
    const ushort* vtb = vt + (size_t)bh * 64 * T_;
    __shared__ __attribute__((aligned(16))) ushort Ks[2][8][64][8];
    __shared__ __attribute__((aligned(16))) ushort Vs[2][8][64][8];
    __shared__ __attribute__((aligned(16))) ushort Es[8][128][8];
    int tid = threadIdx.x, w = tid >> 6, l = tid & 63;
    int wq = w * 32;                     // wave's q-rows [wq, wq+32) local

    // staging coords: per (wave,p) kc fixed, row = l -> wave-uniform dest
    int kcA = w, kcB = w + 4;

    // Q fragments in registers (load once, direct global)
    bf16x8 qf[2][2];
    #pragma unroll
    for (int qt = 0; qt < 2; ++qt)
        #pragma unroll
        for (int ks = 0; ks < 2; ++ks)
            qf[qt][ks] = *(const bf16x8*)(qb
                + (size_t)(q0 + wq + qt*16 + (l & 15)) * 3072
                + (ks*4 + (l >> 4)) * 8);

    f32x4 oacc[2][4];
    #pragma unroll
    for (int qt = 0; qt < 2; ++qt)
        #pragma unroll
        for (int j = 0; j < 4; ++j) oacc[qt][j] = (f32x4){0.f, 0.f, 0.f, 0.f};

    const int NT = T_ / 64;
    // prologue: stage s-tile 0 into buf 0
    g2l16(kb + (size_t)l * 3072 + kcA * 8, &Ks[0][kcA][l][0]);
    g2l16(kb + (size_t)l * 3072 + kcB * 8, &Ks[0][kcB][l][0]);
    g2l16(vtb + (size_t)l * T_ + kcA * 8,  &Vs[0][kcA][l][0]);
    g2l16(vtb + (size_t)l * T_ + kcB * 8,  &Vs[0][kcB][l][0]);
    __syncthreads();

    int cur = 0;
    for (int st = 0; st < NT; ++st) {
        if (st + 1 < NT) {               // stage next s-tile into buf^1
            int s1 = (st + 1) * 64;
            g2l16(kb + (size_t)(s1 + l) * 3072 + kcA * 8, &Ks[cur^1][kcA][l][0]);
            g2l16(kb + (size_t)(s1 + l) * 3072 + kcB * 8, &Ks[cur^1][kcB][l][0]);
            g2l16(vtb + (size_t)l * T_ + s1 + kcA * 8,    &Vs[cur^1][kcA][l][0]);
            g2l16(vtb + (size_t)l * T_ + s1 + kcB * 8,    &Vs[cur^1][kcB][l][0]);
        }
        // QK^T -> exp -> Es (wave-private rows [wq, wq+32))
        #pragma unroll
        for (int qt = 0; qt < 2; ++qt)
            #pragma unroll
            for (int sj = 0; sj < 4; ++sj) {
                f32x4 d = (f32x4){0.f, 0.f, 0.f, 0.f};
                #pragma unroll
                for (int ks = 0; ks < 2; ++ks) {
                    bf16x8 kf = *(const bf16x8*)&Ks[cur][ks*4 + (l>>4)][sj*16 + (l & 15)][0];
                    d = __builtin_amdgcn_mfma_f32_16x16x32_bf16(qf[qt][ks], kf, d, 0, 0, 0);
                }
                #pragma unroll
                for (int r = 0; r < 4; ++r) {
                    int qq = wq + qt*16 + (l>>4)*4 + r;
                    int ss = sj*16 + (l & 15);
                    Es[ss >> 3][qq][ss & 7] = f2bf(__expf(d[r] * 0.125f));
                }
            }
        // PV
        #pragma unroll
        for (int qt = 0; qt < 2; ++qt) {
            bf16x8 ef[2];
            #pragma unroll
            for (int ks = 0; ks < 2; ++ks)
                ef[ks] = *(const bf16x8*)&Es[ks*4 + (l>>4)][wq + qt*16 + (l & 15)][0];
            #pragma unroll
            for (int j = 0; j < 4; ++j)
                #pragma unroll
                for (int ks = 0; ks < 2; ++ks) {
                    bf16x8 vf = *(const bf16x8*)&Vs[cur][ks*4 + (l>>4)][j*16 + (l & 15)][0];
                    oacc[qt][j] = __builtin_amdgcn_mfma_f32_16x16x32_bf16(
                        ef[ks], vf, oacc[qt][j], 0, 0, 0);
                }
        }
        __syncthreads();                 // publish stage + WAR protect
        cur ^= 1;
    }

    #pragma unroll
    for (int qt = 0; qt < 2; ++qt)
        #pragma unroll
        for (int j = 0; j < 4; ++j)
            #pragma unroll
            for (int r = 0; r < 4; ++r) {
                int qq = q0 + wq + qt*16 + (l>>4)*4 + r;
                int dv = j*16 + (l & 15);
                attn_o[(size_t)(b*T_ + qq) * 1024 + h*64 + dv] = f2bf(oacc[qt][j][r]);
            }
}

// ---------------------------------------------------------------------------
// fused norm: y = sum_{z<Z} parts[z] (bf16 partials) (+bias) + resid(f32),
// then mean/std norm (Bessel) -> outf (f32) and optional outb (bf16).
// ---------------------------------------------------------------------------
__device__ __forceinline__ float block_reduce_sum_256(float v, float* tmp)
{
    #pragma unroll
    for (int off = 32; off; off >>= 1) v += __shfl_down(v, off, 64);
    int lane = threadIdx.x & 63, w = threadIdx.x >> 6;
    __syncthreads();
    if (lane == 0) tmp[w] = v;
    __syncthreads();
    return tmp[0] + tmp[1] + tmp[2] + tmp[3];
}

template<int Z>
__global__ __launch_bounds__(256) void normZ_fused_kernel(
    const ushort* __restrict__ parts, long zoff,
    const float* __restrict__ bias, const float* __restrict__ resid,
    float* __restrict__ outf, ushort* __restrict__ outb)
{
    __shared__ float tmp[4];
    int row = blockIdx.x;
    int tid = threadIdx.x;
    int c0 = tid * 4;
    size_t idx = (size_t)row * D_ + c0;
    float vals[4] = {0.f, 0.f, 0.f, 0.f};
    #pragma unroll
    for (int z = 0; z < Z; ++z) {
        ushort4 p = *(const ushort4*)&parts[idx + (size_t)z * zoff];
        vals[0] += bf2f(p.x); vals[1] += bf2f(p.y);
        vals[2] += bf2f(p.z); vals[3] += bf2f(p.w);
    }
    float4 rv = *(const float4*)&resid[idx];
    vals[0] += rv.x; vals[1] += rv.y; vals[2] += rv.z; vals[3] += rv.w;
    if (bias) {
        float4 bv = *(const float4*)&bias[c0];
        vals[0] += bv.x; vals[1] += bv.y; vals[2] += bv.z; vals[3] += bv.w;
    }
    float s = vals[0] + vals[1] + vals[2] + vals[3];
    s = block_reduce_sum_256(s, tmp);
    float m = s * (1.0f / (float)D_);
    float sq = 0.f;
    #pragma unroll
    for (int i = 0; i < 4; ++i) { float c = vals[i] - m; sq += c * c; }
    sq = block_reduce_sum_256(sq, tmp);
    float rs = rsqrtf(sq * (1.0f / (float)(D_ - 1)));
    float4 o;
    o.x = (vals[0] - m) * rs; o.y = (vals[1] - m) * rs;
    o.z = (vals[2] - m) * rs; o.w = (vals[3] - m) * rs;
    *(float4*)&outf[idx] = o;
    if (outb) {
        ushort4 ob;
        ob.x = f2bf(o.x); ob.y = f2bf(o.y); ob.z = f2bf(o.z); ob.w = f2bf(o.w);
        *(ushort4*)&outb[idx] = ob;
    }
}

// ---------------------------------------------------------------------------
extern "C" void kernel_launch(void* const* d_in, const int* in_sizes, int n_in,
                              void* d_out, int out_size, void* d_ws, size_t ws_size,
                              hipStream_t stream)
{
    const float* x  = (const float*)d_in[0];
    const float* Wq = (const float*)d_in[1];
    const float* Wk = (const float*)d_in[2];
    const float* Wv = (const float*)d_in[3];
    const float* Wo = (const float*)d_in[4];
    const float* W1 = (const float*)d_in[5];
    const float* b1 = (const float*)d_in[6];
    const float* W2 = (const float*)d_in[7];
    const float* b2 = (const float*)d_in[8];
    float* out = (float*)d_out;

    const size_t MB = (size_t)1 << 20;
    char* base = (char*)d_ws;
    ushort* qkv    = (ushort*)(base +   0*MB);  // 24MB  [QKV..PV]
    ushort* hid    = (ushort*)(base +   0*MB);  // 32MB  [W1..W2]
    ushort* xb     = (ushort*)(base +  24*MB);  //  8MB  [cvt..QKV]
    ushort* W2t    = (ushort*)(base +  32*MB);  //  8MB  [cvt..W2]
    ushort* Wqkvt  = (ushort*)(base +  40*MB);  //  6MB  [cvt..QKV]
    ushort* wpart  = (ushort*)(base +  40*MB);  // 16MB  [W2..norm2]
    ushort* vt     = (ushort*)(base +  46*MB);  //  8MB  [csumv..PV]
    ushort* Wot    = (ushort*)(base +  55*MB);  //  2MB  [cvt..Wo]
    ushort* W1t    = (ushort*)(base +  57*MB);  //  8MB  [cvt..W1]
    ushort* attn_o = (ushort*)(base +  65*MB);  //  8MB  [PV..Wo]
    ushort* wopart = (ushort*)(base +  73*MB);  // 16MB  [Wo..norm1]
    ushort* out1b  = (ushort*)(base +  89*MB);  //  8MB  [norm1..W1]
    float*  out1f  = (float*) (base +  97*MB);  // 16MB  [norm1..norm2]

    // 1. converts / transposes
    cvt_bf16_kernel<<<dim3(BT_*D_/1024), 256, 0, stream>>>(x, xb, BT_*D_);
    transpose_bf16_kernel<<<dim3(2, 32, 16), 256, 0, stream>>>(
        Wq, Wqkvt + 0*1048576, 1024, 64, 65536, 65536);
    transpose_bf16_kernel<<<dim3(2, 32, 16), 256, 0, stream>>>(
        Wk, Wqkvt + 1*1048576, 1024, 64, 65536, 65536);
    transpose_bf16_kernel<<<dim3(2, 32, 16), 256, 0, stream>>>(
        Wv, Wqkvt + 2*1048576, 1024, 64, 65536, 65536);
    transpose_bf16_kernel<<<dim3(32, 32, 1), 256, 0, stream>>>(
        Wo, Wot, 1024, 1024, 0, 0);
    transpose_bf16_kernel<<<dim3(128, 32, 1), 256, 0, stream>>>(
        W1, W1t, 1024, 4096, 0, 0);
    transpose_bf16_kernel<<<dim3(32, 128, 1), 256, 0, stream>>>(
        W2, W2t, 4096, 1024, 0, 0);

    // 2. QKV: wide tile, 384 blocks.
    gemm_ntw_kernel<1><<<dim3(3072/256, 4096/128), 256, 0, stream>>>(
        xb, 1024, Wqkvt, 1024, qkv, 3072, 1024, nullptr, nullptr, 0);
    // 3. colsum + V-scale/transpose fused (Q dbuf)
    csumv_kernel<<<dim3(T_/128, B_*H_), 256, 0, stream>>>(qkv, vt);
    // 4. PV: QBLK=128, K/V dbuf. 512 blocks.
    attn_pv_kernel<<<dim3(T_/128, B_*H_), 256, 0, stream>>>(qkv, vt, attn_o);
    // 5. Wo split-K2 -> bf16 partials. 512 blocks.
    gemm_nt_kernel<1><<<dim3(1024/128, 4096/128, 2), 256, 0, stream>>>(
        attn_o, 1024, Wot, 1024, wopart, 1024, 512, nullptr, nullptr, 0,
        512, 512, (long)4096*1024);
    // 6. norm1 fused: sum 2 partials + x resid -> out1f + out1b
    normZ_fused_kernel<2><<<dim3(BT_), 256, 0, stream>>>(
        wopart, (long)4096*1024, nullptr, x, out1f, out1b);
    // 7. FFN up + ReLU: wide tile, 512 blocks.
    gemm_ntw_kernel<1><<<dim3(4096/256, 4096/128), 256, 0, stream>>>(
        out1b, 1024, W1t, 1024, hid, 4096, 1024, b1, nullptr, 1);
    // 8. FFN down split-K2 -> bf16 partials. 512 blocks, NT=64.
    gemm_nt_kernel<1><<<dim3(1024/128, 4096/128, 2), 256, 0, stream>>>(
        hid, 4096, W2t, 4096, wpart, 1024, 2048, nullptr, nullptr, 0,
        2048, 2048, (long)4096*1024);
    // 9. norm2 fused: sum 2 partials + b2 + out1 resid -> out
    normZ_fused_kernel<2><<<dim3(BT_), 256, 0, stream>>>(
        wpart, (long)4096*1024, b2, out1f, out, nullptr);
}

// Round 12
// 373.345 us; speedup vs baseline: 1.3353x; 1.0464x over previous
//
#include <hip/hip_runtime.h>
#include <hip/hip_bf16.h>
#include <math.h>

#define B_  2
#define T_  2048
#define D_  1024
#define H_  16
#define DK_ 64
#define FF_ 4096
#define BT_ (B_*T_)

typedef __attribute__((ext_vector_type(8))) short bf16x8;
typedef __attribute__((ext_vector_type(4))) float f32x4;

__device__ __forceinline__ ushort f2bf(float f) {
    __hip_bfloat16 h = __float2bfloat16(f);
    return *reinterpret_cast<ushort*>(&h);
}
__device__ __forceinline__ float bf2f(ushort u) {
    __hip_bfloat16 h;
    *reinterpret_cast<ushort*>(&h) = u;
    return __bfloat162float(h);
}

// async global->LDS, 16B per lane. LDS dest must be wave-uniform base + lane*16.
__device__ __forceinline__ void g2l16(const ushort* g, ushort* l) {
    __builtin_amdgcn_global_load_lds(
        (const __attribute__((address_space(1))) void*)g,
        (__attribute__((address_space(3))) void*)l, 16, 0, 0);
}

// ---------------------------------------------------------------------------
// f32 -> bf16 elementwise
// ---------------------------------------------------------------------------
__global__ __launch_bounds__(256) void cvt_bf16_kernel(
    const float* __restrict__ in, ushort* __restrict__ out, int n)
{
    int i = (blockIdx.x * 256 + threadIdx.x) * 4;
    if (i >= n) return;
    float4 v = *(const float4*)(in + i);
    ushort4 o;
    o.x = f2bf(v.x); o.y = f2bf(v.y); o.z = f2bf(v.z); o.w = f2bf(v.w);
    *(ushort4*)(out + i) = o;
}

// ---------------------------------------------------------------------------
// transpose + convert: in f32 [K][N] -> out bf16 [N][K]; batched over z.
// ---------------------------------------------------------------------------
__global__ __launch_bounds__(256) void transpose_bf16_kernel(
    const float* __restrict__ in, ushort* __restrict__ out,
    int K, int N, long in_bstride, long out_bstride)
{
    __shared__ float t[32][33];
    const float* ib = in + (size_t)blockIdx.z * in_bstride;
    ushort* ob = out + (size_t)blockIdx.z * out_bstride;
    int n0 = blockIdx.x * 32, k0 = blockIdx.y * 32;
    int tid = threadIdx.x;
    int r = tid >> 3, c4 = (tid & 7) * 4;
    float4 v = *(const float4*)(ib + (size_t)(k0 + r) * N + n0 + c4);
    t[r][c4] = v.x; t[r][c4+1] = v.y; t[r][c4+2] = v.z; t[r][c4+3] = v.w;
    __syncthreads();
    int n = tid >> 3, kc = (tid & 7) * 4;
    ushort4 o;
    o.x = f2bf(t[kc+0][n]); o.y = f2bf(t[kc+1][n]);
    o.z = f2bf(t[kc+2][n]); o.w = f2bf(t[kc+3][n]);
    *(ushort4*)(ob + (size_t)(n0 + n) * K + k0 + kc) = o;
}

// fused Wq/Wk/Wv transpose: z in [0,48): mat = z>>4, head = z&15.
__global__ __launch_bounds__(256) void transpose_qkv_kernel(
    const float* __restrict__ Wq, const float* __restrict__ Wk,
    const float* __restrict__ Wv, ushort* __restrict__ outp)
{
    __shared__ float t[32][33];
    int z = blockIdx.z, mat = z >> 4, zz = z & 15;
    const float* ib = (mat == 0 ? Wq : (mat == 1 ? Wk : Wv)) + (size_t)zz * 65536;
    ushort* ob = outp + (size_t)mat * 1048576 + (size_t)zz * 65536;
    int n0 = blockIdx.x * 32, k0 = blockIdx.y * 32;
    int tid = threadIdx.x;
    int r = tid >> 3, c4 = (tid & 7) * 4;
    float4 v = *(const float4*)(ib + (size_t)(k0 + r) * 64 + n0 + c4);
    t[r][c4] = v.x; t[r][c4+1] = v.y; t[r][c4+2] = v.z; t[r][c4+3] = v.w;
    __syncthreads();
    int n = tid >> 3, kc = (tid & 7) * 4;
    ushort4 o;
    o.x = f2bf(t[kc+0][n]); o.y = f2bf(t[kc+1][n]);
    o.z = f2bf(t[kc+2][n]); o.w = f2bf(t[kc+3][n]);
    *(ushort4*)(ob + (size_t)(n0 + n) * 1024 + k0 + kc) = o;
}

// ---------------------------------------------------------------------------
// WIDE 128(M)x256(N) NT GEMM, bf16 MFMA, BK=32, 256 thr (4 waves of 64x128).
// 2-phase dbuf, 48KB LDS.
// ---------------------------------------------------------------------------
template<int OUT_BF16>
__global__ __launch_bounds__(256, 2) void gemm_ntw_kernel(
    const ushort* __restrict__ A, int lda,
    const ushort* __restrict__ Bt, int ldb,
    void* __restrict__ C, int ldc, int K,
    const float* __restrict__ bias,
    const float* __restrict__ resid, int relu)
{
    __shared__ __attribute__((aligned(16))) ushort As[2][4][128][8];
    __shared__ __attribute__((aligned(16))) ushort Bs[2][4][256][8];

    int nwg  = gridDim.x * gridDim.y;
    int orig = blockIdx.y * gridDim.x + blockIdx.x;
    int work = (orig & 7) * (nwg >> 3) + (orig >> 3);
    int bx = work % gridDim.x, by = work / gridDim.x;

    int row0 = by * 128, col0 = bx * 256;
    int tid = threadIdx.x;
    int w = tid >> 6, l = tid & 63;
    int wr = (w >> 1) * 64, wc = (w & 1) * 128;

    int m0 = tid & 127, kc0 = tid >> 7;
    const ushort* gA = A  + (size_t)(row0 + m0) * lda + kc0 * 8;
    const ushort* gB = Bt + (size_t)(col0 + tid) * ldb;

    f32x4 acc[4][8];
    #pragma unroll
    for (int i = 0; i < 4; ++i)
        #pragma unroll
        for (int j = 0; j < 8; ++j) acc[i][j] = (f32x4){0.f, 0.f, 0.f, 0.f};

    const int NT = K >> 5;
    g2l16(gA,      &As[0][kc0    ][m0][0]);
    g2l16(gA + 16, &As[0][kc0 + 2][m0][0]);
    #pragma unroll
    for (int p = 0; p < 4; ++p)
        g2l16(gB + p*8, &Bs[0][p][tid][0]);
    __syncthreads();

    int cur = 0;
    for (int t = 0; t < NT; ++t) {
        if (t + 1 < NT) {
            int k0 = (t + 1) << 5;
            g2l16(gA + k0,      &As[cur ^ 1][kc0    ][m0][0]);
            g2l16(gA + k0 + 16, &As[cur ^ 1][kc0 + 2][m0][0]);
            #pragma unroll
            for (int p = 0; p < 4; ++p)
                g2l16(gB + k0 + p*8, &Bs[cur ^ 1][p][tid][0]);
        }
        int kc = l >> 4;
        bf16x8 bfr[8];
        #pragma unroll
        for (int j = 0; j < 8; ++j)
            bfr[j] = *(const bf16x8*)&Bs[cur][kc][wc + j*16 + (l & 15)][0];
        #pragma unroll
        for (int i = 0; i < 4; ++i) {
            bf16x8 a = *(const bf16x8*)&As[cur][kc][wr + i*16 + (l & 15)][0];
            #pragma unroll
            for (int j = 0; j < 8; ++j)
                acc[i][j] = __builtin_amdgcn_mfma_f32_16x16x32_bf16(
                    a, bfr[j], acc[i][j], 0, 0, 0);
        }
        __syncthreads();
        cur ^= 1;
    }

    #pragma unroll
    for (int i = 0; i < 4; ++i) {
        int rbase = row0 + wr + i*16 + (l >> 4) * 4;
        #pragma unroll
        for (int j = 0; j < 8; ++j) {
            int col = col0 + wc + j*16 + (l & 15);
            float bv = bias ? bias[col] : 0.f;
            #pragma unroll
            for (int r = 0; r < 4; ++r) {
                int row = rbase + r;
                float val = acc[i][j][r] + bv;
                if (resid) val += resid[(size_t)row * ldc + col];
                if (relu)  val = fmaxf(val, 0.f);
                if (OUT_BF16) ((ushort*)C)[(size_t)row * ldc + col] = f2bf(val);
                else          ((float*)C)[(size_t)row * ldc + col]  = val;
            }
        }
    }
}

// ---------------------------------------------------------------------------
// 128x128 NT GEMM, BK=32, 2-phase dbuf, 32KB LDS, split-K via blockIdx.z.
// ---------------------------------------------------------------------------
template<int OUT_BF16>
__global__ __launch_bounds__(256) void gemm_nt_kernel(
    const ushort* __restrict__ A, int lda,
    const ushort* __restrict__ Bt, int ldb,
    void* __restrict__ C, int ldc, int K,
    const float* __restrict__ bias,
    const float* __restrict__ resid, int relu,
    long aZoff, long bZoff, long cZoff)
{
    __shared__ __attribute__((aligned(16))) ushort As[2][4][128][8];
    __shared__ __attribute__((aligned(16))) ushort Bs[2][4][128][8];

    A  += (size_t)blockIdx.z * aZoff;
    Bt += (size_t)blockIdx.z * bZoff;
    char* Cb = (char*)C + (size_t)blockIdx.z * cZoff * (OUT_BF16 ? 2 : 4);

    int nwg  = gridDim.x * gridDim.y;
    int orig = blockIdx.y * gridDim.x + blockIdx.x;
    int work = (orig & 7) * (nwg >> 3) + (orig >> 3);
    int bx = work % gridDim.x, by = work / gridDim.x;

    int row0 = by * 128, col0 = bx * 128;
    int tid = threadIdx.x;
    int w = tid >> 6, l = tid & 63;
    int wr = (w >> 1) * 64, wc = (w & 1) * 64;

    int m0 = tid & 127, kc0 = tid >> 7;
    const ushort* ga0 = A  + (size_t)(row0 + m0) * lda + kc0 * 8;
    const ushort* gb0 = Bt + (size_t)(col0 + m0) * ldb + kc0 * 8;

    f32x4 acc[4][4];
    #pragma unroll
    for (int i = 0; i < 4; ++i)
        #pragma unroll
        for (int j = 0; j < 4; ++j) acc[i][j] = (f32x4){0.f, 0.f, 0.f, 0.f};

    const int NT = K >> 5;
    g2l16(ga0,      &As[0][kc0    ][m0][0]);
    g2l16(ga0 + 16, &As[0][kc0 + 2][m0][0]);
    g2l16(gb0,      &Bs[0][kc0    ][m0][0]);
    g2l16(gb0 + 16, &Bs[0][kc0 + 2][m0][0]);
    __syncthreads();

    int cur = 0;
    for (int t = 0; t < NT; ++t) {
        if (t + 1 < NT) {
            int k0 = (t + 1) << 5;
            g2l16(ga0 + k0,      &As[cur ^ 1][kc0    ][m0][0]);
            g2l16(ga0 + k0 + 16, &As[cur ^ 1][kc0 + 2][m0][0]);
            g2l16(gb0 + k0,      &Bs[cur ^ 1][kc0    ][m0][0]);
            g2l16(gb0 + k0 + 16, &Bs[cur ^ 1][kc0 + 2][m0][0]);
        }
        int kc = l >> 4;
        bf16x8 af[4], bfr[4];
        #pragma unroll
        for (int i = 0; i < 4; ++i)
            af[i] = *(const bf16x8*)&As[cur][kc][wr + i*16 + (l & 15)][0];
        #pragma unroll
        for (int j = 0; j < 4; ++j)
            bfr[j] = *(const bf16x8*)&Bs[cur][kc][wc + j*16 + (l & 15)][0];
        #pragma unroll
        for (int i = 0; i < 4; ++i)
            #pragma unroll
            for (int j = 0; j < 4; ++j)
                acc[i][j] = __builtin_amdgcn_mfma_f32_16x16x32_bf16(
                    af[i], bfr[j], acc[i][j], 0, 0, 0);
        __syncthreads();
        cur ^= 1;
    }

    #pragma unroll
    for (int i = 0; i < 4; ++i) {
        int rbase = row0 + wr + i*16 + (l >> 4) * 4;
        #pragma unroll
        for (int j = 0; j < 4; ++j) {
            int col = col0 + wc + j*16 + (l & 15);
            float bv = bias ? bias[col] : 0.f;
            #pragma unroll
            for (int r = 0; r < 4; ++r) {
                int row = rbase + r;
                float val = acc[i][j][r] + bv;
                if (resid) val += resid[(size_t)row * ldc + col];
                if (relu)  val = fmaxf(val, 0.f);
                if (OUT_BF16) ((ushort*)Cb)[(size_t)row * ldc + col] = f2bf(val);
                else          ((float*)Cb)[(size_t)row * ldc + col]  = val;
            }
        }
    }
}

// ---------------------------------------------------------------------------
// csum + vscale fused, Q-tile dbuf. XCD swizzle: all s-tiles of one bh land
// on one XCD -> shared Q stream becomes L2-resident.
// ---------------------------------------------------------------------------
__global__ __launch_bounds__(256) void csumv_kernel(
    const ushort* __restrict__ qkv, ushort* __restrict__ vt)
{
    int nwg  = gridDim.x * gridDim.y;
    int orig = blockIdx.y * gridDim.x + blockIdx.x;
    int work = (orig & 7) * (nwg >> 3) + (orig >> 3);
    int bx = work % gridDim.x;
    int bh = work / gridDim.x;
    int b = bh >> 4, h = bh & 15;
    int s0 = bx * 128;
    const ushort* qb = qkv + (size_t)b * T_ * 3072 + h * 64;
    const ushort* kb = qb + 1024;
    const ushort* vb = qb + 2048;
    __shared__ __attribute__((aligned(16))) ushort Ks[8][128][8];
    __shared__ __attribute__((aligned(16))) ushort Qs[2][8][64][8];
    __shared__ float csl[128];
    __shared__ float t[64][65];
    int tid = threadIdx.x, w = tid >> 6, l = tid & 63;
    int scol = w * 32;
    int qq0 = l, kcA = w, kcB = w + 4;

    #pragma unroll
    for (int p = 0; p < 4; ++p) {
        int idx = tid + p * 256;
        int s = idx & 127, kc = idx >> 7;
        *(uint4*)&Ks[kc][s][0] =
            *(const uint4*)(kb + (size_t)(s0 + s) * 3072 + kc * 8);
    }
    g2l16(qb + (size_t)qq0 * 3072 + kcA * 8, &Qs[0][kcA][qq0][0]);
    g2l16(qb + (size_t)qq0 * 3072 + kcB * 8, &Qs[0][kcB][qq0][0]);
    __syncthreads();

    float cs[2] = {0.f, 0.f};
    int cur = 0;
    for (int qt = 0; qt < T_ / 64; ++qt) {
        if (qt + 1 < T_ / 64) {
            const ushort* qn = qb + (size_t)((qt + 1) * 64 + qq0) * 3072;
            g2l16(qn + kcA * 8, &Qs[cur ^ 1][kcA][qq0][0]);
            g2l16(qn + kcB * 8, &Qs[cur ^ 1][kcB][qq0][0]);
        }
        bf16x8 af[4][2], bfr[2][2];
        #pragma unroll
        for (int qi = 0; qi < 4; ++qi)
            #pragma unroll
            for (int ks = 0; ks < 2; ++ks)
                af[qi][ks] = *(const bf16x8*)&Qs[cur][ks*4 + (l>>4)][qi*16 + (l & 15)][0];
        #pragma unroll
        for (int sj = 0; sj < 2; ++sj)
            #pragma unroll
            for (int ks = 0; ks < 2; ++ks)
                bfr[sj][ks] = *(const bf16x8*)&Ks[ks*4 + (l>>4)][scol + sj*16 + (l & 15)][0];
        #pragma unroll
        for (int qi = 0; qi < 4; ++qi)
            #pragma unroll
            for (int sj = 0; sj < 2; ++sj) {
                f32x4 d = (f32x4){0.f, 0.f, 0.f, 0.f};
                #pragma unroll
                for (int ks = 0; ks < 2; ++ks)
                    d = __builtin_amdgcn_mfma_f32_16x16x32_bf16(
                        af[qi][ks], bfr[sj][ks], d, 0, 0, 0);
                cs[sj] += __expf(d[0]*0.125f) + __expf(d[1]*0.125f)
                        + __expf(d[2]*0.125f) + __expf(d[3]*0.125f);
            }
        __syncthreads();
        cur ^= 1;
    }
    #pragma unroll
    for (int sj = 0; sj < 2; ++sj) {
        float v = cs[sj];
        v += __shfl_down(v, 32, 64);
        v += __shfl_down(v, 16, 64);
        if (l < 16) csl[scol + sj*16 + l] = v;
    }
    __syncthreads();

    #pragma unroll
    for (int p2 = 0; p2 < 2; ++p2) {
        int sb = s0 + p2 * 64;
        #pragma unroll
        for (int p = 0; p < 2; ++p) {
            int idx = tid + p * 256;
            int s = idx >> 3, c0 = (idx & 7) * 8;
            uint4 raw = *(const uint4*)(vb + (size_t)(sb + s) * 3072 + c0);
            float rc = 1.0f / csl[p2 * 64 + s];
            ushort* u = (ushort*)&raw;
            #pragma unroll
            for (int i = 0; i < 8; ++i) t[s][c0 + i] = bf2f(u[i]) * rc;
        }
        __syncthreads();
        #pragma unroll
        for (int p = 0; p < 2; ++p) {
            int idx = tid + p * 256;
            int dv = idx >> 3, sc = (idx & 7) * 8;
            ushort o[8];
            #pragma unroll
            for (int i = 0; i < 8; ++i) o[i] = f2bf(t[sc + i][dv]);
            *(uint4*)(vt + ((size_t)bh * 64 + dv) * T_ + sb + sc) = *(uint4*)o;
        }
        __syncthreads();
    }
}

// ---------------------------------------------------------------------------
// PV: QBLK=128, K/V dbuf, Q in regs. XCD swizzle: all q-tiles of one bh on
// one XCD -> K/V stream L2-resident (4 bh x 512KB = 2MB per XCD L2).
// ---------------------------------------------------------------------------
__global__ __launch_bounds__(256) void attn_pv_kernel(
    const ushort* __restrict__ qkv, const ushort* __restrict__ vt,
    ushort* __restrict__ attn_o)
{
    int nwg  = gridDim.x * gridDim.y;
    int orig = blockIdx.y * gridDim.x + blockIdx.x;
    int work = (orig & 7) * (nwg >> 3) + (orig >> 3);
    int bx = work % gridDim.x;
    int bh = work / gridDim.x;
    int b = bh >> 4, h = bh & 15;
    int q0 = bx * 128;
    const ushort* qb = qkv + (size_t)b * T_ * 3072 + h * 64;
    const ushort* kb = qb + 1024;
    const ushort* vtb = vt + (size_t)bh * 64 * T_;
    __shared__ __attribute__((aligned(16))) ushort Ks[2][8][64][8];
    __shared__ __attribute__((aligned(16))) ushort Vs[2][8][64][8];
    __shared__ __attribute__((aligned(16))) ushort Es[8][128][8];
    int tid = threadIdx.x, w = tid >> 6, l = tid & 63;
    int wq = w * 32;
    int kcA = w, kcB = w + 4;

    bf16x8 qf[2][2];
    #pragma unroll
    for (int qt = 0; qt < 2; ++qt)
        #pragma unroll
        for (int ks = 0; ks < 2; ++ks)
            qf[qt][ks] = *(const bf16x8*)(qb
                + (size_t)(q0 + wq + qt*16 + (l & 15)) * 3072
                + (ks*4 + (l >> 4)) * 8);

    f32x4 oacc[2][4];
    #pragma unroll
    for (int qt = 0; qt < 2; ++qt)
        #pragma unroll
        for (int j = 0; j < 4; ++j) oacc[qt][j] = (f32x4){0.f, 0.f, 0.f, 0.f};

    const int NT = T_ / 64;
    g2l16(kb + (size_t)l * 3072 + kcA * 8, &Ks[0][kcA][l][0]);
    g2l16(kb + (size_t)l * 3072 + kcB * 8, &Ks[0][kcB][l][0]);
    g2l16(vtb + (size_t)l * T_ + kcA * 8,  &Vs[0][kcA][l][0]);
    g2l16(vtb + (size_t)l * T_ + kcB * 8,  &Vs[0][kcB][l][0]);
    __syncthreads();

    int cur = 0;
    for (int st = 0; st < NT; ++st) {
        if (st + 1 < NT) {
            int s1 = (st + 1) * 64;
            g2l16(kb + (size_t)(s1 + l) * 3072 + kcA * 8, &Ks[cur^1][kcA][l][0]);
            g2l16(kb + (size_t)(s1 + l) * 3072 + kcB * 8, &Ks[cur^1][kcB][l][0]);
            g2l16(vtb + (size_t)l * T_ + s1 + kcA * 8,    &Vs[cur^1][kcA][l][0]);
            g2l16(vtb + (size_t)l * T_ + s1 + kcB * 8,    &Vs[cur^1][kcB][l][0]);
        }
        #pragma unroll
        for (int qt = 0; qt < 2; ++qt)
            #pragma unroll
            for (int sj = 0; sj < 4; ++sj) {
                f32x4 d = (f32x4){0.f, 0.f, 0.f, 0.f};
                #pragma unroll
                for (int ks = 0; ks < 2; ++ks) {
                    bf16x8 kf = *(const bf16x8*)&Ks[cur][ks*4 + (l>>4)][sj*16 + (l & 15)][0];
                    d = __builtin_amdgcn_mfma_f32_16x16x32_bf16(qf[qt][ks], kf, d, 0, 0, 0);
                }
                #pragma unroll
                for (int r = 0; r < 4; ++r) {
                    int qq = wq + qt*16 + (l>>4)*4 + r;
                    int ss = sj*16 + (l & 15);
                    Es[ss >> 3][qq][ss & 7] = f2bf(__expf(d[r] * 0.125f));
                }
            }
        #pragma unroll
        for (int qt = 0; qt < 2; ++qt) {
            bf16x8 ef[2];
            #pragma unroll
            for (int ks = 0; ks < 2; ++ks)
                ef[ks] = *(const bf16x8*)&Es[ks*4 + (l>>4)][wq + qt*16 + (l & 15)][0];
            #pragma unroll
            for (int j = 0; j < 4; ++j)
                #pragma unroll
                for (int ks = 0; ks < 2; ++ks) {
                    bf16x8 vf = *(const bf16x8*)&Vs[cur][ks*4 + (l>>4)][j*16 + (l & 15)][0];
                    oacc[qt][j] = __builtin_amdgcn_mfma_f32_16x16x32_bf16(
                        ef[ks], vf, oacc[qt][j], 0, 0, 0);
                }
        }
        __syncthreads();
        cur ^= 1;
    }

    #pragma unroll
    for (int qt = 0; qt < 2; ++qt)
        #pragma unroll
        for (int j = 0; j < 4; ++j)
            #pragma unroll
            for (int r = 0; r < 4; ++r) {
                int qq = q0 + wq + qt*16 + (l>>4)*4 + r;
                int dv = j*16 + (l & 15);
                attn_o[(size_t)(b*T_ + qq) * 1024 + h*64 + dv] = f2bf(oacc[qt][j][r]);
            }
}

// ---------------------------------------------------------------------------
// fused norm
// ---------------------------------------------------------------------------
__device__ __forceinline__ float block_reduce_sum_256(float v, float* tmp)
{
    #pragma unroll
    for (int off = 32; off; off >>= 1) v += __shfl_down(v, off, 64);
    int lane = threadIdx.x & 63, w = threadIdx.x >> 6;
    __syncthreads();
    if (lane == 0) tmp[w] = v;
    __syncthreads();
    return tmp[0] + tmp[1] + tmp[2] + tmp[3];
}

template<int Z>
__global__ __launch_bounds__(256) void normZ_fused_kernel(
    const ushort* __restrict__ parts, long zoff,
    const float* __restrict__ bias, const float* __restrict__ resid,
    float* __restrict__ outf, ushort* __restrict__ outb)
{
    __shared__ float tmp[4];
    int row = blockIdx.x;
    int tid = threadIdx.x;
    int c0 = tid * 4;
    size_t idx = (size_t)row * D_ + c0;
    float vals[4] = {0.f, 0.f, 0.f, 0.f};
    #pragma unroll
    for (int z = 0; z < Z; ++z) {
        ushort4 p = *(const ushort4*)&parts[idx + (size_t)z * zoff];
        vals[0] += bf2f(p.x); vals[1] += bf2f(p.y);
        vals[2] += bf2f(p.z); vals[3] += bf2f(p.w);
    }
    float4 rv = *(const float4*)&resid[idx];
    vals[0] += rv.x; vals[1] += rv.y; vals[2] += rv.z; vals[3] += rv.w;
    if (bias) {
        float4 bv = *(const float4*)&bias[c0];
        vals[0] += bv.x; vals[1] += bv.y; vals[2] += bv.z; vals[3] += bv.w;
    }
    float s = vals[0] + vals[1] + vals[2] + vals[3];
    s = block_reduce_sum_256(s, tmp);
    float m = s * (1.0f / (float)D_);
    float sq = 0.f;
    #pragma unroll
    for (int i = 0; i < 4; ++i) { float c = vals[i] - m; sq += c * c; }
    sq = block_reduce_sum_256(sq, tmp);
    float rs = rsqrtf(sq * (1.0f / (float)(D_ - 1)));
    float4 o;
    o.x = (vals[0] - m) * rs; o.y = (vals[1] - m) * rs;
    o.z = (vals[2] - m) * rs; o.w = (vals[3] - m) * rs;
    *(float4*)&outf[idx] = o;
    if (outb) {
        ushort4 ob;
        ob.x = f2bf(o.x); ob.y = f2bf(o.y); ob.z = f2bf(o.z); ob.w = f2bf(o.w);
        *(ushort4*)&outb[idx] = ob;
    }
}

// ---------------------------------------------------------------------------
extern "C" void kernel_launch(void* const* d_in, const int* in_sizes, int n_in,
                              void* d_out, int out_size, void* d_ws, size_t ws_size,
                              hipStream_t stream)
{
    const float* x  = (const float*)d_in[0];
    const float* Wq = (const float*)d_in[1];
    const float* Wk = (const float*)d_in[2];
    const float* Wv = (const float*)d_in[3];
    const float* Wo = (const float*)d_in[4];
    const float* W1 = (const float*)d_in[5];
    const float* b1 = (const float*)d_in[6];
    const float* W2 = (const float*)d_in[7];
    const float* b2 = (const float*)d_in[8];
    float* out = (float*)d_out;

    const size_t MB = (size_t)1 << 20;
    char* base = (char*)d_ws;
    ushort* qkv    = (ushort*)(base +   0*MB);  // 24MB  [QKV..PV]
    ushort* hid    = (ushort*)(base +   0*MB);  // 32MB  [W1..W2]
    ushort* xb     = (ushort*)(base +  24*MB);  //  8MB  [cvt..QKV]
    ushort* W2t    = (ushort*)(base +  32*MB);  //  8MB  [cvt..W2]
    ushort* Wqkvt  = (ushort*)(base +  40*MB);  //  6MB  [cvt..QKV]
    ushort* wpart  = (ushort*)(base +  40*MB);  // 16MB  [W2..norm2]
    ushort* vt     = (ushort*)(base +  46*MB);  //  8MB  [csumv..PV]
    ushort* Wot    = (ushort*)(base +  55*MB);  //  2MB  [cvt..Wo]
    ushort* W1t    = (ushort*)(base +  57*MB);  //  8MB  [cvt..W1]
    ushort* attn_o = (ushort*)(base +  65*MB);  //  8MB  [PV..Wo]
    ushort* wopart = (ushort*)(base +  73*MB);  // 16MB  [Wo..norm1]
    ushort* out1b  = (ushort*)(base +  89*MB);  //  8MB  [norm1..W1]
    float*  out1f  = (float*) (base +  97*MB);  // 16MB  [norm1..norm2]

    // 1. converts / transposes
    cvt_bf16_kernel<<<dim3(BT_*D_/1024), 256, 0, stream>>>(x, xb, BT_*D_);
    transpose_qkv_kernel<<<dim3(2, 32, 48), 256, 0, stream>>>(Wq, Wk, Wv, Wqkvt);
    transpose_bf16_kernel<<<dim3(32, 32, 1), 256, 0, stream>>>(
        Wo, Wot, 1024, 1024, 0, 0);
    transpose_bf16_kernel<<<dim3(128, 32, 1), 256, 0, stream>>>(
        W1, W1t, 1024, 4096, 0, 0);
    transpose_bf16_kernel<<<dim3(32, 128, 1), 256, 0, stream>>>(
        W2, W2t, 4096, 1024, 0, 0);

    // 2. QKV: wide tile, 384 blocks.
    gemm_ntw_kernel<1><<<dim3(3072/256, 4096/128), 256, 0, stream>>>(
        xb, 1024, Wqkvt, 1024, qkv, 3072, 1024, nullptr, nullptr, 0);
    // 3. colsum + V-scale/transpose fused (Q dbuf, XCD swizzle)
    csumv_kernel<<<dim3(T_/128, B_*H_), 256, 0, stream>>>(qkv, vt);
    // 4. PV: QBLK=128, K/V dbuf, XCD swizzle. 512 blocks.
    attn_pv_kernel<<<dim3(T_/128, B_*H_), 256, 0, stream>>>(qkv, vt, attn_o);
    // 5. Wo split-K2 -> bf16 partials. 512 blocks.
    gemm_nt_kernel<1><<<dim3(1024/128, 4096/128, 2), 256, 0, stream>>>(
        attn_o, 1024, Wot, 1024, wopart, 1024, 512, nullptr, nullptr, 0,
        512, 512, (long)4096*1024);
    // 6. norm1 fused: sum 2 partials + x resid -> out1f + out1b
    normZ_fused_kernel<2><<<dim3(BT_), 256, 0, stream>>>(
        wopart, (long)4096*1024, nullptr, x, out1f, out1b);
    // 7. FFN up + ReLU: wide tile, 512 blocks.
    gemm_ntw_kernel<1><<<dim3(4096/256, 4096/128), 256, 0, stream>>>(
        out1b, 1024, W1t, 1024, hid, 4096, 1024, b1, nullptr, 1);
    // 8. FFN down split-K2 -> bf16 partials. 512 blocks, NT=64.
    gemm_nt_kernel<1><<<dim3(1024/128, 4096/128, 2), 256, 0, stream>>>(
        hid, 4096, W2t, 4096, wpart, 1024, 2048, nullptr, nullptr, 0,
        2048, 2048, (long)4096*1024);
    // 9. norm2 fused: sum 2 partials + b2 + out1 resid -> out
    normZ_fused_kernel<2><<<dim3(BT_), 256, 0, stream>>>(
        wpart, (long)4096*1024, b2, out1f, out, nullptr);
}

// Round 13
// 368.290 us; speedup vs baseline: 1.3537x; 1.0137x over previous
//
#include <hip/hip_runtime.h>
#include <hip/hip_bf16.h>
#include <math.h>

#define B_  2
#define T_  2048
#define D_  1024
#define H_  16
#define DK_ 64
#define FF_ 4096
#define BT_ (B_*T_)

typedef __attribute__((ext_vector_type(8))) short bf16x8;
typedef __attribute__((ext_vector_type(4))) float f32x4;

__device__ __forceinline__ ushort f2bf(float f) {
    __hip_bfloat16 h = __float2bfloat16(f);
    return *reinterpret_cast<ushort*>(&h);
}
__device__ __forceinline__ float bf2f(ushort u) {
    __hip_bfloat16 h;
    *reinterpret_cast<ushort*>(&h) = u;
    return __bfloat162float(h);
}
__device__ __forceinline__ uint pk2(float a, float b) {
    return (uint)f2bf(a) | ((uint)f2bf(b) << 16);
}

// async global->LDS, 16B per lane. LDS dest must be wave-uniform base + lane*16.
__device__ __forceinline__ void g2l16(const ushort* g, ushort* l) {
    __builtin_amdgcn_global_load_lds(
        (const __attribute__((address_space(1))) void*)g,
        (__attribute__((address_space(3))) void*)l, 16, 0, 0);
}

// ---------------------------------------------------------------------------
// f32 -> bf16 elementwise
// ---------------------------------------------------------------------------
__global__ __launch_bounds__(256) void cvt_bf16_kernel(
    const float* __restrict__ in, ushort* __restrict__ out, int n)
{
    int i = (blockIdx.x * 256 + threadIdx.x) * 4;
    if (i >= n) return;
    float4 v = *(const float4*)(in + i);
    ushort4 o;
    o.x = f2bf(v.x); o.y = f2bf(v.y); o.z = f2bf(v.z); o.w = f2bf(v.w);
    *(ushort4*)(out + i) = o;
}

// ---------------------------------------------------------------------------
// transpose + convert: in f32 [K][N] -> out bf16 [N][K]; batched over z.
// ---------------------------------------------------------------------------
__global__ __launch_bounds__(256) void transpose_bf16_kernel(
    const float* __restrict__ in, ushort* __restrict__ out,
    int K, int N, long in_bstride, long out_bstride)
{
    __shared__ float t[32][33];
    const float* ib = in + (size_t)blockIdx.z * in_bstride;
    ushort* ob = out + (size_t)blockIdx.z * out_bstride;
    int n0 = blockIdx.x * 32, k0 = blockIdx.y * 32;
    int tid = threadIdx.x;
    int r = tid >> 3, c4 = (tid & 7) * 4;
    float4 v = *(const float4*)(ib + (size_t)(k0 + r) * N + n0 + c4);
    t[r][c4] = v.x; t[r][c4+1] = v.y; t[r][c4+2] = v.z; t[r][c4+3] = v.w;
    __syncthreads();
    int n = tid >> 3, kc = (tid & 7) * 4;
    ushort4 o;
    o.x = f2bf(t[kc+0][n]); o.y = f2bf(t[kc+1][n]);
    o.z = f2bf(t[kc+2][n]); o.w = f2bf(t[kc+3][n]);
    *(ushort4*)(ob + (size_t)(n0 + n) * K + k0 + kc) = o;
}

// fused Wq/Wk/Wv transpose: z in [0,48): mat = z>>4, head = z&15.
__global__ __launch_bounds__(256) void transpose_qkv_kernel(
    const float* __restrict__ Wq, const float* __restrict__ Wk,
    const float* __restrict__ Wv, ushort* __restrict__ outp)
{
    __shared__ float t[32][33];
    int z = blockIdx.z, mat = z >> 4, zz = z & 15;
    const float* ib = (mat == 0 ? Wq : (mat == 1 ? Wk : Wv)) + (size_t)zz * 65536;
    ushort* ob = outp + (size_t)mat * 1048576 + (size_t)zz * 65536;
    int n0 = blockIdx.x * 32, k0 = blockIdx.y * 32;
    int tid = threadIdx.x;
    int r = tid >> 3, c4 = (tid & 7) * 4;
    float4 v = *(const float4*)(ib + (size_t)(k0 + r) * 64 + n0 + c4);
    t[r][c4] = v.x; t[r][c4+1] = v.y; t[r][c4+2] = v.z; t[r][c4+3] = v.w;
    __syncthreads();
    int n = tid >> 3, kc = (tid & 7) * 4;
    ushort4 o;
    o.x = f2bf(t[kc+0][n]); o.y = f2bf(t[kc+1][n]);
    o.z = f2bf(t[kc+2][n]); o.w = f2bf(t[kc+3][n]);
    *(ushort4*)(ob + (size_t)(n0 + n) * 1024 + k0 + kc) = o;
}

// ---------------------------------------------------------------------------
// WIDE 128(M)x256(N) NT GEMM, bf16 MFMA, BK=32, 256 thr (4 waves of 64x128).
// 2-phase dbuf, 48KB LDS.
// ---------------------------------------------------------------------------
template<int OUT_BF16>
__global__ __launch_bounds__(256, 2) void gemm_ntw_kernel(
    const ushort* __restrict__ A, int lda,
    const ushort* __restrict__ Bt, int ldb,
    void* __restrict__ C, int ldc, int K,
    const float* __restrict__ bias,
    const float* __restrict__ resid, int relu)
{
    __shared__ __attribute__((aligned(16))) ushort As[2][4][128][8];
    __shared__ __attribute__((aligned(16))) ushort Bs[2][4][256][8];

    int nwg  = gridDim.x * gridDim.y;
    int orig = blockIdx.y * gridDim.x + blockIdx.x;
    int work = (orig & 7) * (nwg >> 3) + (orig >> 3);
    int bx = work % gridDim.x, by = work / gridDim.x;

    int row0 = by * 128, col0 = bx * 256;
    int tid = threadIdx.x;
    int w = tid >> 6, l = tid & 63;
    int wr = (w >> 1) * 64, wc = (w & 1) * 128;

    int m0 = tid & 127, kc0 = tid >> 7;
    const ushort* gA = A  + (size_t)(row0 + m0) * lda + kc0 * 8;
    const ushort* gB = Bt + (size_t)(col0 + tid) * ldb;

    f32x4 acc[4][8];
    #pragma unroll
    for (int i = 0; i < 4; ++i)
        #pragma unroll
        for (int j = 0; j < 8; ++j) acc[i][j] = (f32x4){0.f, 0.f, 0.f, 0.f};

    const int NT = K >> 5;
    g2l16(gA,      &As[0][kc0    ][m0][0]);
    g2l16(gA + 16, &As[0][kc0 + 2][m0][0]);
    #pragma unroll
    for (int p = 0; p < 4; ++p)
        g2l16(gB + p*8, &Bs[0][p][tid][0]);
    __syncthreads();

    int cur = 0;
    for (int t = 0; t < NT; ++t) {
        if (t + 1 < NT) {
            int k0 = (t + 1) << 5;
            g2l16(gA + k0,      &As[cur ^ 1][kc0    ][m0][0]);
            g2l16(gA + k0 + 16, &As[cur ^ 1][kc0 + 2][m0][0]);
            #pragma unroll
            for (int p = 0; p < 4; ++p)
                g2l16(gB + k0 + p*8, &Bs[cur ^ 1][p][tid][0]);
        }
        int kc = l >> 4;
        bf16x8 bfr[8];
        #pragma unroll
        for (int j = 0; j < 8; ++j)
            bfr[j] = *(const bf16x8*)&Bs[cur][kc][wc + j*16 + (l & 15)][0];
        #pragma unroll
        for (int i = 0; i < 4; ++i) {
            bf16x8 a = *(const bf16x8*)&As[cur][kc][wr + i*16 + (l & 15)][0];
            #pragma unroll
            for (int j = 0; j < 8; ++j)
                acc[i][j] = __builtin_amdgcn_mfma_f32_16x16x32_bf16(
                    a, bfr[j], acc[i][j], 0, 0, 0);
        }
        __syncthreads();
        cur ^= 1;
    }

    #pragma unroll
    for (int i = 0; i < 4; ++i) {
        int rbase = row0 + wr + i*16 + (l >> 4) * 4;
        #pragma unroll
        for (int j = 0; j < 8; ++j) {
            int col = col0 + wc + j*16 + (l & 15);
            float bv = bias ? bias[col] : 0.f;
            #pragma unroll
            for (int r = 0; r < 4; ++r) {
                int row = rbase + r;
                float val = acc[i][j][r] + bv;
                if (resid) val += resid[(size_t)row * ldc + col];
                if (relu)  val = fmaxf(val, 0.f);
                if (OUT_BF16) ((ushort*)C)[(size_t)row * ldc + col] = f2bf(val);
                else          ((float*)C)[(size_t)row * ldc + col]  = val;
            }
        }
    }
}

// ---------------------------------------------------------------------------
// 128x128 NT GEMM, BK=32, 2-phase dbuf, 32KB LDS, split-K via blockIdx.z.
// ---------------------------------------------------------------------------
template<int OUT_BF16>
__global__ __launch_bounds__(256) void gemm_nt_kernel(
    const ushort* __restrict__ A, int lda,
    const ushort* __restrict__ Bt, int ldb,
    void* __restrict__ C, int ldc, int K,
    const float* __restrict__ bias,
    const float* __restrict__ resid, int relu,
    long aZoff, long bZoff, long cZoff)
{
    __shared__ __attribute__((aligned(16))) ushort As[2][4][128][8];
    __shared__ __attribute__((aligned(16))) ushort Bs[2][4][128][8];

    A  += (size_t)blockIdx.z * aZoff;
    Bt += (size_t)blockIdx.z * bZoff;
    char* Cb = (char*)C + (size_t)blockIdx.z * cZoff * (OUT_BF16 ? 2 : 4);

    int nwg  = gridDim.x * gridDim.y;
    int orig = blockIdx.y * gridDim.x + blockIdx.x;
    int work = (orig & 7) * (nwg >> 3) + (orig >> 3);
    int bx = work % gridDim.x, by = work / gridDim.x;

    int row0 = by * 128, col0 = bx * 128;
    int tid = threadIdx.x;
    int w = tid >> 6, l = tid & 63;
    int wr = (w >> 1) * 64, wc = (w & 1) * 64;

    int m0 = tid & 127, kc0 = tid >> 7;
    const ushort* ga0 = A  + (size_t)(row0 + m0) * lda + kc0 * 8;
    const ushort* gb0 = Bt + (size_t)(col0 + m0) * ldb + kc0 * 8;

    f32x4 acc[4][4];
    #pragma unroll
    for (int i = 0; i < 4; ++i)
        #pragma unroll
        for (int j = 0; j < 4; ++j) acc[i][j] = (f32x4){0.f, 0.f, 0.f, 0.f};

    const int NT = K >> 5;
    g2l16(ga0,      &As[0][kc0    ][m0][0]);
    g2l16(ga0 + 16, &As[0][kc0 + 2][m0][0]);
    g2l16(gb0,      &Bs[0][kc0    ][m0][0]);
    g2l16(gb0 + 16, &Bs[0][kc0 + 2][m0][0]);
    __syncthreads();

    int cur = 0;
    for (int t = 0; t < NT; ++t) {
        if (t + 1 < NT) {
            int k0 = (t + 1) << 5;
            g2l16(ga0 + k0,      &As[cur ^ 1][kc0    ][m0][0]);
            g2l16(ga0 + k0 + 16, &As[cur ^ 1][kc0 + 2][m0][0]);
            g2l16(gb0 + k0,      &Bs[cur ^ 1][kc0    ][m0][0]);
            g2l16(gb0 + k0 + 16, &Bs[cur ^ 1][kc0 + 2][m0][0]);
        }
        int kc = l >> 4;
        bf16x8 af[4], bfr[4];
        #pragma unroll
        for (int i = 0; i < 4; ++i)
            af[i] = *(const bf16x8*)&As[cur][kc][wr + i*16 + (l & 15)][0];
        #pragma unroll
        for (int j = 0; j < 4; ++j)
            bfr[j] = *(const bf16x8*)&Bs[cur][kc][wc + j*16 + (l & 15)][0];
        #pragma unroll
        for (int i = 0; i < 4; ++i)
            #pragma unroll
            for (int j = 0; j < 4; ++j)
                acc[i][j] = __builtin_amdgcn_mfma_f32_16x16x32_bf16(
                    af[i], bfr[j], acc[i][j], 0, 0, 0);
        __syncthreads();
        cur ^= 1;
    }

    #pragma unroll
    for (int i = 0; i < 4; ++i) {
        int rbase = row0 + wr + i*16 + (l >> 4) * 4;
        #pragma unroll
        for (int j = 0; j < 4; ++j) {
            int col = col0 + wc + j*16 + (l & 15);
            float bv = bias ? bias[col] : 0.f;
            #pragma unroll
            for (int r = 0; r < 4; ++r) {
                int row = rbase + r;
                float val = acc[i][j][r] + bv;
                if (resid) val += resid[(size_t)row * ldc + col];
                if (relu)  val = fmaxf(val, 0.f);
                if (OUT_BF16) ((ushort*)Cb)[(size_t)row * ldc + col] = f2bf(val);
                else          ((float*)Cb)[(size_t)row * ldc + col]  = val;
            }
        }
    }
}

// ---------------------------------------------------------------------------
// csum + vscale fused, Q-tile dbuf, XCD swizzle. (unchanged from R12)
// ---------------------------------------------------------------------------
__global__ __launch_bounds__(256) void csumv_kernel(
    const ushort* __restrict__ qkv, ushort* __restrict__ vt)
{
    int nwg  = gridDim.x * gridDim.y;
    int orig = blockIdx.y * gridDim.x + blockIdx.x;
    int work = (orig & 7) * (nwg >> 3) + (orig >> 3);
    int bx = work % gridDim.x;
    int bh = work / gridDim.x;
    int b = bh >> 4, h = bh & 15;
    int s0 = bx * 128;
    const ushort* qb = qkv + (size_t)b * T_ * 3072 + h * 64;
    const ushort* kb = qb + 1024;
    const ushort* vb = qb + 2048;
    __shared__ __attribute__((aligned(16))) ushort Ks[8][128][8];
    __shared__ __attribute__((aligned(16))) ushort Qs[2][8][64][8];
    __shared__ float csl[128];
    __shared__ float t[64][65];
    int tid = threadIdx.x, w = tid >> 6, l = tid & 63;
    int scol = w * 32;
    int qq0 = l, kcA = w, kcB = w + 4;

    #pragma unroll
    for (int p = 0; p < 4; ++p) {
        int idx = tid + p * 256;
        int s = idx & 127, kc = idx >> 7;
        *(uint4*)&Ks[kc][s][0] =
            *(const uint4*)(kb + (size_t)(s0 + s) * 3072 + kc * 8);
    }
    g2l16(qb + (size_t)qq0 * 3072 + kcA * 8, &Qs[0][kcA][qq0][0]);
    g2l16(qb + (size_t)qq0 * 3072 + kcB * 8, &Qs[0][kcB][qq0][0]);
    __syncthreads();

    float cs[2] = {0.f, 0.f};
    int cur = 0;
    for (int qt = 0; qt < T_ / 64; ++qt) {
        if (qt + 1 < T_ / 64) {
            const ushort* qn = qb + (size_t)((qt + 1) * 64 + qq0) * 3072;
            g2l16(qn + kcA * 8, &Qs[cur ^ 1][kcA][qq0][0]);
            g2l16(qn + kcB * 8, &Qs[cur ^ 1][kcB][qq0][0]);
        }
        bf16x8 af[4][2], bfr[2][2];
        #pragma unroll
        for (int qi = 0; qi < 4; ++qi)
            #pragma unroll
            for (int ks = 0; ks < 2; ++ks)
                af[qi][ks] = *(const bf16x8*)&Qs[cur][ks*4 + (l>>4)][qi*16 + (l & 15)][0];
        #pragma unroll
        for (int sj = 0; sj < 2; ++sj)
            #pragma unroll
            for (int ks = 0; ks < 2; ++ks)
                bfr[sj][ks] = *(const bf16x8*)&Ks[ks*4 + (l>>4)][scol + sj*16 + (l & 15)][0];
        #pragma unroll
        for (int qi = 0; qi < 4; ++qi)
            #pragma unroll
            for (int sj = 0; sj < 2; ++sj) {
                f32x4 d = (f32x4){0.f, 0.f, 0.f, 0.f};
                #pragma unroll
                for (int ks = 0; ks < 2; ++ks)
                    d = __builtin_amdgcn_mfma_f32_16x16x32_bf16(
                        af[qi][ks], bfr[sj][ks], d, 0, 0, 0);
                cs[sj] += __expf(d[0]*0.125f) + __expf(d[1]*0.125f)
                        + __expf(d[2]*0.125f) + __expf(d[3]*0.125f);
            }
        __syncthreads();
        cur ^= 1;
    }
    #pragma unroll
    for (int sj = 0; sj < 2; ++sj) {
        float v = cs[sj];
        v += __shfl_down(v, 32, 64);
        v += __shfl_down(v, 16, 64);
        if (l < 16) csl[scol + sj*16 + l] = v;
    }
    __syncthreads();

    #pragma unroll
    for (int p2 = 0; p2 < 2; ++p2) {
        int sb = s0 + p2 * 64;
        #pragma unroll
        for (int p = 0; p < 2; ++p) {
            int idx = tid + p * 256;
            int s = idx >> 3, c0 = (idx & 7) * 8;
            uint4 raw = *(const uint4*)(vb + (size_t)(sb + s) * 3072 + c0);
            float rc = 1.0f / csl[p2 * 64 + s];
            ushort* u = (ushort*)&raw;
            #pragma unroll
            for (int i = 0; i < 8; ++i) t[s][c0 + i] = bf2f(u[i]) * rc;
        }
        __syncthreads();
        #pragma unroll
        for (int p = 0; p < 2; ++p) {
            int idx = tid + p * 256;
            int dv = idx >> 3, sc = (idx & 7) * 8;
            ushort o[8];
            #pragma unroll
            for (int i = 0; i < 8; ++i) o[i] = f2bf(t[sc + i][dv]);
            *(uint4*)(vt + ((size_t)bh * 64 + dv) * T_ + sb + sc) = *(uint4*)o;
        }
        __syncthreads();
    }
}

// ---------------------------------------------------------------------------
// PV: QBLK=128, K/V dbuf, Q in regs, XCD swizzle.
// SWAPPED QK^T: mfma(K,Q) -> lane holds 4 consecutive s at fixed q ->
// exp + pack -> one 8B ds_write_b64 into Es[q][s] (16B-chunk XOR swizzle).
// PV reads Es as A-fragment (vector, conflict-free). Es rows wave-private.
// ---------------------------------------------------------------------------
__global__ __launch_bounds__(256) void attn_pv_kernel(
    const ushort* __restrict__ qkv, const ushort* __restrict__ vt,
    ushort* __restrict__ attn_o)
{
    int nwg  = gridDim.x * gridDim.y;
    int orig = blockIdx.y * gridDim.x + blockIdx.x;
    int work = (orig & 7) * (nwg >> 3) + (orig >> 3);
    int bx = work % gridDim.x;
    int bh = work / gridDim.x;
    int b = bh >> 4, h = bh & 15;
    int q0 = bx * 128;
    const ushort* qb = qkv + (size_t)b * T_ * 3072 + h * 64;
    const ushort* kb = qb + 1024;
    const ushort* vtb = vt + (size_t)bh * 64 * T_;
    __shared__ __attribute__((aligned(16))) ushort Ks[2][8][64][8];
    __shared__ __attribute__((aligned(16))) ushort Vs[2][8][64][8];
    __shared__ __attribute__((aligned(16))) ushort Es[128][64]; // [q][s], swizzled
    int tid = threadIdx.x, w = tid >> 6, l = tid & 63;
    int wq = w * 32;
    int kcA = w, kcB = w + 4;

    // Q fragments (used as B-operand of swapped QK^T; same [row][kchunk] layout)
    bf16x8 qf[2][2];
    #pragma unroll
    for (int qt = 0; qt < 2; ++qt)
        #pragma unroll
        for (int ks = 0; ks < 2; ++ks)
            qf[qt][ks] = *(const bf16x8*)(qb
                + (size_t)(q0 + wq + qt*16 + (l & 15)) * 3072
                + (ks*4 + (l >> 4)) * 8);

    f32x4 oacc[2][4];
    #pragma unroll
    for (int qt = 0; qt < 2; ++qt)
        #pragma unroll
        for (int j = 0; j < 4; ++j) oacc[qt][j] = (f32x4){0.f, 0.f, 0.f, 0.f};

    const int NT = T_ / 64;
    g2l16(kb + (size_t)l * 3072 + kcA * 8, &Ks[0][kcA][l][0]);
    g2l16(kb + (size_t)l * 3072 + kcB * 8, &Ks[0][kcB][l][0]);
    g2l16(vtb + (size_t)l * T_ + kcA * 8,  &Vs[0][kcA][l][0]);
    g2l16(vtb + (size_t)l * T_ + kcB * 8,  &Vs[0][kcB][l][0]);
    __syncthreads();

    int cur = 0;
    for (int st = 0; st < NT; ++st) {
        if (st + 1 < NT) {
            int s1 = (st + 1) * 64;
            g2l16(kb + (size_t)(s1 + l) * 3072 + kcA * 8, &Ks[cur^1][kcA][l][0]);
            g2l16(kb + (size_t)(s1 + l) * 3072 + kcB * 8, &Ks[cur^1][kcB][l][0]);
            g2l16(vtb + (size_t)l * T_ + s1 + kcA * 8,    &Vs[cur^1][kcA][l][0]);
            g2l16(vtb + (size_t)l * T_ + s1 + kcB * 8,    &Vs[cur^1][kcB][l][0]);
        }
        // QK^T swapped: D[s][q]; lane: q = wq+qt*16+(l&15), s = sj*16+(l>>4)*4+r
        #pragma unroll
        for (int sj = 0; sj < 4; ++sj) {
            bf16x8 kfa[2];
            #pragma unroll
            for (int ks = 0; ks < 2; ++ks)
                kfa[ks] = *(const bf16x8*)&Ks[cur][ks*4 + (l>>4)][sj*16 + (l & 15)][0];
            #pragma unroll
            for (int qt = 0; qt < 2; ++qt) {
                f32x4 d = (f32x4){0.f, 0.f, 0.f, 0.f};
                #pragma unroll
                for (int ks = 0; ks < 2; ++ks)
                    d = __builtin_amdgcn_mfma_f32_16x16x32_bf16(
                        kfa[ks], qf[qt][ks], d, 0, 0, 0);
                int row = wq + qt*16 + (l & 15);
                int c16 = sj*2 + ((l >> 4) >> 1);     // 16B chunk (s/8)
                int sub = (l >> 4) & 1;               // 8B half within chunk
                uint2 pv2;
                pv2.x = pk2(__expf(d[0]*0.125f), __expf(d[1]*0.125f));
                pv2.y = pk2(__expf(d[2]*0.125f), __expf(d[3]*0.125f));
                *(uint2*)((char*)Es + row*128 + ((c16 ^ (row & 7))*16 + sub*8)) = pv2;
            }
        }
        // PV: A-frag from Es (row = q, kchunk = s), B = Vt
        bf16x8 efa[2][2];
        #pragma unroll
        for (int qt = 0; qt < 2; ++qt) {
            int row = wq + qt*16 + (l & 15);
            #pragma unroll
            for (int ks = 0; ks < 2; ++ks)
                efa[qt][ks] = *(const bf16x8*)((char*)Es + row*128
                    + (((ks*4 + (l >> 4)) ^ (row & 7))*16));
        }
        #pragma unroll
        for (int j = 0; j < 4; ++j)
            #pragma unroll
            for (int ks = 0; ks < 2; ++ks) {
                bf16x8 vf = *(const bf16x8*)&Vs[cur][ks*4 + (l>>4)][j*16 + (l & 15)][0];
                #pragma unroll
                for (int qt = 0; qt < 2; ++qt)
                    oacc[qt][j] = __builtin_amdgcn_mfma_f32_16x16x32_bf16(
                        efa[qt][ks], vf, oacc[qt][j], 0, 0, 0);
            }
        __syncthreads();
        cur ^= 1;
    }

    #pragma unroll
    for (int qt = 0; qt < 2; ++qt)
        #pragma unroll
        for (int j = 0; j < 4; ++j)
            #pragma unroll
            for (int r = 0; r < 4; ++r) {
                int qq = q0 + wq + qt*16 + (l>>4)*4 + r;
                int dv = j*16 + (l & 15);
                attn_o[(size_t)(b*T_ + qq) * 1024 + h*64 + dv] = f2bf(oacc[qt][j][r]);
            }
}

// ---------------------------------------------------------------------------
// fused norm
// ---------------------------------------------------------------------------
__device__ __forceinline__ float block_reduce_sum_256(float v, float* tmp)
{
    #pragma unroll
    for (int off = 32; off; off >>= 1) v += __shfl_down(v, off, 64);
    int lane = threadIdx.x & 63, w = threadIdx.x >> 6;
    __syncthreads();
    if (lane == 0) tmp[w] = v;
    __syncthreads();
    return tmp[0] + tmp[1] + tmp[2] + tmp[3];
}

template<int Z>
__global__ __launch_bounds__(256) void normZ_fused_kernel(
    const ushort* __restrict__ parts, long zoff,
    const float* __restrict__ bias, const float* __restrict__ resid,
    float* __restrict__ outf, ushort* __restrict__ outb)
{
    __shared__ float tmp[4];
    int row = blockIdx.x;
    int tid = threadIdx.x;
    int c0 = tid * 4;
    size_t idx = (size_t)row * D_ + c0;
    float vals[4] = {0.f, 0.f, 0.f, 0.f};
    #pragma unroll
    for (int z = 0; z < Z; ++z) {
        ushort4 p = *(const ushort4*)&parts[idx + (size_t)z * zoff];
        vals[0] += bf2f(p.x); vals[1] += bf2f(p.y);
        vals[2] += bf2f(p.z); vals[3] += bf2f(p.w);
    }
    float4 rv = *(const float4*)&resid[idx];
    vals[0] += rv.x; vals[1] += rv.y; vals[2] += rv.z; vals[3] += rv.w;
    if (bias) {
        float4 bv = *(const float4*)&bias[c0];
        vals[0] += bv.x; vals[1] += bv.y; vals[2] += bv.z; vals[3] += bv.w;
    }
    float s = vals[0] + vals[1] + vals[2] + vals[3];
    s = block_reduce_sum_256(s, tmp);
    float m = s * (1.0f / (float)D_);
    float sq = 0.f;
    #pragma unroll
    for (int i = 0; i < 4; ++i) { float c = vals[i] - m; sq += c * c; }
    sq = block_reduce_sum_256(sq, tmp);
    float rs = rsqrtf(sq * (1.0f / (float)(D_ - 1)));
    float4 o;
    o.x = (vals[0] - m) * rs; o.y = (vals[1] - m) * rs;
    o.z = (vals[2] - m) * rs; o.w = (vals[3] - m) * rs;
    *(float4*)&outf[idx] = o;
    if (outb) {
        ushort4 ob;
        ob.x = f2bf(o.x); ob.y = f2bf(o.y); ob.z = f2bf(o.z); ob.w = f2bf(o.w);
        *(ushort4*)&outb[idx] = ob;
    }
}

// ---------------------------------------------------------------------------
extern "C" void kernel_launch(void* const* d_in, const int* in_sizes, int n_in,
                              void* d_out, int out_size, void* d_ws, size_t ws_size,
                              hipStream_t stream)
{
    const float* x  = (const float*)d_in[0];
    const float* Wq = (const float*)d_in[1];
    const float* Wk = (const float*)d_in[2];
    const float* Wv = (const float*)d_in[3];
    const float* Wo = (const float*)d_in[4];
    const float* W1 = (const float*)d_in[5];
    const float* b1 = (const float*)d_in[6];
    const float* W2 = (const float*)d_in[7];
    const float* b2 = (const float*)d_in[8];
    float* out = (float*)d_out;

    const size_t MB = (size_t)1 << 20;
    char* base = (char*)d_ws;
    ushort* qkv    = (ushort*)(base +   0*MB);  // 24MB  [QKV..PV]
    ushort* hid    = (ushort*)(base +   0*MB);  // 32MB  [W1..W2]
    ushort* xb     = (ushort*)(base +  24*MB);  //  8MB  [cvt..QKV]
    ushort* W2t    = (ushort*)(base +  32*MB);  //  8MB  [cvt..W2]
    ushort* Wqkvt  = (ushort*)(base +  40*MB);  //  6MB  [cvt..QKV]
    ushort* wpart  = (ushort*)(base +  40*MB);  // 16MB  [W2..norm2]
    ushort* vt     = (ushort*)(base +  46*MB);  //  8MB  [csumv..PV]
    ushort* Wot    = (ushort*)(base +  55*MB);  //  2MB  [cvt..Wo]
    ushort* W1t    = (ushort*)(base +  57*MB);  //  8MB  [cvt..W1]
    ushort* attn_o = (ushort*)(base +  65*MB);  //  8MB  [PV..Wo]
    ushort* wopart = (ushort*)(base +  73*MB);  // 16MB  [Wo..norm1]
    ushort* out1b  = (ushort*)(base +  89*MB);  //  8MB  [norm1..W1]
    float*  out1f  = (float*) (base +  97*MB);  // 16MB  [norm1..norm2]

    // 1. converts / transposes
    cvt_bf16_kernel<<<dim3(BT_*D_/1024), 256, 0, stream>>>(x, xb, BT_*D_);
    transpose_qkv_kernel<<<dim3(2, 32, 48), 256, 0, stream>>>(Wq, Wk, Wv, Wqkvt);
    transpose_bf16_kernel<<<dim3(32, 32, 1), 256, 0, stream>>>(
        Wo, Wot, 1024, 1024, 0, 0);
    transpose_bf16_kernel<<<dim3(128, 32, 1), 256, 0, stream>>>(
        W1, W1t, 1024, 4096, 0, 0);
    transpose_bf16_kernel<<<dim3(32, 128, 1), 256, 0, stream>>>(
        W2, W2t, 4096, 1024, 0, 0);

    // 2. QKV: wide tile, 384 blocks.
    gemm_ntw_kernel<1><<<dim3(3072/256, 4096/128), 256, 0, stream>>>(
        xb, 1024, Wqkvt, 1024, qkv, 3072, 1024, nullptr, nullptr, 0);
    // 3. colsum + V-scale/transpose fused (Q dbuf, XCD swizzle)
    csumv_kernel<<<dim3(T_/128, B_*H_), 256, 0, stream>>>(qkv, vt);
    // 4. PV: QBLK=128, K/V dbuf, XCD swizzle, swapped-QK^T packed-E. 512 blocks.
    attn_pv_kernel<<<dim3(T_/128, B_*H_), 256, 0, stream>>>(qkv, vt, attn_o);
    // 5. Wo split-K2 -> bf16 partials. 512 blocks.
    gemm_nt_kernel<1><<<dim3(1024/128, 4096/128, 2), 256, 0, stream>>>(
        attn_o, 1024, Wot, 1024, wopart, 1024, 512, nullptr, nullptr, 0,
        512, 512, (long)4096*1024);
    // 6. norm1 fused: sum 2 partials + x resid -> out1f + out1b
    normZ_fused_kernel<2><<<dim3(BT_), 256, 0, stream>>>(
        wopart, (long)4096*1024, nullptr, x, out1f, out1b);
    // 7. FFN up + ReLU: wide tile, 512 blocks.
    gemm_ntw_kernel<1><<<dim3(4096/256, 4096/128), 256, 0, stream>>>(
        out1b, 1024, W1t, 1024, hid, 4096, 1024, b1, nullptr, 1);
    // 8. FFN down split-K2 -> bf16 partials. 512 blocks, NT=64.
    gemm_nt_kernel<1><<<dim3(1024/128, 4096/128, 2), 256, 0, stream>>>(
        hid, 4096, W2t, 4096, wpart, 1024, 2048, nullptr, nullptr, 0,
        2048, 2048, (long)4096*1024);
    // 9. norm2 fused: sum 2 partials + b2 + out1 resid -> out
    normZ_fused_kernel<2><<<dim3(BT_), 256, 0, stream>>>(
        wpart, (long)4096*1024, b2, out1f, out, nullptr);
}

// Round 14
// 364.604 us; speedup vs baseline: 1.3673x; 1.0101x over previous
//
#include <hip/hip_runtime.h>
#include <hip/hip_bf16.h>
#include <math.h>

#define B_  2
#define T_  2048
#define D_  1024
#define H_  16
#define DK_ 64
#define FF_ 4096
#define BT_ (B_*T_)

typedef __attribute__((ext_vector_type(8))) short bf16x8;
typedef __attribute__((ext_vector_type(4))) float f32x4;

__device__ __forceinline__ ushort f2bf(float f) {
    __hip_bfloat16 h = __float2bfloat16(f);
    return *reinterpret_cast<ushort*>(&h);
}
__device__ __forceinline__ float bf2f(ushort u) {
    __hip_bfloat16 h;
    *reinterpret_cast<ushort*>(&h) = u;
    return __bfloat162float(h);
}
__device__ __forceinline__ uint pk2(float a, float b) {
    return (uint)f2bf(a) | ((uint)f2bf(b) << 16);
}

// async global->LDS, 16B per lane. LDS dest must be wave-uniform base + lane*16.
__device__ __forceinline__ void g2l16(const ushort* g, ushort* l) {
    __builtin_amdgcn_global_load_lds(
        (const __attribute__((address_space(1))) void*)g,
        (__attribute__((address_space(3))) void*)l, 16, 0, 0);
}

// ---------------------------------------------------------------------------
// f32 -> bf16 elementwise
// ---------------------------------------------------------------------------
__global__ __launch_bounds__(256) void cvt_bf16_kernel(
    const float* __restrict__ in, ushort* __restrict__ out, int n)
{
    int i = (blockIdx.x * 256 + threadIdx.x) * 4;
    if (i >= n) return;
    float4 v = *(const float4*)(in + i);
    ushort4 o;
    o.x = f2bf(v.x); o.y = f2bf(v.y); o.z = f2bf(v.z); o.w = f2bf(v.w);
    *(ushort4*)(out + i) = o;
}

// ---------------------------------------------------------------------------
// transpose + convert: in f32 [K][N] -> out bf16 [N][K]; batched over z.
// ---------------------------------------------------------------------------
__global__ __launch_bounds__(256) void transpose_bf16_kernel(
    const float* __restrict__ in, ushort* __restrict__ out,
    int K, int N, long in_bstride, long out_bstride)
{
    __shared__ float t[32][33];
    const float* ib = in + (size_t)blockIdx.z * in_bstride;
    ushort* ob = out + (size_t)blockIdx.z * out_bstride;
    int n0 = blockIdx.x * 32, k0 = blockIdx.y * 32;
    int tid = threadIdx.x;
    int r = tid >> 3, c4 = (tid & 7) * 4;
    float4 v = *(const float4*)(ib + (size_t)(k0 + r) * N + n0 + c4);
    t[r][c4] = v.x; t[r][c4+1] = v.y; t[r][c4+2] = v.z; t[r][c4+3] = v.w;
    __syncthreads();
    int n = tid >> 3, kc = (tid & 7) * 4;
    ushort4 o;
    o.x = f2bf(t[kc+0][n]); o.y = f2bf(t[kc+1][n]);
    o.z = f2bf(t[kc+2][n]); o.w = f2bf(t[kc+3][n]);
    *(ushort4*)(ob + (size_t)(n0 + n) * K + k0 + kc) = o;
}

// fused Wq/Wk/Wv transpose: z in [0,48): mat = z>>4, head = z&15.
__global__ __launch_bounds__(256) void transpose_qkv_kernel(
    const float* __restrict__ Wq, const float* __restrict__ Wk,
    const float* __restrict__ Wv, ushort* __restrict__ outp)
{
    __shared__ float t[32][33];
    int z = blockIdx.z, mat = z >> 4, zz = z & 15;
    const float* ib = (mat == 0 ? Wq : (mat == 1 ? Wk : Wv)) + (size_t)zz * 65536;
    ushort* ob = outp + (size_t)mat * 1048576 + (size_t)zz * 65536;
    int n0 = blockIdx.x * 32, k0 = blockIdx.y * 32;
    int tid = threadIdx.x;
    int r = tid >> 3, c4 = (tid & 7) * 4;
    float4 v = *(const float4*)(ib + (size_t)(k0 + r) * 64 + n0 + c4);
    t[r][c4] = v.x; t[r][c4+1] = v.y; t[r][c4+2] = v.z; t[r][c4+3] = v.w;
    __syncthreads();
    int n = tid >> 3, kc = (tid & 7) * 4;
    ushort4 o;
    o.x = f2bf(t[kc+0][n]); o.y = f2bf(t[kc+1][n]);
    o.z = f2bf(t[kc+2][n]); o.w = f2bf(t[kc+3][n]);
    *(ushort4*)(ob + (size_t)(n0 + n) * 1024 + k0 + kc) = o;
}

// ---------------------------------------------------------------------------
// WIDE 128(M)x256(N) NT GEMM, bf16 MFMA, BK=32, 256 thr (4 waves of 64x128).
// 2-phase dbuf, 48KB LDS. Split-K via blockIdx.z (offsets in elements).
// ---------------------------------------------------------------------------
template<int OUT_BF16>
__global__ __launch_bounds__(256, 2) void gemm_ntw_kernel(
    const ushort* __restrict__ A, int lda,
    const ushort* __restrict__ Bt, int ldb,
    void* __restrict__ C, int ldc, int K,
    const float* __restrict__ bias,
    const float* __restrict__ resid, int relu,
    long aZoff, long bZoff, long cZoff)
{
    __shared__ __attribute__((aligned(16))) ushort As[2][4][128][8];
    __shared__ __attribute__((aligned(16))) ushort Bs[2][4][256][8];

    A  += (size_t)blockIdx.z * aZoff;
    Bt += (size_t)blockIdx.z * bZoff;
    char* Cb = (char*)C + (size_t)blockIdx.z * cZoff * (OUT_BF16 ? 2 : 4);

    int nwg  = gridDim.x * gridDim.y;
    int orig = blockIdx.y * gridDim.x + blockIdx.x;
    int work = (orig & 7) * (nwg >> 3) + (orig >> 3);
    int bx = work % gridDim.x, by = work / gridDim.x;

    int row0 = by * 128, col0 = bx * 256;
    int tid = threadIdx.x;
    int w = tid >> 6, l = tid & 63;
    int wr = (w >> 1) * 64, wc = (w & 1) * 128;

    int m0 = tid & 127, kc0 = tid >> 7;
    const ushort* gA = A  + (size_t)(row0 + m0) * lda + kc0 * 8;
    const ushort* gB = Bt + (size_t)(col0 + tid) * ldb;

    f32x4 acc[4][8];
    #pragma unroll
    for (int i = 0; i < 4; ++i)
        #pragma unroll
        for (int j = 0; j < 8; ++j) acc[i][j] = (f32x4){0.f, 0.f, 0.f, 0.f};

    const int NT = K >> 5;
    g2l16(gA,      &As[0][kc0    ][m0][0]);
    g2l16(gA + 16, &As[0][kc0 + 2][m0][0]);
    #pragma unroll
    for (int p = 0; p < 4; ++p)
        g2l16(gB + p*8, &Bs[0][p][tid][0]);
    __syncthreads();

    int cur = 0;
    for (int t = 0; t < NT; ++t) {
        if (t + 1 < NT) {
            int k0 = (t + 1) << 5;
            g2l16(gA + k0,      &As[cur ^ 1][kc0    ][m0][0]);
            g2l16(gA + k0 + 16, &As[cur ^ 1][kc0 + 2][m0][0]);
            #pragma unroll
            for (int p = 0; p < 4; ++p)
                g2l16(gB + k0 + p*8, &Bs[cur ^ 1][p][tid][0]);
        }
        int kc = l >> 4;
        bf16x8 bfr[8];
        #pragma unroll
        for (int j = 0; j < 8; ++j)
            bfr[j] = *(const bf16x8*)&Bs[cur][kc][wc + j*16 + (l & 15)][0];
        #pragma unroll
        for (int i = 0; i < 4; ++i) {
            bf16x8 a = *(const bf16x8*)&As[cur][kc][wr + i*16 + (l & 15)][0];
            #pragma unroll
            for (int j = 0; j < 8; ++j)
                acc[i][j] = __builtin_amdgcn_mfma_f32_16x16x32_bf16(
                    a, bfr[j], acc[i][j], 0, 0, 0);
        }
        __syncthreads();
        cur ^= 1;
    }

    #pragma unroll
    for (int i = 0; i < 4; ++i) {
        int rbase = row0 + wr + i*16 + (l >> 4) * 4;
        #pragma unroll
        for (int j = 0; j < 8; ++j) {
            int col = col0 + wc + j*16 + (l & 15);
            float bv = bias ? bias[col] : 0.f;
            #pragma unroll
            for (int r = 0; r < 4; ++r) {
                int row = rbase + r;
                float val = acc[i][j][r] + bv;
                if (resid) val += resid[(size_t)row * ldc + col];
                if (relu)  val = fmaxf(val, 0.f);
                if (OUT_BF16) ((ushort*)Cb)[(size_t)row * ldc + col] = f2bf(val);
                else          ((float*)Cb)[(size_t)row * ldc + col]  = val;
            }
        }
    }
}

// ---------------------------------------------------------------------------
// 128x128 NT GEMM, BK=32, 2-phase dbuf, 32KB LDS, split-K via blockIdx.z.
// (kept for Wo)
// ---------------------------------------------------------------------------
template<int OUT_BF16>
__global__ __launch_bounds__(256) void gemm_nt_kernel(
    const ushort* __restrict__ A, int lda,
    const ushort* __restrict__ Bt, int ldb,
    void* __restrict__ C, int ldc, int K,
    const float* __restrict__ bias,
    const float* __restrict__ resid, int relu,
    long aZoff, long bZoff, long cZoff)
{
    __shared__ __attribute__((aligned(16))) ushort As[2][4][128][8];
    __shared__ __attribute__((aligned(16))) ushort Bs[2][4][128][8];

    A  += (size_t)blockIdx.z * aZoff;
    Bt += (size_t)blockIdx.z * bZoff;
    char* Cb = (char*)C + (size_t)blockIdx.z * cZoff * (OUT_BF16 ? 2 : 4);

    int nwg  = gridDim.x * gridDim.y;
    int orig = blockIdx.y * gridDim.x + blockIdx.x;
    int work = (orig & 7) * (nwg >> 3) + (orig >> 3);
    int bx = work % gridDim.x, by = work / gridDim.x;

    int row0 = by * 128, col0 = bx * 128;
    int tid = threadIdx.x;
    int w = tid >> 6, l = tid & 63;
    int wr = (w >> 1) * 64, wc = (w & 1) * 64;

    int m0 = tid & 127, kc0 = tid >> 7;
    const ushort* ga0 = A  + (size_t)(row0 + m0) * lda + kc0 * 8;
    const ushort* gb0 = Bt + (size_t)(col0 + m0) * ldb + kc0 * 8;

    f32x4 acc[4][4];
    #pragma unroll
    for (int i = 0; i < 4; ++i)
        #pragma unroll
        for (int j = 0; j < 4; ++j) acc[i][j] = (f32x4){0.f, 0.f, 0.f, 0.f};

    const int NT = K >> 5;
    g2l16(ga0,      &As[0][kc0    ][m0][0]);
    g2l16(ga0 + 16, &As[0][kc0 + 2][m0][0]);
    g2l16(gb0,      &Bs[0][kc0    ][m0][0]);
    g2l16(gb0 + 16, &Bs[0][kc0 + 2][m0][0]);
    __syncthreads();

    int cur = 0;
    for (int t = 0; t < NT; ++t) {
        if (t + 1 < NT) {
            int k0 = (t + 1) << 5;
            g2l16(ga0 + k0,      &As[cur ^ 1][kc0    ][m0][0]);
            g2l16(ga0 + k0 + 16, &As[cur ^ 1][kc0 + 2][m0][0]);
            g2l16(gb0 + k0,      &Bs[cur ^ 1][kc0    ][m0][0]);
            g2l16(gb0 + k0 + 16, &Bs[cur ^ 1][kc0 + 2][m0][0]);
        }
        int kc = l >> 4;
        bf16x8 af[4], bfr[4];
        #pragma unroll
        for (int i = 0; i < 4; ++i)
            af[i] = *(const bf16x8*)&As[cur][kc][wr + i*16 + (l & 15)][0];
        #pragma unroll
        for (int j = 0; j < 4; ++j)
            bfr[j] = *(const bf16x8*)&Bs[cur][kc][wc + j*16 + (l & 15)][0];
        #pragma unroll
        for (int i = 0; i < 4; ++i)
            #pragma unroll
            for (int j = 0; j < 4; ++j)
                acc[i][j] = __builtin_amdgcn_mfma_f32_16x16x32_bf16(
                    af[i], bfr[j], acc[i][j], 0, 0, 0);
        __syncthreads();
        cur ^= 1;
    }

    #pragma unroll
    for (int i = 0; i < 4; ++i) {
        int rbase = row0 + wr + i*16 + (l >> 4) * 4;
        #pragma unroll
        for (int j = 0; j < 4; ++j) {
            int col = col0 + wc + j*16 + (l & 15);
            float bv = bias ? bias[col] : 0.f;
            #pragma unroll
            for (int r = 0; r < 4; ++r) {
                int row = rbase + r;
                float val = acc[i][j][r] + bv;
                if (resid) val += resid[(size_t)row * ldc + col];
                if (relu)  val = fmaxf(val, 0.f);
                if (OUT_BF16) ((ushort*)Cb)[(size_t)row * ldc + col] = f2bf(val);
                else          ((float*)Cb)[(size_t)row * ldc + col]  = val;
            }
        }
    }
}

// ---------------------------------------------------------------------------
// csum + vscale fused, Q-tile dbuf, XCD swizzle. K-fragments hoisted to
// registers before the qt loop (Ks is read-only after the prologue barrier;
// the in-loop barrier otherwise blocks compiler hoisting).
// ---------------------------------------------------------------------------
__global__ __launch_bounds__(256) void csumv_kernel(
    const ushort* __restrict__ qkv, ushort* __restrict__ vt)
{
    int nwg  = gridDim.x * gridDim.y;
    int orig = blockIdx.y * gridDim.x + blockIdx.x;
    int work = (orig & 7) * (nwg >> 3) + (orig >> 3);
    int bx = work % gridDim.x;
    int bh = work / gridDim.x;
    int b = bh >> 4, h = bh & 15;
    int s0 = bx * 128;
    const ushort* qb = qkv + (size_t)b * T_ * 3072 + h * 64;
    const ushort* kb = qb + 1024;
    const ushort* vb = qb + 2048;
    __shared__ __attribute__((aligned(16))) ushort Ks[8][128][8];
    __shared__ __attribute__((aligned(16))) ushort Qs[2][8][64][8];
    __shared__ float csl[128];
    __shared__ float t[64][65];
    int tid = threadIdx.x, w = tid >> 6, l = tid & 63;
    int scol = w * 32;
    int qq0 = l, kcA = w, kcB = w + 4;

    #pragma unroll
    for (int p = 0; p < 4; ++p) {
        int idx = tid + p * 256;
        int s = idx & 127, kc = idx >> 7;
        *(uint4*)&Ks[kc][s][0] =
            *(const uint4*)(kb + (size_t)(s0 + s) * 3072 + kc * 8);
    }
    g2l16(qb + (size_t)qq0 * 3072 + kcA * 8, &Qs[0][kcA][qq0][0]);
    g2l16(qb + (size_t)qq0 * 3072 + kcB * 8, &Qs[0][kcB][qq0][0]);
    __syncthreads();

    // hoist K fragments (Ks read-only from here on)
    bf16x8 bfr[2][2];
    #pragma unroll
    for (int sj = 0; sj < 2; ++sj)
        #pragma unroll
        for (int ks = 0; ks < 2; ++ks)
            bfr[sj][ks] = *(const bf16x8*)&Ks[ks*4 + (l>>4)][scol + sj*16 + (l & 15)][0];

    float cs[2] = {0.f, 0.f};
    int cur = 0;
    for (int qt = 0; qt < T_ / 64; ++qt) {
        if (qt + 1 < T_ / 64) {
            const ushort* qn = qb + (size_t)((qt + 1) * 64 + qq0) * 3072;
            g2l16(qn + kcA * 8, &Qs[cur ^ 1][kcA][qq0][0]);
            g2l16(qn + kcB * 8, &Qs[cur ^ 1][kcB][qq0][0]);
        }
        bf16x8 af[4][2];
        #pragma unroll
        for (int qi = 0; qi < 4; ++qi)
            #pragma unroll
            for (int ks = 0; ks < 2; ++ks)
                af[qi][ks] = *(const bf16x8*)&Qs[cur][ks*4 + (l>>4)][qi*16 + (l & 15)][0];
        #pragma unroll
        for (int qi = 0; qi < 4; ++qi)
            #pragma unroll
            for (int sj = 0; sj < 2; ++sj) {
                f32x4 d = (f32x4){0.f, 0.f, 0.f, 0.f};
                #pragma unroll
                for (int ks = 0; ks < 2; ++ks)
                    d = __builtin_amdgcn_mfma_f32_16x16x32_bf16(
                        af[qi][ks], bfr[sj][ks], d, 0, 0, 0);
                cs[sj] += __expf(d[0]*0.125f) + __expf(d[1]*0.125f)
                        + __expf(d[2]*0.125f) + __expf(d[3]*0.125f);
            }
        __syncthreads();
        cur ^= 1;
    }
    #pragma unroll
    for (int sj = 0; sj < 2; ++sj) {
        float v = cs[sj];
        v += __shfl_down(v, 32, 64);
        v += __shfl_down(v, 16, 64);
        if (l < 16) csl[scol + sj*16 + l] = v;
    }
    __syncthreads();

    #pragma unroll
    for (int p2 = 0; p2 < 2; ++p2) {
        int sb = s0 + p2 * 64;
        #pragma unroll
        for (int p = 0; p < 2; ++p) {
            int idx = tid + p * 256;
            int s = idx >> 3, c0 = (idx & 7) * 8;
            uint4 raw = *(const uint4*)(vb + (size_t)(sb + s) * 3072 + c0);
            float rc = 1.0f / csl[p2 * 64 + s];
            ushort* u = (ushort*)&raw;
            #pragma unroll
            for (int i = 0; i < 8; ++i) t[s][c0 + i] = bf2f(u[i]) * rc;
        }
        __syncthreads();
        #pragma unroll
        for (int p = 0; p < 2; ++p) {
            int idx = tid + p * 256;
            int dv = idx >> 3, sc = (idx & 7) * 8;
            ushort o[8];
            #pragma unroll
            for (int i = 0; i < 8; ++i) o[i] = f2bf(t[sc + i][dv]);
            *(uint4*)(vt + ((size_t)bh * 64 + dv) * T_ + sb + sc) = *(uint4*)o;
        }
        __syncthreads();
    }
}

// ---------------------------------------------------------------------------
// PV: QBLK=128, K/V dbuf, Q in regs, XCD swizzle, swapped-QK^T packed-E.
// ---------------------------------------------------------------------------
__global__ __launch_bounds__(256) void attn_pv_kernel(
    const ushort* __restrict__ qkv, const ushort* __restrict__ vt,
    ushort* __restrict__ attn_o)
{
    int nwg  = gridDim.x * gridDim.y;
    int orig = blockIdx.y * gridDim.x + blockIdx.x;
    int work = (orig & 7) * (nwg >> 3) + (orig >> 3);
    int bx = work % gridDim.x;
    int bh = work / gridDim.x;
    int b = bh >> 4, h = bh & 15;
    int q0 = bx * 128;
    const ushort* qb = qkv + (size_t)b * T_ * 3072 + h * 64;
    const ushort* kb = qb + 1024;
    const ushort* vtb = vt + (size_t)bh * 64 * T_;
    __shared__ __attribute__((aligned(16))) ushort Ks[2][8][64][8];
    __shared__ __attribute__((aligned(16))) ushort Vs[2][8][64][8];
    __shared__ __attribute__((aligned(16))) ushort Es[128][64]; // [q][s], swizzled
    int tid = threadIdx.x, w = tid >> 6, l = tid & 63;
    int wq = w * 32;
    int kcA = w, kcB = w + 4;

    bf16x8 qf[2][2];
    #pragma unroll
    for (int qt = 0; qt < 2; ++qt)
        #pragma unroll
        for (int ks = 0; ks < 2; ++ks)
            qf[qt][ks] = *(const bf16x8*)(qb
                + (size_t)(q0 + wq + qt*16 + (l & 15)) * 3072
                + (ks*4 + (l >> 4)) * 8);

    f32x4 oacc[2][4];
    #pragma unroll
    for (int qt = 0; qt < 2; ++qt)
        #pragma unroll
        for (int j = 0; j < 4; ++j) oacc[qt][j] = (f32x4){0.f, 0.f, 0.f, 0.f};

    const int NT = T_ / 64;
    g2l16(kb + (size_t)l * 3072 + kcA * 8, &Ks[0][kcA][l][0]);
    g2l16(kb + (size_t)l * 3072 + kcB * 8, &Ks[0][kcB][l][0]);
    g2l16(vtb + (size_t)l * T_ + kcA * 8,  &Vs[0][kcA][l][0]);
    g2l16(vtb + (size_t)l * T_ + kcB * 8,  &Vs[0][kcB][l][0]);
    __syncthreads();

    int cur = 0;
    for (int st = 0; st < NT; ++st) {
        if (st + 1 < NT) {
            int s1 = (st + 1) * 64;
            g2l16(kb + (size_t)(s1 + l) * 3072 + kcA * 8, &Ks[cur^1][kcA][l][0]);
            g2l16(kb + (size_t)(s1 + l) * 3072 + kcB * 8, &Ks[cur^1][kcB][l][0]);
            g2l16(vtb + (size_t)l * T_ + s1 + kcA * 8,    &Vs[cur^1][kcA][l][0]);
            g2l16(vtb + (size_t)l * T_ + s1 + kcB * 8,    &Vs[cur^1][kcB][l][0]);
        }
        #pragma unroll
        for (int sj = 0; sj < 4; ++sj) {
            bf16x8 kfa[2];
            #pragma unroll
            for (int ks = 0; ks < 2; ++ks)
                kfa[ks] = *(const bf16x8*)&Ks[cur][ks*4 + (l>>4)][sj*16 + (l & 15)][0];
            #pragma unroll
            for (int qt = 0; qt < 2; ++qt) {
                f32x4 d = (f32x4){0.f, 0.f, 0.f, 0.f};
                #pragma unroll
                for (int ks = 0; ks < 2; ++ks)
                    d = __builtin_amdgcn_mfma_f32_16x16x32_bf16(
                        kfa[ks], qf[qt][ks], d, 0, 0, 0);
                int row = wq + qt*16 + (l & 15);
                int c16 = sj*2 + ((l >> 4) >> 1);
                int sub = (l >> 4) & 1;
                uint2 pv2;
                pv2.x = pk2(__expf(d[0]*0.125f), __expf(d[1]*0.125f));
                pv2.y = pk2(__expf(d[2]*0.125f), __expf(d[3]*0.125f));
                *(uint2*)((char*)Es + row*128 + ((c16 ^ (row & 7))*16 + sub*8)) = pv2;
            }
        }
        bf16x8 efa[2][2];
        #pragma unroll
        for (int qt = 0; qt < 2; ++qt) {
            int row = wq + qt*16 + (l & 15);
            #pragma unroll
            for (int ks = 0; ks < 2; ++ks)
                efa[qt][ks] = *(const bf16x8*)((char*)Es + row*128
                    + (((ks*4 + (l >> 4)) ^ (row & 7))*16));
        }
        #pragma unroll
        for (int j = 0; j < 4; ++j)
            #pragma unroll
            for (int ks = 0; ks < 2; ++ks) {
                bf16x8 vf = *(const bf16x8*)&Vs[cur][ks*4 + (l>>4)][j*16 + (l & 15)][0];
                #pragma unroll
                for (int qt = 0; qt < 2; ++qt)
                    oacc[qt][j] = __builtin_amdgcn_mfma_f32_16x16x32_bf16(
                        efa[qt][ks], vf, oacc[qt][j], 0, 0, 0);
            }
        __syncthreads();
        cur ^= 1;
    }

    #pragma unroll
    for (int qt = 0; qt < 2; ++qt)
        #pragma unroll
        for (int j = 0; j < 4; ++j)
            #pragma unroll
            for (int r = 0; r < 4; ++r) {
                int qq = q0 + wq + qt*16 + (l>>4)*4 + r;
                int dv = j*16 + (l & 15);
                attn_o[(size_t)(b*T_ + qq) * 1024 + h*64 + dv] = f2bf(oacc[qt][j][r]);
            }
}

// ---------------------------------------------------------------------------
// fused norm
// ---------------------------------------------------------------------------
__device__ __forceinline__ float block_reduce_sum_256(float v, float* tmp)
{
    #pragma unroll
    for (int off = 32; off; off >>= 1) v += __shfl_down(v, off, 64);
    int lane = threadIdx.x & 63, w = threadIdx.x >> 6;
    __syncthreads();
    if (lane == 0) tmp[w] = v;
    __syncthreads();
    return tmp[0] + tmp[1] + tmp[2] + tmp[3];
}

template<int Z>
__global__ __launch_bounds__(256) void normZ_fused_kernel(
    const ushort* __restrict__ parts, long zoff,
    const float* __restrict__ bias, const float* __restrict__ resid,
    float* __restrict__ outf, ushort* __restrict__ outb)
{
    __shared__ float tmp[4];
    int row = blockIdx.x;
    int tid = threadIdx.x;
    int c0 = tid * 4;
    size_t idx = (size_t)row * D_ + c0;
    float vals[4] = {0.f, 0.f, 0.f, 0.f};
    #pragma unroll
    for (int z = 0; z < Z; ++z) {
        ushort4 p = *(const ushort4*)&parts[idx + (size_t)z * zoff];
        vals[0] += bf2f(p.x); vals[1] += bf2f(p.y);
        vals[2] += bf2f(p.z); vals[3] += bf2f(p.w);
    }
    float4 rv = *(const float4*)&resid[idx];
    vals[0] += rv.x; vals[1] += rv.y; vals[2] += rv.z; vals[3] += rv.w;
    if (bias) {
        float4 bv = *(const float4*)&bias[c0];
        vals[0] += bv.x; vals[1] += bv.y; vals[2] += bv.z; vals[3] += bv.w;
    }
    float s = vals[0] + vals[1] + vals[2] + vals[3];
    s = block_reduce_sum_256(s, tmp);
    float m = s * (1.0f / (float)D_);
    float sq = 0.f;
    #pragma unroll
    for (int i = 0; i < 4; ++i) { float c = vals[i] - m; sq += c * c; }
    sq = block_reduce_sum_256(sq, tmp);
    float rs = rsqrtf(sq * (1.0f / (float)(D_ - 1)));
    float4 o;
    o.x = (vals[0] - m) * rs; o.y = (vals[1] - m) * rs;
    o.z = (vals[2] - m) * rs; o.w = (vals[3] - m) * rs;
    *(float4*)&outf[idx] = o;
    if (outb) {
        ushort4 ob;
        ob.x = f2bf(o.x); ob.y = f2bf(o.y); ob.z = f2bf(o.z); ob.w = f2bf(o.w);
        *(ushort4*)&outb[idx] = ob;
    }
}

// ---------------------------------------------------------------------------
extern "C" void kernel_launch(void* const* d_in, const int* in_sizes, int n_in,
                              void* d_out, int out_size, void* d_ws, size_t ws_size,
                              hipStream_t stream)
{
    const float* x  = (const float*)d_in[0];
    const float* Wq = (const float*)d_in[1];
    const float* Wk = (const float*)d_in[2];
    const float* Wv = (const float*)d_in[3];
    const float* Wo = (const float*)d_in[4];
    const float* W1 = (const float*)d_in[5];
    const float* b1 = (const float*)d_in[6];
    const float* W2 = (const float*)d_in[7];
    const float* b2 = (const float*)d_in[8];
    float* out = (float*)d_out;

    const size_t MB = (size_t)1 << 20;
    char* base = (char*)d_ws;
    ushort* qkv    = (ushort*)(base +   0*MB);  // 24MB  [QKV..PV]
    ushort* hid    = (ushort*)(base +   0*MB);  // 32MB  [W1..W2]
    ushort* xb     = (ushort*)(base +  24*MB);  //  8MB  [cvt..QKV]
    ushort* W2t    = (ushort*)(base +  32*MB);  //  8MB  [cvt..W2]
    ushort* Wqkvt  = (ushort*)(base +  40*MB);  //  6MB  [cvt..QKV]
    ushort* wpart  = (ushort*)(base +  40*MB);  // 32MB  [W2..norm2]  (vt/Wot/W1t/attn_o dead)
    ushort* vt     = (ushort*)(base +  46*MB);  //  8MB  [csumv..PV]
    ushort* Wot    = (ushort*)(base +  55*MB);  //  2MB  [cvt..Wo]
    ushort* W1t    = (ushort*)(base +  57*MB);  //  8MB  [cvt..W1]
    ushort* attn_o = (ushort*)(base +  65*MB);  //  8MB  [PV..Wo]
    ushort* wopart = (ushort*)(base +  73*MB);  // 16MB  [Wo..norm1]
    ushort* out1b  = (ushort*)(base +  89*MB);  //  8MB  [norm1..W1]
    float*  out1f  = (float*) (base +  97*MB);  // 16MB  [norm1..norm2]

    // 1. converts / transposes
    cvt_bf16_kernel<<<dim3(BT_*D_/1024), 256, 0, stream>>>(x, xb, BT_*D_);
    transpose_qkv_kernel<<<dim3(2, 32, 48), 256, 0, stream>>>(Wq, Wk, Wv, Wqkvt);
    transpose_bf16_kernel<<<dim3(32, 32, 1), 256, 0, stream>>>(
        Wo, Wot, 1024, 1024, 0, 0);
    transpose_bf16_kernel<<<dim3(128, 32, 1), 256, 0, stream>>>(
        W1, W1t, 1024, 4096, 0, 0);
    transpose_bf16_kernel<<<dim3(32, 128, 1), 256, 0, stream>>>(
        W2, W2t, 4096, 1024, 0, 0);

    // 2. QKV: wide tile, 384 blocks.
    gemm_ntw_kernel<1><<<dim3(3072/256, 4096/128, 1), 256, 0, stream>>>(
        xb, 1024, Wqkvt, 1024, qkv, 3072, 1024, nullptr, nullptr, 0, 0, 0, 0);
    // 3. colsum + V-scale/transpose fused
    csumv_kernel<<<dim3(T_/128, B_*H_), 256, 0, stream>>>(qkv, vt);
    // 4. PV
    attn_pv_kernel<<<dim3(T_/128, B_*H_), 256, 0, stream>>>(qkv, vt, attn_o);
    // 5. Wo split-K2 -> bf16 partials. 512 blocks.
    gemm_nt_kernel<1><<<dim3(1024/128, 4096/128, 2), 256, 0, stream>>>(
        attn_o, 1024, Wot, 1024, wopart, 1024, 512, nullptr, nullptr, 0,
        512, 512, (long)4096*1024);
    // 6. norm1 fused
    normZ_fused_kernel<2><<<dim3(BT_), 256, 0, stream>>>(
        wopart, (long)4096*1024, nullptr, x, out1f, out1b);
    // 7. FFN up + ReLU: wide tile, 512 blocks.
    gemm_ntw_kernel<1><<<dim3(4096/256, 4096/128, 1), 256, 0, stream>>>(
        out1b, 1024, W1t, 1024, hid, 4096, 1024, b1, nullptr, 1, 0, 0, 0);
    // 8. FFN down: WIDE tile + split-K4 -> bf16 partials. 512 blocks, NT=32.
    gemm_ntw_kernel<1><<<dim3(1024/256, 4096/128, 4), 256, 0, stream>>>(
        hid, 4096, W2t, 4096, wpart, 1024, 1024, nullptr, nullptr, 0,
        1024, 1024, (long)4096*1024);
    // 9. norm2 fused: sum 4 partials + b2 + out1 resid -> out
    normZ_fused_kernel<4><<<dim3(BT_), 256, 0, stream>>>(
        wpart, (long)4096*1024, b2, out1f, out, nullptr);
}